// Round 1
// baseline (3987.981 us; speedup 1.0000x reference)
//
#include <hip/hip_runtime.h>
#include <math.h>

#define DI __device__ __forceinline__

DI float silu_f(float v) { return v / (1.f + __expf(-v)); }
DI float4 ld4(const float* p) { return *reinterpret_cast<const float4*>(p); }
DI void st4(float* p, const float4& v) { *reinterpret_cast<float4*>(p) = v; }

// ---------------------------------------------------------------------------
// Direct 3x3 SAME conv, f32. Thread = 4px (1x4 row) x 4co register tile.
// FUSE: 0 = none, 1 = SiLU, 2 = p3o epilogue: out = xres + ctx*(1+tanh(val))
// ---------------------------------------------------------------------------
template <int TH, int TW, int CO_BLK, int CO_T, int CIC, int FUSE>
__global__ void __launch_bounds__(576)
conv3x3_kernel(const float* __restrict__ in, const float* __restrict__ wgt,
               float* __restrict__ out, int B, int Ci, int Co, int H, int W,
               const float* __restrict__ ctx, const float* __restrict__ xres) {
    constexpr int TWH = TW + 2;   // halo width
    constexpr int TWP = TW + 3;   // padded LDS stride (odd-ish -> fewer conflicts)
    constexpr int SPAT = TH * (TW / 4);
    __shared__ float lin[CIC][TH + 2][TWP];
    __shared__ float wls[CIC][9][CO_BLK];

    const int nTx = W / TW, nTy = H / TH;
    const int nCoG = (Co + CO_BLK - 1) / CO_BLK;
    int bid = blockIdx.x;
    const int cog = bid % nCoG; bid /= nCoG;
    const int tx = bid % nTx;   bid /= nTx;
    const int ty = bid % nTy;
    const int b = bid / nTy;
    const int ox = tx * TW, oy = ty * TH;
    const int co0 = cog * CO_BLK;

    const int tid = threadIdx.x;
    const int cot = tid / SPAT;        // 0..CO_T-1
    const int sp = tid % SPAT;
    const int r = sp / (TW / 4);
    const int cg = sp % (TW / 4);

    float acc[4][4];
#pragma unroll
    for (int i = 0; i < 4; ++i)
#pragma unroll
        for (int j = 0; j < 4; ++j) acc[i][j] = 0.f;

    for (int ci0 = 0; ci0 < Ci; ci0 += CIC) {
        // stage input halo tiles
        for (int e = tid; e < CIC * (TH + 2) * TWH; e += SPAT * CO_T) {
            int xx = e % TWH;
            int yy = (e / TWH) % (TH + 2);
            int cc = e / (TWH * (TH + 2));
            int gy = oy - 1 + yy, gx = ox - 1 + xx;
            float v = 0.f;
            if (gy >= 0 && gy < H && gx >= 0 && gx < W)
                v = in[(((size_t)b * Ci + ci0 + cc) * H + gy) * W + gx];
            lin[cc][yy][xx] = v;
        }
        // stage weights [cic][k][co]
        for (int e = tid; e < CIC * 9 * CO_BLK; e += SPAT * CO_T) {
            int col = e % CO_BLK;
            int k = (e / CO_BLK) % 9;
            int cc = e / (CO_BLK * 9);
            int co = co0 + col;
            float v = 0.f;
            if (co < Co) v = wgt[((size_t)co * Ci + ci0 + cc) * 9 + k];
            wls[cc][k][col] = v;
        }
        __syncthreads();
#pragma unroll
        for (int cc = 0; cc < CIC; ++cc) {
            float v0[3][6];
#pragma unroll
            for (int ky = 0; ky < 3; ++ky)
#pragma unroll
                for (int u = 0; u < 6; ++u)
                    v0[ky][u] = lin[cc][r + ky][cg * 4 + u];
#pragma unroll
            for (int ky = 0; ky < 3; ++ky)
#pragma unroll
                for (int kx = 0; kx < 3; ++kx) {
                    const float4 w4 = ld4(&wls[cc][ky * 3 + kx][cot * 4]);
                    const float wv_[4] = {w4.x, w4.y, w4.z, w4.w};
#pragma unroll
                    for (int i = 0; i < 4; ++i)
#pragma unroll
                        for (int j = 0; j < 4; ++j)
                            acc[i][j] = fmaf(wv_[i], v0[ky][kx + j], acc[i][j]);
                }
        }
        __syncthreads();
    }
    // epilogue
    const int y = oy + r;
    const int xb = ox + cg * 4;
#pragma unroll
    for (int i = 0; i < 4; ++i) {
        int co = co0 + cot * 4 + i;
        if (co >= Co) continue;
        size_t base = (((size_t)b * Co + co) * H + y) * W + xb;
        float4 res;
        if (FUSE == 2) {
            float4 c4 = ld4(&ctx[base]);
            float4 x4 = ld4(&xres[base]);
            res.x = x4.x + c4.x * (1.f + tanhf(acc[i][0]));
            res.y = x4.y + c4.y * (1.f + tanhf(acc[i][1]));
            res.z = x4.z + c4.z * (1.f + tanhf(acc[i][2]));
            res.w = x4.w + c4.w * (1.f + tanhf(acc[i][3]));
        } else if (FUSE == 1) {
            res.x = silu_f(acc[i][0]); res.y = silu_f(acc[i][1]);
            res.z = silu_f(acc[i][2]); res.w = silu_f(acc[i][3]);
        } else {
            res.x = acc[i][0]; res.y = acc[i][1];
            res.z = acc[i][2]; res.w = acc[i][3];
        }
        st4(&out[base], res);
    }
}

// ---------------------------------------------------------------------------
// Batched GEMV: out[b][o][m] = act(sum_c W[o][c]*in[b][c][m] + bias[o])
// ---------------------------------------------------------------------------
template <int ACT>
__global__ void matmul_bcm(const float* __restrict__ W, const float* __restrict__ bias,
                           const float* __restrict__ in, float* __restrict__ out,
                           int B, int C, int O, int M) {
    long long idx = (long long)blockIdx.x * blockDim.x + threadIdx.x;
    long long total = (long long)B * O * M;
    if (idx >= total) return;
    int m = (int)(idx % M);
    int o = (int)((idx / M) % O);
    int b = (int)(idx / ((long long)M * O));
    const float* ip = in + (size_t)b * C * M + m;
    const float* wp = W + (size_t)o * C;
    float acc = bias ? bias[o] : 0.f;
    for (int c = 0; c < C; ++c) {
        acc = fmaf(wp[c], *ip, acc);
        ip += M;
    }
    if (ACT == 1) acc = silu_f(acc);
    out[idx] = acc;
}

// ---------------------------------------------------------------------------
// PSP pooling: one block per (b,c) plane, kf[b][c][50]
// ---------------------------------------------------------------------------
__global__ void psp_kernel(const float* __restrict__ x, float* __restrict__ kf) {
    __shared__ float pl[576];
    int bc = blockIdx.x;
    const float* xp = x + (size_t)bc * 576;
    for (int e = threadIdx.x; e < 576; e += 64) pl[e] = xp[e];
    __syncthreads();
    int m = threadIdx.x;
    if (m < 50) {
        int g, i0;
        if (m < 36)      { g = 6; i0 = m; }
        else if (m < 45) { g = 3; i0 = m - 36; }
        else if (m < 49) { g = 2; i0 = m - 45; }
        else             { g = 1; i0 = 0; }
        int bs = 24 / g;
        int by = i0 / g, bx = i0 % g;
        float s = 0.f;
        for (int yy = 0; yy < bs; ++yy)
            for (int xx = 0; xx < bs; ++xx)
                s += pl[(by * bs + yy) * 24 + bx * bs + xx];
        kf[(size_t)bc * 50 + m] = s / (float)(bs * bs);
    }
}

// ---------------------------------------------------------------------------
// Fused attention: sim = softmax(q^T k), ctx = v sim^T. Block = (b, 32 n's).
// ---------------------------------------------------------------------------
__global__ void attn_kernel(const float* __restrict__ q, const float* __restrict__ k,
                            const float* __restrict__ v, float* __restrict__ ctx) {
    __shared__ float qs[32][33];
    __shared__ float ks[32][53];
    __shared__ float sim[32][53];
    int bidx = blockIdx.x;
    int b = bidx / 18;
    int n0 = (bidx % 18) * 32;
    int tid = threadIdx.x;
    for (int e = tid; e < 32 * 32; e += 256) {
        int c = e / 32, nl = e % 32;
        qs[c][nl] = q[((size_t)b * 32 + c) * 576 + n0 + nl];
    }
    for (int e = tid; e < 32 * 50; e += 256) {
        int c = e / 50, m = e % 50;
        ks[c][m] = k[((size_t)b * 32 + c) * 50 + m];
    }
    __syncthreads();
    for (int e = tid; e < 32 * 50; e += 256) {
        int nl = e / 50, m = e % 50;
        float s = 0.f;
        for (int c = 0; c < 32; ++c) s = fmaf(qs[c][nl], ks[c][m], s);
        sim[nl][m] = s;
    }
    __syncthreads();
    if (tid < 32) {
        float mx = -1e30f;
        for (int m = 0; m < 50; ++m) mx = fmaxf(mx, sim[tid][m]);
        float sum = 0.f;
        for (int m = 0; m < 50; ++m) {
            float e2 = __expf(sim[tid][m] - mx);
            sim[tid][m] = e2;
            sum += e2;
        }
        float inv = 1.f / sum;
        for (int m = 0; m < 50; ++m) sim[tid][m] *= inv;
    }
    __syncthreads();
    int nl = tid % 32, c0 = tid / 32;
    for (int c = c0; c < 512; c += 8) {
        const float* vp = v + ((size_t)b * 512 + c) * 50;
        float s = 0.f;
        for (int m = 0; m < 50; ++m) s = fmaf(vp[m], sim[nl][m], s);
        ctx[((size_t)b * 512 + c) * 576 + n0 + nl] = s;
    }
}

// ---------------------------------------------------------------------------
// Tiled 1x1 conv on concat [cp; sp] (512 -> 64) + SiLU. Tile 64co x 128m.
// ---------------------------------------------------------------------------
__global__ void __launch_bounds__(256)
conv1x1_cat_kernel(const float* __restrict__ cp, const float* __restrict__ sp,
                   const float* __restrict__ w, float* __restrict__ out) {
    __shared__ float ins[8][128];
    __shared__ float wls[8][64];
    int bid = blockIdx.x;
    int mt = bid % 72;
    int b = bid / 72;
    int m0 = mt * 128;
    int tid = threadIdx.x;
    int ml = (tid & 31) * 4;
    int col = (tid >> 5) * 8;
    float acc[8][4];
#pragma unroll
    for (int i = 0; i < 8; ++i)
#pragma unroll
        for (int j = 0; j < 4; ++j) acc[i][j] = 0.f;
    for (int c0 = 0; c0 < 512; c0 += 8) {
        {
            int e = tid * 4;
            int cl = e >> 7, mm = e & 127;
            int cidx = c0 + cl;
            const float* src = (cidx < 256)
                ? (cp + ((size_t)b * 256 + cidx) * 9216 + m0 + mm)
                : (sp + ((size_t)b * 256 + (cidx - 256)) * 9216 + m0 + mm);
            st4(&ins[cl][mm], ld4(src));
        }
        for (int e = tid; e < 512; e += 256) {
            int cl = e & 7;
            int o = e >> 3;
            wls[cl][o] = w[(size_t)o * 512 + c0 + cl];
        }
        __syncthreads();
#pragma unroll
        for (int cl = 0; cl < 8; ++cl) {
            float4 a4 = ld4(&ins[cl][ml]);
            float4 w0 = ld4(&wls[cl][col]);
            float4 w1 = ld4(&wls[cl][col + 4]);
            float av[4] = {a4.x, a4.y, a4.z, a4.w};
            float wv_[8] = {w0.x, w0.y, w0.z, w0.w, w1.x, w1.y, w1.z, w1.w};
#pragma unroll
            for (int oo = 0; oo < 8; ++oo)
#pragma unroll
                for (int j = 0; j < 4; ++j)
                    acc[oo][j] = fmaf(wv_[oo], av[j], acc[oo][j]);
        }
        __syncthreads();
    }
#pragma unroll
    for (int oo = 0; oo < 8; ++oo) {
        float4 r;
        r.x = silu_f(acc[oo][0]);
        r.y = silu_f(acc[oo][1]);
        r.z = silu_f(acc[oo][2]);
        r.w = silu_f(acc[oo][3]);
        st4(&out[((size_t)b * 64 + col + oo) * 9216 + m0 + ml], r);
    }
}

// ---------------------------------------------------------------------------
// Bilinear upsample 24x24 -> 96x96, align_corners=True
// ---------------------------------------------------------------------------
__global__ void upsample_kernel(const float* __restrict__ in, float* __restrict__ out) {
    int idx = blockIdx.x * 256 + threadIdx.x;
    const int total = 8 * 256 * 96 * 96;
    if (idx >= total) return;
    int x = idx % 96;
    int y = (idx / 96) % 96;
    int p = idx / 9216;
    float fy = y * (23.f / 95.f);
    float fx = x * (23.f / 95.f);
    int y0 = (int)fy; if (y0 > 22) y0 = 22;
    int x0 = (int)fx; if (x0 > 22) x0 = 22;
    float wy = fy - y0, wx = fx - x0;
    const float* ip = in + (size_t)p * 576;
    float a = ip[y0 * 24 + x0], b = ip[y0 * 24 + x0 + 1];
    float c = ip[(y0 + 1) * 24 + x0], d = ip[(y0 + 1) * 24 + x0 + 1];
    float l = a * (1.f - wy) + c * wy;
    float r = b * (1.f - wy) + d * wy;
    out[idx] = l * (1.f - wx) + r * wx;
}

// ---------------------------------------------------------------------------
// grid_sample (bilinear, align_corners=True, zeros pad) x2 + tanh blend
// ---------------------------------------------------------------------------
DI float bsample(const float* __restrict__ pl, float gx, float gy) {
    float px = (gx + 1.f) * 47.5f;
    float py = (gy + 1.f) * 47.5f;
    float x0 = floorf(px), y0 = floorf(py);
    float wx = px - x0, wy = py - y0;
    float acc = 0.f;
#pragma unroll
    for (int dy = 0; dy < 2; ++dy) {
        float yf = y0 + dy;
        float wyy = dy ? wy : (1.f - wy);
        if (yf < 0.f || yf > 95.f) continue;
        int yi = (int)yf;
#pragma unroll
        for (int dx = 0; dx < 2; ++dx) {
            float xf = x0 + dx;
            float wxx = dx ? wx : (1.f - wx);
            if (xf < 0.f || xf > 95.f) continue;
            acc = fmaf(pl[yi * 96 + (int)xf], wyy * wxx, acc);
        }
    }
    return acc;
}

__global__ void gsample_kernel(const float* __restrict__ cp, const float* __restrict__ sp,
                               const float* __restrict__ cr, float* __restrict__ p5o) {
    int idx = blockIdx.x * 256 + threadIdx.x;
    const int total = 8 * 256 * 96 * 96;
    if (idx >= total) return;
    int x = idx % 96;
    int y = (idx / 96) % 96;
    int c = (idx / 9216) % 256;
    int b = idx / (9216 * 256);
    int g = c >> 7;
    const float* crb = cr + (size_t)b * 10 * 9216;
    int pix = y * 96 + x;
    float offlx = crb[(2 * g) * 9216 + pix];
    float offly = crb[(2 * g + 1) * 9216 + pix];
    float offhx = crb[(4 + 2 * g) * 9216 + pix];
    float offhy = crb[(5 + 2 * g) * 9216 + pix];
    float bx = -1.f + x * (2.f / 95.f);
    float by = -1.f + y * (2.f / 95.f);
    const float* cpp = cp + (size_t)(b * 256 + c) * 9216;
    const float* spp = sp + (size_t)(b * 256 + c) * 9216;
    float cps = bsample(cpp, bx + offlx * (1.f / 96.f), by + offly * (1.f / 96.f));
    float sps = bsample(spp, bx + offhx * (1.f / 96.f), by + offhy * (1.f / 96.f));
    float att0 = 1.f + tanhf(crb[8 * 9216 + pix]);
    float att1 = 1.f + tanhf(crb[9 * 9216 + pix]);
    p5o[idx] = sps * att0 + cps * att1;
}

// ---------------------------------------------------------------------------
extern "C" void kernel_launch(void* const* d_in, const int* in_sizes, int n_in,
                              void* d_out, int out_size, void* d_ws, size_t ws_size,
                              hipStream_t stream) {
    const float* p3    = (const float*)d_in[0];
    const float* p5    = (const float*)d_in[1];
    const float* w_red = (const float*)d_in[2];
    const float* wq    = (const float*)d_in[3];
    const float* bq    = (const float*)d_in[4];
    const float* wk    = (const float*)d_in[5];
    const float* bk    = (const float*)d_in[6];
    const float* wv    = (const float*)d_in[7];
    const float* bv    = (const float*)d_in[8];
    const float* la_w1 = (const float*)d_in[9];
    const float* la_w2 = (const float*)d_in[10];
    const float* w32   = (const float*)d_in[11];
    const float* w8    = (const float*)d_in[12];
    const float* woff1 = (const float*)d_in[13];
    const float* woff2 = (const float*)d_in[14];

    float* out = (float*)d_out;
    float* p3o = out;                 // [8,512,24,24]  2359296
    float* p5o = out + 2359296;       // [8,256,96,96] 18874368

    float* ws = (float*)d_ws;
    float* x_   = ws + 0;             // 2359296
    float* ctx  = ws + 2359296;       // 2359296
    float* q    = ws + 4718592;       // 147456
    float* kf   = ws + 4866048;       // 204800
    float* km   = ws + 5070848;       // 12800
    float* vm   = ws + 5083648;       // 204800
    float* la1  = ws + 5288448;       // 294912
    float* sp24 = ws + 5583360;       // 1179648
    float* sp96 = ws + 6763008;       // 18874368
    float* cp   = ws + 25637376;      // 18874368
    // reuse (dead after p3o/sp24 phases):
    float* t64  = ws + 0;             // 4718592 (reuses x_/ctx, both dead)
    float* cr   = ws + 4718592;       // 737280 (reuses q/kf/km/vm/la1, all dead)

    // K1: x = silu(conv3x3(p3, w_red)) 512->512, 24x24
    conv3x3_kernel<24, 24, 16, 4, 4, 1><<<dim3(8 * 32), dim3(576), 0, stream>>>(
        p3, w_red, x_, 8, 512, 512, 24, 24, nullptr, nullptr);
    // K2: q = conv1x1(x, wq) + bq
    matmul_bcm<0><<<dim3((8 * 32 * 576 + 255) / 256), dim3(256), 0, stream>>>(
        wq, bq, x_, q, 8, 512, 32, 576);
    // K3: kfeat = psp(x)
    psp_kernel<<<dim3(8 * 512), dim3(64), 0, stream>>>(x_, kf);
    // K4: k, v projections of kfeat
    matmul_bcm<0><<<dim3((8 * 32 * 50 + 255) / 256), dim3(256), 0, stream>>>(
        wk, bk, kf, km, 8, 512, 32, 50);
    matmul_bcm<0><<<dim3((8 * 512 * 50 + 255) / 256), dim3(256), 0, stream>>>(
        wv, bv, kf, vm, 8, 512, 512, 50);
    // K5: sim = softmax(q^T k); ctx = v sim^T
    attn_kernel<<<dim3(8 * 18), dim3(256), 0, stream>>>(q, km, vm, ctx);
    // K6: la1 = silu(conv1x1(ctx, la_w1))
    matmul_bcm<1><<<dim3((8 * 64 * 576 + 255) / 256), dim3(256), 0, stream>>>(
        la_w1, nullptr, ctx, la1, 8, 512, 64, 576);
    // K7: p3o = x + ctx*(1 + tanh(conv3x3(la1, la_w2)))
    conv3x3_kernel<24, 24, 16, 4, 4, 2><<<dim3(8 * 32), dim3(576), 0, stream>>>(
        la1, la_w2, p3o, 8, 64, 512, 24, 24, ctx, x_);
    // K8: sp24 = silu(conv3x3(p3o, w32)) 512->256
    conv3x3_kernel<24, 24, 16, 4, 4, 1><<<dim3(8 * 16), dim3(576), 0, stream>>>(
        p3o, w32, sp24, 8, 512, 256, 24, 24, nullptr, nullptr);
    // K9: sp96 = bilinear upsample(sp24) 24->96
    upsample_kernel<<<dim3(8 * 256 * 9216 / 256), dim3(256), 0, stream>>>(sp24, sp96);
    // K10: cp = silu(conv3x3(p5, w8)) 256->256, 96x96  (dominant)
    conv3x3_kernel<16, 32, 16, 4, 4, 1><<<dim3(8 * 6 * 3 * 16), dim3(512), 0, stream>>>(
        p5, w8, cp, 8, 256, 256, 96, 96, nullptr, nullptr);
    // K11: t64 = silu(conv1x1(concat[cp, sp96], woff1))
    conv1x1_cat_kernel<<<dim3(8 * 72), dim3(256), 0, stream>>>(cp, sp96, woff1, t64);
    // K12: cr = conv3x3(t64, woff2) 64->10 (no act)
    conv3x3_kernel<16, 32, 12, 3, 4, 0><<<dim3(8 * 6 * 3 * 1), dim3(384), 0, stream>>>(
        t64, woff2, cr, 8, 64, 10, 96, 96, nullptr, nullptr);
    // K13: p5o = grid_sample blend
    gsample_kernel<<<dim3(8 * 256 * 9216 / 256), dim3(256), 0, stream>>>(
        cp, sp96, cr, p5o);
}

// Round 2
// 1485.490 us; speedup vs baseline: 2.6846x; 2.6846x over previous
//
#include <hip/hip_runtime.h>
#include <math.h>

#define DI __device__ __forceinline__

typedef __attribute__((ext_vector_type(8))) short bf16x8;
typedef __attribute__((ext_vector_type(4))) float f32x4;

DI float silu_f(float v) { return v / (1.f + __expf(-v)); }
DI float4 ld4(const float* p) { return *reinterpret_cast<const float4*>(p); }
DI void st4(float* p, const float4& v) { *reinterpret_cast<float4*>(p) = v; }
DI unsigned short f2bf(float f) {
    unsigned u = __float_as_uint(f);
    unsigned r = (u + 0x7FFFu + ((u >> 16) & 1u)) >> 16;
    return (unsigned short)r;
}

// ---------------------------------------------------------------------------
// Weight pre-pack: w f32 [Co][Ci][3][3] -> pk bf16 [Ci/32][Co][296]
// where pk[ch][co][dydx*32+cc] = w[co][ch*32+cc][dydx]; slots 288..295 = 0 pad.
// ---------------------------------------------------------------------------
__global__ void pack_w_kernel(const float* __restrict__ w, unsigned short* __restrict__ pk,
                              int Ci, int Co) {
    int idx = blockIdx.x * 256 + threadIdx.x;
    int total = (Ci >> 5) * Co * 296;
    if (idx >= total) return;
    int e = idx % 296;
    int co = (idx / 296) % Co;
    int ch = idx / (296 * Co);
    unsigned short v = 0;
    if (e < 288) {
        int dydx = e >> 5;
        int cc = e & 31;
        v = f2bf(w[((size_t)co * Ci + (ch << 5) + cc) * 9 + dydx]);
    }
    pk[idx] = v;
}

// ---------------------------------------------------------------------------
// MFMA implicit-GEMM 3x3 SAME conv. Input f32 NCHW, weights packed bf16,
// output f32 NCHW (optional SiLU). Block: 64co x (TH*TW=64 px), 4 waves 2x2.
// ---------------------------------------------------------------------------
template <int TH, int TW, int SILU>
__global__ void __launch_bounds__(256)
conv3x3_mfma(const float* __restrict__ in, const unsigned short* __restrict__ wpk,
             float* __restrict__ out, int B, int Ci, int Co, int H, int W) {
    constexpr int TWH = TW + 2;
    constexpr int HP = (TH + 2) * TWH;
    __shared__ __align__(16) unsigned short lin[HP * 40];
    __shared__ __align__(16) unsigned short wls[64 * 296];

    const int nTx = W / TW, nTy = H / TH, nCoG = Co >> 6;
    int bid = blockIdx.x;
    const int cog = bid % nCoG; bid /= nCoG;
    const int tx = bid % nTx;   bid /= nTx;
    const int ty = bid % nTy;
    const int b = bid / nTy;
    const int ox = tx * TW, oy = ty * TH, co0 = cog << 6;

    const int tid = threadIdx.x;
    const int wave = tid >> 6, lane = tid & 63;
    const int l15 = lane & 15, g = lane >> 4;
    const int wco = (wave >> 1) << 5;   // 0 or 32
    const int wpx = (wave & 1) << 5;    // 0 or 32
    const int px0 = wpx + l15, px1 = px0 + 16;
    const int r0 = px0 / TW, c0 = px0 % TW;
    const int r1 = px1 / TW, c1 = px1 % TW;

    f32x4 acc00 = {}, acc01 = {}, acc10 = {}, acc11 = {};
    const int nCh = Ci >> 5;
    const size_t HWs = (size_t)H * W;

    for (int ch = 0; ch < nCh; ++ch) {
        // ---- stage input chunk: lin[hp][cc], cc in [0,32), pad to 40 ----
#pragma unroll
        for (int it = 0; it < (HP * 8 + 255) / 256; ++it) {
            int e = tid + it * 256;
            if (e < HP * 8) {
                int hp = e % HP;
                int cg = e / HP;               // 4 ci per thread
                int hy = hp / TWH, hx = hp % TWH;
                int gy = oy + hy - 1, gx = ox + hx - 1;
                unsigned p0 = 0, p1 = 0;
                if ((unsigned)gy < (unsigned)H && (unsigned)gx < (unsigned)W) {
                    const float* ip = in + ((size_t)b * Ci + (ch << 5) + (cg << 2)) * HWs
                                         + (size_t)gy * W + gx;
                    float f0 = ip[0], f1 = ip[HWs], f2 = ip[2 * HWs], f3 = ip[3 * HWs];
                    p0 = (unsigned)f2bf(f0) | ((unsigned)f2bf(f1) << 16);
                    p1 = (unsigned)f2bf(f2) | ((unsigned)f2bf(f3) << 16);
                }
                *(uint2*)&lin[hp * 40 + (cg << 2)] = make_uint2(p0, p1);
            }
        }
        // ---- stage weights: 64co x 296 bf16 = 37888 B, 16B/thread-iter ----
        {
            const unsigned short* src = wpk + ((size_t)ch * Co + co0) * 296;
#pragma unroll
            for (int it = 0; it < 10; ++it) {
                int e = tid + it * 256;
                if (e < 2368) *(uint4*)&wls[e * 8] = *(const uint4*)&src[e * 8];
            }
        }
        __syncthreads();

        const unsigned short* wb0 = &wls[(wco + l15) * 296 + g * 8];
        const unsigned short* wb1 = wb0 + 16 * 296;
#pragma unroll
        for (int dy = 0; dy < 3; ++dy) {
#pragma unroll
            for (int dx = 0; dx < 3; ++dx) {
                const int dydx = dy * 3 + dx;
                bf16x8 a0 = *(const bf16x8*)(wb0 + dydx * 32);
                bf16x8 a1 = *(const bf16x8*)(wb1 + dydx * 32);
                bf16x8 b0v = *(const bf16x8*)&lin[((r0 + dy) * TWH + c0 + dx) * 40 + g * 8];
                bf16x8 b1v = *(const bf16x8*)&lin[((r1 + dy) * TWH + c1 + dx) * 40 + g * 8];
                acc00 = __builtin_amdgcn_mfma_f32_16x16x32_bf16(a0, b0v, acc00, 0, 0, 0);
                acc01 = __builtin_amdgcn_mfma_f32_16x16x32_bf16(a0, b1v, acc01, 0, 0, 0);
                acc10 = __builtin_amdgcn_mfma_f32_16x16x32_bf16(a1, b0v, acc10, 0, 0, 0);
                acc11 = __builtin_amdgcn_mfma_f32_16x16x32_bf16(a1, b1v, acc11, 0, 0, 0);
            }
        }
        __syncthreads();
    }
    // ---- epilogue: D col = lane&15 (px), row = 4*(lane>>4)+reg (co) ----
    const int yA = oy + r0, xA = ox + c0;
    const int yB = oy + r1, xB = ox + c1;
#pragma unroll
    for (int r4 = 0; r4 < 4; ++r4) {
        int coA = co0 + wco + (g << 2) + r4;
        int coB = coA + 16;
        float v00 = acc00[r4], v01 = acc01[r4], v10 = acc10[r4], v11 = acc11[r4];
        if (SILU) { v00 = silu_f(v00); v01 = silu_f(v01); v10 = silu_f(v10); v11 = silu_f(v11); }
        out[((size_t)b * Co + coA) * HWs + (size_t)yA * W + xA] = v00;
        out[((size_t)b * Co + coA) * HWs + (size_t)yB * W + xB] = v01;
        out[((size_t)b * Co + coB) * HWs + (size_t)yA * W + xA] = v10;
        out[((size_t)b * Co + coB) * HWs + (size_t)yB * W + xB] = v11;
    }
}

// ---------------------------------------------------------------------------
// Direct 3x3 SAME conv, f32 (kept for small-Ci / small-Co cases).
// FUSE: 0 = none, 1 = SiLU, 2 = p3o epilogue: out = xres + ctx*(1+tanh(val))
// ---------------------------------------------------------------------------
template <int TH, int TW, int CO_BLK, int CO_T, int CIC, int FUSE>
__global__ void __launch_bounds__(576)
conv3x3_kernel(const float* __restrict__ in, const float* __restrict__ wgt,
               float* __restrict__ out, int B, int Ci, int Co, int H, int W,
               const float* __restrict__ ctx, const float* __restrict__ xres) {
    constexpr int TWH = TW + 2;
    constexpr int TWP = TW + 3;
    constexpr int SPAT = TH * (TW / 4);
    __shared__ float lin[CIC][TH + 2][TWP];
    __shared__ float wls[CIC][9][CO_BLK];

    const int nTx = W / TW, nTy = H / TH;
    const int nCoG = (Co + CO_BLK - 1) / CO_BLK;
    int bid = blockIdx.x;
    const int cog = bid % nCoG; bid /= nCoG;
    const int tx = bid % nTx;   bid /= nTx;
    const int ty = bid % nTy;
    const int b = bid / nTy;
    const int ox = tx * TW, oy = ty * TH;
    const int co0 = cog * CO_BLK;

    const int tid = threadIdx.x;
    const int cot = tid / SPAT;
    const int sp = tid % SPAT;
    const int r = sp / (TW / 4);
    const int cg = sp % (TW / 4);

    float acc[4][4];
#pragma unroll
    for (int i = 0; i < 4; ++i)
#pragma unroll
        for (int j = 0; j < 4; ++j) acc[i][j] = 0.f;

    for (int ci0 = 0; ci0 < Ci; ci0 += CIC) {
        for (int e = tid; e < CIC * (TH + 2) * TWH; e += SPAT * CO_T) {
            int xx = e % TWH;
            int yy = (e / TWH) % (TH + 2);
            int cc = e / (TWH * (TH + 2));
            int gy = oy - 1 + yy, gx = ox - 1 + xx;
            float v = 0.f;
            if (gy >= 0 && gy < H && gx >= 0 && gx < W)
                v = in[(((size_t)b * Ci + ci0 + cc) * H + gy) * W + gx];
            lin[cc][yy][xx] = v;
        }
        for (int e = tid; e < CIC * 9 * CO_BLK; e += SPAT * CO_T) {
            int col = e % CO_BLK;
            int k = (e / CO_BLK) % 9;
            int cc = e / (CO_BLK * 9);
            int co = co0 + col;
            float v = 0.f;
            if (co < Co) v = wgt[((size_t)co * Ci + ci0 + cc) * 9 + k];
            wls[cc][k][col] = v;
        }
        __syncthreads();
#pragma unroll
        for (int cc = 0; cc < CIC; ++cc) {
            float v0[3][6];
#pragma unroll
            for (int ky = 0; ky < 3; ++ky)
#pragma unroll
                for (int u = 0; u < 6; ++u)
                    v0[ky][u] = lin[cc][r + ky][cg * 4 + u];
#pragma unroll
            for (int ky = 0; ky < 3; ++ky)
#pragma unroll
                for (int kx = 0; kx < 3; ++kx) {
                    const float4 w4 = ld4(&wls[cc][ky * 3 + kx][cot * 4]);
                    const float wv_[4] = {w4.x, w4.y, w4.z, w4.w};
#pragma unroll
                    for (int i = 0; i < 4; ++i)
#pragma unroll
                        for (int j = 0; j < 4; ++j)
                            acc[i][j] = fmaf(wv_[i], v0[ky][kx + j], acc[i][j]);
                }
        }
        __syncthreads();
    }
    const int y = oy + r;
    const int xb = ox + cg * 4;
#pragma unroll
    for (int i = 0; i < 4; ++i) {
        int co = co0 + cot * 4 + i;
        if (co >= Co) continue;
        size_t base = (((size_t)b * Co + co) * H + y) * W + xb;
        float4 res;
        if (FUSE == 2) {
            float4 c4 = ld4(&ctx[base]);
            float4 x4 = ld4(&xres[base]);
            res.x = x4.x + c4.x * (1.f + tanhf(acc[i][0]));
            res.y = x4.y + c4.y * (1.f + tanhf(acc[i][1]));
            res.z = x4.z + c4.z * (1.f + tanhf(acc[i][2]));
            res.w = x4.w + c4.w * (1.f + tanhf(acc[i][3]));
        } else if (FUSE == 1) {
            res.x = silu_f(acc[i][0]); res.y = silu_f(acc[i][1]);
            res.z = silu_f(acc[i][2]); res.w = silu_f(acc[i][3]);
        } else {
            res.x = acc[i][0]; res.y = acc[i][1];
            res.z = acc[i][2]; res.w = acc[i][3];
        }
        st4(&out[base], res);
    }
}

// ---------------------------------------------------------------------------
// Batched GEMV: out[b][o][m] = act(sum_c W[o][c]*in[b][c][m] + bias[o])
// ---------------------------------------------------------------------------
template <int ACT>
__global__ void matmul_bcm(const float* __restrict__ W, const float* __restrict__ bias,
                           const float* __restrict__ in, float* __restrict__ out,
                           int B, int C, int O, int M) {
    long long idx = (long long)blockIdx.x * blockDim.x + threadIdx.x;
    long long total = (long long)B * O * M;
    if (idx >= total) return;
    int m = (int)(idx % M);
    int o = (int)((idx / M) % O);
    int b = (int)(idx / ((long long)M * O));
    const float* ip = in + (size_t)b * C * M + m;
    const float* wp = W + (size_t)o * C;
    float acc = bias ? bias[o] : 0.f;
    for (int c = 0; c < C; ++c) {
        acc = fmaf(wp[c], *ip, acc);
        ip += M;
    }
    if (ACT == 1) acc = silu_f(acc);
    out[idx] = acc;
}

// ---------------------------------------------------------------------------
__global__ void psp_kernel(const float* __restrict__ x, float* __restrict__ kf) {
    __shared__ float pl[576];
    int bc = blockIdx.x;
    const float* xp = x + (size_t)bc * 576;
    for (int e = threadIdx.x; e < 576; e += 64) pl[e] = xp[e];
    __syncthreads();
    int m = threadIdx.x;
    if (m < 50) {
        int g, i0;
        if (m < 36)      { g = 6; i0 = m; }
        else if (m < 45) { g = 3; i0 = m - 36; }
        else if (m < 49) { g = 2; i0 = m - 45; }
        else             { g = 1; i0 = 0; }
        int bs = 24 / g;
        int by = i0 / g, bx = i0 % g;
        float s = 0.f;
        for (int yy = 0; yy < bs; ++yy)
            for (int xx = 0; xx < bs; ++xx)
                s += pl[(by * bs + yy) * 24 + bx * bs + xx];
        kf[(size_t)bc * 50 + m] = s / (float)(bs * bs);
    }
}

// ---------------------------------------------------------------------------
__global__ void attn_kernel(const float* __restrict__ q, const float* __restrict__ k,
                            const float* __restrict__ v, float* __restrict__ ctx) {
    __shared__ float qs[32][33];
    __shared__ float ks[32][53];
    __shared__ float sim[32][53];
    int bidx = blockIdx.x;
    int b = bidx / 18;
    int n0 = (bidx % 18) * 32;
    int tid = threadIdx.x;
    for (int e = tid; e < 32 * 32; e += 256) {
        int c = e / 32, nl = e % 32;
        qs[c][nl] = q[((size_t)b * 32 + c) * 576 + n0 + nl];
    }
    for (int e = tid; e < 32 * 50; e += 256) {
        int c = e / 50, m = e % 50;
        ks[c][m] = k[((size_t)b * 32 + c) * 50 + m];
    }
    __syncthreads();
    for (int e = tid; e < 32 * 50; e += 256) {
        int nl = e / 50, m = e % 50;
        float s = 0.f;
        for (int c = 0; c < 32; ++c) s = fmaf(qs[c][nl], ks[c][m], s);
        sim[nl][m] = s;
    }
    __syncthreads();
    if (tid < 32) {
        float mx = -1e30f;
        for (int m = 0; m < 50; ++m) mx = fmaxf(mx, sim[tid][m]);
        float sum = 0.f;
        for (int m = 0; m < 50; ++m) {
            float e2 = __expf(sim[tid][m] - mx);
            sim[tid][m] = e2;
            sum += e2;
        }
        float inv = 1.f / sum;
        for (int m = 0; m < 50; ++m) sim[tid][m] *= inv;
    }
    __syncthreads();
    int nl = tid % 32, c0 = tid / 32;
    for (int c = c0; c < 512; c += 8) {
        const float* vp = v + ((size_t)b * 512 + c) * 50;
        float s = 0.f;
        for (int m = 0; m < 50; ++m) s = fmaf(vp[m], sim[nl][m], s);
        ctx[((size_t)b * 512 + c) * 576 + n0 + nl] = s;
    }
}

// ---------------------------------------------------------------------------
__global__ void __launch_bounds__(256)
conv1x1_cat_kernel(const float* __restrict__ cp, const float* __restrict__ sp,
                   const float* __restrict__ w, float* __restrict__ out) {
    __shared__ float ins[8][128];
    __shared__ float wls[8][64];
    int bid = blockIdx.x;
    int mt = bid % 72;
    int b = bid / 72;
    int m0 = mt * 128;
    int tid = threadIdx.x;
    int ml = (tid & 31) * 4;
    int col = (tid >> 5) * 8;
    float acc[8][4];
#pragma unroll
    for (int i = 0; i < 8; ++i)
#pragma unroll
        for (int j = 0; j < 4; ++j) acc[i][j] = 0.f;
    for (int c0 = 0; c0 < 512; c0 += 8) {
        {
            int e = tid * 4;
            int cl = e >> 7, mm = e & 127;
            int cidx = c0 + cl;
            const float* src = (cidx < 256)
                ? (cp + ((size_t)b * 256 + cidx) * 9216 + m0 + mm)
                : (sp + ((size_t)b * 256 + (cidx - 256)) * 9216 + m0 + mm);
            st4(&ins[cl][mm], ld4(src));
        }
        for (int e = tid; e < 512; e += 256) {
            int cl = e & 7;
            int o = e >> 3;
            wls[cl][o] = w[(size_t)o * 512 + c0 + cl];
        }
        __syncthreads();
#pragma unroll
        for (int cl = 0; cl < 8; ++cl) {
            float4 a4 = ld4(&ins[cl][ml]);
            float4 w0 = ld4(&wls[cl][col]);
            float4 w1 = ld4(&wls[cl][col + 4]);
            float av[4] = {a4.x, a4.y, a4.z, a4.w};
            float wv_[8] = {w0.x, w0.y, w0.z, w0.w, w1.x, w1.y, w1.z, w1.w};
#pragma unroll
            for (int oo = 0; oo < 8; ++oo)
#pragma unroll
                for (int j = 0; j < 4; ++j)
                    acc[oo][j] = fmaf(wv_[oo], av[j], acc[oo][j]);
        }
        __syncthreads();
    }
#pragma unroll
    for (int oo = 0; oo < 8; ++oo) {
        float4 r;
        r.x = silu_f(acc[oo][0]);
        r.y = silu_f(acc[oo][1]);
        r.z = silu_f(acc[oo][2]);
        r.w = silu_f(acc[oo][3]);
        st4(&out[((size_t)b * 64 + col + oo) * 9216 + m0 + ml], r);
    }
}

// ---------------------------------------------------------------------------
__global__ void upsample_kernel(const float* __restrict__ in, float* __restrict__ out) {
    int idx = blockIdx.x * 256 + threadIdx.x;
    const int total = 8 * 256 * 96 * 96;
    if (idx >= total) return;
    int x = idx % 96;
    int y = (idx / 96) % 96;
    int p = idx / 9216;
    float fy = y * (23.f / 95.f);
    float fx = x * (23.f / 95.f);
    int y0 = (int)fy; if (y0 > 22) y0 = 22;
    int x0 = (int)fx; if (x0 > 22) x0 = 22;
    float wy = fy - y0, wx = fx - x0;
    const float* ip = in + (size_t)p * 576;
    float a = ip[y0 * 24 + x0], b = ip[y0 * 24 + x0 + 1];
    float c = ip[(y0 + 1) * 24 + x0], d = ip[(y0 + 1) * 24 + x0 + 1];
    float l = a * (1.f - wy) + c * wy;
    float r = b * (1.f - wy) + d * wy;
    out[idx] = l * (1.f - wx) + r * wx;
}

// ---------------------------------------------------------------------------
DI float bsample(const float* __restrict__ pl, float gx, float gy) {
    float px = (gx + 1.f) * 47.5f;
    float py = (gy + 1.f) * 47.5f;
    float x0 = floorf(px), y0 = floorf(py);
    float wx = px - x0, wy = py - y0;
    float acc = 0.f;
#pragma unroll
    for (int dy = 0; dy < 2; ++dy) {
        float yf = y0 + dy;
        float wyy = dy ? wy : (1.f - wy);
        if (yf < 0.f || yf > 95.f) continue;
        int yi = (int)yf;
#pragma unroll
        for (int dx = 0; dx < 2; ++dx) {
            float xf = x0 + dx;
            float wxx = dx ? wx : (1.f - wx);
            if (xf < 0.f || xf > 95.f) continue;
            acc = fmaf(pl[yi * 96 + (int)xf], wyy * wxx, acc);
        }
    }
    return acc;
}

__global__ void gsample_kernel(const float* __restrict__ cp, const float* __restrict__ sp,
                               const float* __restrict__ cr, float* __restrict__ p5o) {
    int idx = blockIdx.x * 256 + threadIdx.x;
    const int total = 8 * 256 * 96 * 96;
    if (idx >= total) return;
    int x = idx % 96;
    int y = (idx / 96) % 96;
    int c = (idx / 9216) % 256;
    int b = idx / (9216 * 256);
    int g = c >> 7;
    const float* crb = cr + (size_t)b * 10 * 9216;
    int pix = y * 96 + x;
    float offlx = crb[(2 * g) * 9216 + pix];
    float offly = crb[(2 * g + 1) * 9216 + pix];
    float offhx = crb[(4 + 2 * g) * 9216 + pix];
    float offhy = crb[(5 + 2 * g) * 9216 + pix];
    float bx = -1.f + x * (2.f / 95.f);
    float by = -1.f + y * (2.f / 95.f);
    const float* cpp = cp + (size_t)(b * 256 + c) * 9216;
    const float* spp = sp + (size_t)(b * 256 + c) * 9216;
    float cps = bsample(cpp, bx + offlx * (1.f / 96.f), by + offly * (1.f / 96.f));
    float sps = bsample(spp, bx + offhx * (1.f / 96.f), by + offhy * (1.f / 96.f));
    float att0 = 1.f + tanhf(crb[8 * 9216 + pix]);
    float att1 = 1.f + tanhf(crb[9 * 9216 + pix]);
    p5o[idx] = sps * att0 + cps * att1;
}

// ---------------------------------------------------------------------------
extern "C" void kernel_launch(void* const* d_in, const int* in_sizes, int n_in,
                              void* d_out, int out_size, void* d_ws, size_t ws_size,
                              hipStream_t stream) {
    const float* p3    = (const float*)d_in[0];
    const float* p5    = (const float*)d_in[1];
    const float* w_red = (const float*)d_in[2];
    const float* wq    = (const float*)d_in[3];
    const float* bq    = (const float*)d_in[4];
    const float* wk    = (const float*)d_in[5];
    const float* bk    = (const float*)d_in[6];
    const float* wv    = (const float*)d_in[7];
    const float* bv    = (const float*)d_in[8];
    const float* la_w1 = (const float*)d_in[9];
    const float* la_w2 = (const float*)d_in[10];
    const float* w32   = (const float*)d_in[11];
    const float* w8    = (const float*)d_in[12];
    const float* woff1 = (const float*)d_in[13];
    const float* woff2 = (const float*)d_in[14];

    float* out = (float*)d_out;
    float* p3o = out;                 // [8,512,24,24]  2359296
    float* p5o = out + 2359296;       // [8,256,96,96] 18874368

    float* ws = (float*)d_ws;
    float* x_   = ws + 0;             // 2359296
    float* ctx  = ws + 2359296;       // 2359296
    float* q    = ws + 4718592;       // 147456
    float* kf   = ws + 4866048;       // 204800
    float* km   = ws + 5070848;       // 12800
    float* vm   = ws + 5083648;       // 204800
    float* la1  = ws + 5288448;       // 294912
    float* sp24 = ws + 5583360;       // 1179648
    float* sp96 = ws + 6763008;       // 18874368
    float* cp   = ws + 25637376;      // 18874368
    unsigned short* wred_pk = (unsigned short*)(ws + 44511744); // 2424832 u16
    unsigned short* w32_pk  = (unsigned short*)(ws + 45724160); // 1212416 u16
    unsigned short* w8_pk   = (unsigned short*)(ws + 46330368); // 606208 u16
    // reuse (dead after p3o/sp24 phases):
    float* t64  = ws + 0;             // reuses x_/ctx (dead by K11)
    float* cr   = ws + 4718592;       // reuses q..la1 (dead by K12)

    // P0: pack weights to bf16 [chunk][co][296]
    pack_w_kernel<<<dim3((2424832 + 255) / 256), dim3(256), 0, stream>>>(w_red, wred_pk, 512, 512);
    pack_w_kernel<<<dim3((1212416 + 255) / 256), dim3(256), 0, stream>>>(w32, w32_pk, 512, 256);
    pack_w_kernel<<<dim3((606208 + 255) / 256), dim3(256), 0, stream>>>(w8, w8_pk, 256, 256);

    // K1: x = silu(conv3x3(p3, w_red)) 512->512, 24x24  [MFMA]
    conv3x3_mfma<8, 8, 1><<<dim3(8 * 3 * 3 * 8), dim3(256), 0, stream>>>(
        p3, wred_pk, x_, 8, 512, 512, 24, 24);
    // K2: q = conv1x1(x, wq) + bq
    matmul_bcm<0><<<dim3((8 * 32 * 576 + 255) / 256), dim3(256), 0, stream>>>(
        wq, bq, x_, q, 8, 512, 32, 576);
    // K3: kfeat = psp(x)
    psp_kernel<<<dim3(8 * 512), dim3(64), 0, stream>>>(x_, kf);
    // K4: k, v projections of kfeat
    matmul_bcm<0><<<dim3((8 * 32 * 50 + 255) / 256), dim3(256), 0, stream>>>(
        wk, bk, kf, km, 8, 512, 32, 50);
    matmul_bcm<0><<<dim3((8 * 512 * 50 + 255) / 256), dim3(256), 0, stream>>>(
        wv, bv, kf, vm, 8, 512, 512, 50);
    // K5: sim = softmax(q^T k); ctx = v sim^T
    attn_kernel<<<dim3(8 * 18), dim3(256), 0, stream>>>(q, km, vm, ctx);
    // K6: la1 = silu(conv1x1(ctx, la_w1))
    matmul_bcm<1><<<dim3((8 * 64 * 576 + 255) / 256), dim3(256), 0, stream>>>(
        la_w1, nullptr, ctx, la1, 8, 512, 64, 576);
    // K7: p3o = x + ctx*(1 + tanh(conv3x3(la1, la_w2)))  [direct f32]
    conv3x3_kernel<24, 24, 16, 4, 4, 2><<<dim3(8 * 32), dim3(576), 0, stream>>>(
        la1, la_w2, p3o, 8, 64, 512, 24, 24, ctx, x_);
    // K8: sp24 = silu(conv3x3(p3o, w32)) 512->256, 24x24  [MFMA]
    conv3x3_mfma<8, 8, 1><<<dim3(8 * 3 * 3 * 4), dim3(256), 0, stream>>>(
        p3o, w32_pk, sp24, 8, 512, 256, 24, 24);
    // K9: sp96 = bilinear upsample(sp24) 24->96
    upsample_kernel<<<dim3(8 * 256 * 9216 / 256), dim3(256), 0, stream>>>(sp24, sp96);
    // K10: cp = silu(conv3x3(p5, w8)) 256->256, 96x96  [MFMA, dominant]
    conv3x3_mfma<4, 16, 1><<<dim3(8 * 24 * 6 * 4), dim3(256), 0, stream>>>(
        p5, w8_pk, cp, 8, 256, 256, 96, 96);
    // K11: t64 = silu(conv1x1(concat[cp, sp96], woff1))
    conv1x1_cat_kernel<<<dim3(8 * 72), dim3(256), 0, stream>>>(cp, sp96, woff1, t64);
    // K12: cr = conv3x3(t64, woff2) 64->10 (no act)  [direct f32]
    conv3x3_kernel<16, 32, 12, 3, 4, 0><<<dim3(8 * 6 * 3 * 1), dim3(384), 0, stream>>>(
        t64, woff2, cr, 8, 64, 10, 96, 96, nullptr, nullptr);
    // K13: p5o = grid_sample blend
    gsample_kernel<<<dim3(8 * 256 * 9216 / 256), dim3(256), 0, stream>>>(
        cp, sp96, cr, p5o);
}

// Round 3
// 1297.315 us; speedup vs baseline: 3.0740x; 1.1450x over previous
//
#include <hip/hip_runtime.h>
#include <math.h>

#define DI __device__ __forceinline__

typedef __attribute__((ext_vector_type(8))) short bf16x8;
typedef __attribute__((ext_vector_type(4))) float f32x4;

DI float silu_f(float v) { return v / (1.f + __expf(-v)); }
DI float4 ld4(const float* p) { return *reinterpret_cast<const float4*>(p); }
DI void st4(float* p, const float4& v) { *reinterpret_cast<float4*>(p) = v; }
DI unsigned short f2bf(float f) {
    unsigned u = __float_as_uint(f);
    unsigned r = (u + 0x7FFFu + ((u >> 16) & 1u)) >> 16;
    return (unsigned short)r;
}

// ---------------------------------------------------------------------------
// Weight pre-pack: w f32 [Co][Ci][3][3] -> pk bf16 [Ci/32][Co][296]
// pk[ch][co][dydx*32+cc] = w[co][ch*32+cc][dydx]; slots 288..295 zero.
// ---------------------------------------------------------------------------
__global__ void pack_w_kernel(const float* __restrict__ w, unsigned short* __restrict__ pk,
                              int Ci, int Co) {
    int idx = blockIdx.x * 256 + threadIdx.x;
    int total = (Ci >> 5) * Co * 296;
    if (idx >= total) return;
    int e = idx % 296;
    int co = (idx / 296) % Co;
    int ch = idx / (296 * Co);
    unsigned short v = 0;
    if (e < 288) {
        int dydx = e >> 5;
        int cc = e & 31;
        v = f2bf(w[((size_t)co * Ci + (ch << 5) + cc) * 9 + dydx]);
    }
    pk[idx] = v;
}

// ---------------------------------------------------------------------------
// Input pre-pack: f32 NCHW -> bf16 [b][ci/32][H][W][32]
// ---------------------------------------------------------------------------
__global__ void pack_in_kernel(const float* __restrict__ in, unsigned short* __restrict__ pk,
                               int Ci, int HW, int total) {
    int idx = blockIdx.x * 256 + threadIdx.x;
    if (idx >= total) return;
    const int nCh = Ci >> 5;
    int cg = idx & 3;
    int t = idx >> 2;
    int pix = t % HW; t /= HW;
    int ch = t % nCh;
    int b = t / nCh;
    const float* src = in + ((size_t)b * Ci + (ch << 5) + (cg << 3)) * HW + pix;
    unsigned p[4];
#pragma unroll
    for (int j = 0; j < 4; ++j) {
        float v0 = src[(size_t)(2 * j) * HW];
        float v1 = src[(size_t)(2 * j + 1) * HW];
        p[j] = (unsigned)f2bf(v0) | ((unsigned)f2bf(v1) << 16);
    }
    *(uint4*)&pk[(((size_t)b * nCh + ch) * HW + pix) * 32 + (cg << 3)] =
        make_uint4(p[0], p[1], p[2], p[3]);
}

// ---------------------------------------------------------------------------
// MFMA implicit-GEMM 3x3 SAME conv. Input packed bf16, weights packed bf16,
// output f32 NCHW. Block: 64co x (4*BF*16)px, 4 waves, wave = 64co x BF*16px.
// FUSE: 0 none, 1 SiLU, 2 p3o epilogue (out = xres + ctx*(1+tanh(v))).
// Grid must be divisible by 8 (XCD swizzle, cog innermost).
// ---------------------------------------------------------------------------
template <int TH, int TW, int BF, int FUSE>
__global__ void __launch_bounds__(256)
conv3x3_mfma(const unsigned short* __restrict__ pin, const unsigned short* __restrict__ wpk,
             float* __restrict__ out, int B, int Ci, int Co, int H, int W,
             const float* __restrict__ ctx, const float* __restrict__ xres) {
    static_assert(TH * TW == 4 * BF * 16, "tile px = 4 waves * BF frags * 16");
    constexpr int TWH = TW + 2;
    constexpr int HP = (TH + 2) * TWH;
    __shared__ __align__(16) unsigned short lin[HP * 40];
    __shared__ __align__(16) unsigned short wls[64 * 296];

    const int nTx = W / TW, nTy = H / TH, nCoG = Co >> 6;
    const int nwg = gridDim.x;
    int wg = (blockIdx.x & 7) * (nwg >> 3) + (blockIdx.x >> 3);
    const int cog = wg % nCoG; wg /= nCoG;
    const int tx = wg % nTx;   wg /= nTx;
    const int ty = wg % nTy;
    const int b = wg / nTy;
    const int ox = tx * TW, oy = ty * TH, co0 = cog << 6;

    const int tid = threadIdx.x;
    const int wave = tid >> 6, lane = tid & 63;
    const int l15 = lane & 15, g = lane >> 4;
    const int wpx = wave * (BF * 16);

    int rr[BF], cc_[BF];
#pragma unroll
    for (int bf = 0; bf < BF; ++bf) {
        int px = wpx + bf * 16 + l15;
        rr[bf] = px / TW;
        cc_[bf] = px % TW;
    }

    f32x4 acc[4][BF];
#pragma unroll
    for (int af = 0; af < 4; ++af)
#pragma unroll
        for (int bf = 0; bf < BF; ++bf) acc[af][bf] = {};

    const int nCh = Ci >> 5;
    const size_t HWs = (size_t)H * W;

    for (int ch = 0; ch < nCh; ++ch) {
        // ---- stage input: HP px * 32cc, 16B (8cc) per thread-iter ----
#pragma unroll
        for (int it = 0; it < (HP * 4 + 255) / 256; ++it) {
            int e = tid + it * 256;
            if (e < HP * 4) {
                int cg = e & 3;
                int hp = e >> 2;
                int hy = hp / TWH, hx = hp % TWH;
                int gy = oy + hy - 1, gx = ox + hx - 1;
                uint4 v = make_uint4(0, 0, 0, 0);
                if ((unsigned)gy < (unsigned)H && (unsigned)gx < (unsigned)W)
                    v = *(const uint4*)&pin[(((size_t)b * nCh + ch) * H * W
                                            + (size_t)gy * W + gx) * 32 + (cg << 3)];
                *(uint4*)&lin[hp * 40 + (cg << 3)] = v;
            }
        }
        // ---- stage weights: 64co x 296 halfs = 2368 uint4 ----
        {
            const unsigned short* src = wpk + ((size_t)ch * Co + co0) * 296;
#pragma unroll
            for (int it = 0; it < 10; ++it) {
                int e = tid + it * 256;
                if (e < 2368) *(uint4*)&wls[e * 8] = *(const uint4*)&src[e * 8];
            }
        }
        __syncthreads();

        const unsigned short* wb = &wls[l15 * 296 + g * 8];
#pragma unroll
        for (int dy = 0; dy < 3; ++dy) {
#pragma unroll
            for (int dx = 0; dx < 3; ++dx) {
                const int dydx = dy * 3 + dx;
                bf16x8 a[4];
#pragma unroll
                for (int af = 0; af < 4; ++af)
                    a[af] = *(const bf16x8*)(wb + (af * 16) * 296 + dydx * 32);
                bf16x8 bb[BF];
#pragma unroll
                for (int bf = 0; bf < BF; ++bf)
                    bb[bf] = *(const bf16x8*)&lin[((rr[bf] + dy) * TWH + cc_[bf] + dx) * 40 + g * 8];
#pragma unroll
                for (int af = 0; af < 4; ++af)
#pragma unroll
                    for (int bf = 0; bf < BF; ++bf)
                        acc[af][bf] = __builtin_amdgcn_mfma_f32_16x16x32_bf16(
                            a[af], bb[bf], acc[af][bf], 0, 0, 0);
            }
        }
        __syncthreads();
    }
    // ---- epilogue: D col = lane&15 (px), row = 4*(lane>>4)+reg (co) ----
#pragma unroll
    for (int af = 0; af < 4; ++af) {
#pragma unroll
        for (int bf = 0; bf < BF; ++bf) {
            int px = wpx + bf * 16 + l15;
            int y = oy + px / TW, x = ox + px % TW;
#pragma unroll
            for (int r4 = 0; r4 < 4; ++r4) {
                int co = co0 + af * 16 + (g << 2) + r4;
                size_t base = ((size_t)b * Co + co) * HWs + (size_t)y * W + x;
                float v = acc[af][bf][r4];
                if (FUSE == 1) v = silu_f(v);
                else if (FUSE == 2) v = xres[base] + ctx[base] * (1.f + tanhf(v));
                out[base] = v;
            }
        }
    }
}

// ---------------------------------------------------------------------------
// Direct 3x3 SAME conv, f32 (kept for K12: 64->10).
// ---------------------------------------------------------------------------
template <int TH, int TW, int CO_BLK, int CO_T, int CIC, int FUSE>
__global__ void __launch_bounds__(576)
conv3x3_kernel(const float* __restrict__ in, const float* __restrict__ wgt,
               float* __restrict__ out, int B, int Ci, int Co, int H, int W,
               const float* __restrict__ ctx, const float* __restrict__ xres) {
    constexpr int TWH = TW + 2;
    constexpr int TWP = TW + 3;
    constexpr int SPAT = TH * (TW / 4);
    __shared__ float lin[CIC][TH + 2][TWP];
    __shared__ float wls[CIC][9][CO_BLK];

    const int nTx = W / TW, nTy = H / TH;
    const int nCoG = (Co + CO_BLK - 1) / CO_BLK;
    int bid = blockIdx.x;
    const int cog = bid % nCoG; bid /= nCoG;
    const int tx = bid % nTx;   bid /= nTx;
    const int ty = bid % nTy;
    const int b = bid / nTy;
    const int ox = tx * TW, oy = ty * TH;
    const int co0 = cog * CO_BLK;

    const int tid = threadIdx.x;
    const int cot = tid / SPAT;
    const int sp = tid % SPAT;
    const int r = sp / (TW / 4);
    const int cg = sp % (TW / 4);

    float acc[4][4];
#pragma unroll
    for (int i = 0; i < 4; ++i)
#pragma unroll
        for (int j = 0; j < 4; ++j) acc[i][j] = 0.f;

    for (int ci0 = 0; ci0 < Ci; ci0 += CIC) {
        for (int e = tid; e < CIC * (TH + 2) * TWH; e += SPAT * CO_T) {
            int xx = e % TWH;
            int yy = (e / TWH) % (TH + 2);
            int cc = e / (TWH * (TH + 2));
            int gy = oy - 1 + yy, gx = ox - 1 + xx;
            float v = 0.f;
            if (gy >= 0 && gy < H && gx >= 0 && gx < W)
                v = in[(((size_t)b * Ci + ci0 + cc) * H + gy) * W + gx];
            lin[cc][yy][xx] = v;
        }
        for (int e = tid; e < CIC * 9 * CO_BLK; e += SPAT * CO_T) {
            int col = e % CO_BLK;
            int k = (e / CO_BLK) % 9;
            int cc = e / (CO_BLK * 9);
            int co = co0 + col;
            float v = 0.f;
            if (co < Co) v = wgt[((size_t)co * Ci + ci0 + cc) * 9 + k];
            wls[cc][k][col] = v;
        }
        __syncthreads();
#pragma unroll
        for (int cc = 0; cc < CIC; ++cc) {
            float v0[3][6];
#pragma unroll
            for (int ky = 0; ky < 3; ++ky)
#pragma unroll
                for (int u = 0; u < 6; ++u)
                    v0[ky][u] = lin[cc][r + ky][cg * 4 + u];
#pragma unroll
            for (int ky = 0; ky < 3; ++ky)
#pragma unroll
                for (int kx = 0; kx < 3; ++kx) {
                    const float4 w4 = ld4(&wls[cc][ky * 3 + kx][cot * 4]);
                    const float wv_[4] = {w4.x, w4.y, w4.z, w4.w};
#pragma unroll
                    for (int i = 0; i < 4; ++i)
#pragma unroll
                        for (int j = 0; j < 4; ++j)
                            acc[i][j] = fmaf(wv_[i], v0[ky][kx + j], acc[i][j]);
                }
        }
        __syncthreads();
    }
    const int y = oy + r;
    const int xb = ox + cg * 4;
#pragma unroll
    for (int i = 0; i < 4; ++i) {
        int co = co0 + cot * 4 + i;
        if (co >= Co) continue;
        size_t base = (((size_t)b * Co + co) * H + y) * W + xb;
        float4 res;
        if (FUSE == 2) {
            float4 c4 = ld4(&ctx[base]);
            float4 x4 = ld4(&xres[base]);
            res.x = x4.x + c4.x * (1.f + tanhf(acc[i][0]));
            res.y = x4.y + c4.y * (1.f + tanhf(acc[i][1]));
            res.z = x4.z + c4.z * (1.f + tanhf(acc[i][2]));
            res.w = x4.w + c4.w * (1.f + tanhf(acc[i][3]));
        } else if (FUSE == 1) {
            res.x = silu_f(acc[i][0]); res.y = silu_f(acc[i][1]);
            res.z = silu_f(acc[i][2]); res.w = silu_f(acc[i][3]);
        } else {
            res.x = acc[i][0]; res.y = acc[i][1];
            res.z = acc[i][2]; res.w = acc[i][3];
        }
        st4(&out[base], res);
    }
}

// ---------------------------------------------------------------------------
// Batched GEMV: out[b][o][m] = act(sum_c W[o][c]*in[b][c][m] + bias[o])
// ---------------------------------------------------------------------------
template <int ACT>
__global__ void matmul_bcm(const float* __restrict__ W, const float* __restrict__ bias,
                           const float* __restrict__ in, float* __restrict__ out,
                           int B, int C, int O, int M) {
    long long idx = (long long)blockIdx.x * blockDim.x + threadIdx.x;
    long long total = (long long)B * O * M;
    if (idx >= total) return;
    int m = (int)(idx % M);
    int o = (int)((idx / M) % O);
    int b = (int)(idx / ((long long)M * O));
    const float* ip = in + (size_t)b * C * M + m;
    const float* wp = W + (size_t)o * C;
    float acc = bias ? bias[o] : 0.f;
    for (int c = 0; c < C; ++c) {
        acc = fmaf(wp[c], *ip, acc);
        ip += M;
    }
    if (ACT == 1) acc = silu_f(acc);
    out[idx] = acc;
}

// ---------------------------------------------------------------------------
__global__ void psp_kernel(const float* __restrict__ x, float* __restrict__ kf) {
    __shared__ float pl[576];
    int bc = blockIdx.x;
    const float* xp = x + (size_t)bc * 576;
    for (int e = threadIdx.x; e < 576; e += 64) pl[e] = xp[e];
    __syncthreads();
    int m = threadIdx.x;
    if (m < 50) {
        int g, i0;
        if (m < 36)      { g = 6; i0 = m; }
        else if (m < 45) { g = 3; i0 = m - 36; }
        else if (m < 49) { g = 2; i0 = m - 45; }
        else             { g = 1; i0 = 0; }
        int bs = 24 / g;
        int by = i0 / g, bx = i0 % g;
        float s = 0.f;
        for (int yy = 0; yy < bs; ++yy)
            for (int xx = 0; xx < bs; ++xx)
                s += pl[(by * bs + yy) * 24 + bx * bs + xx];
        kf[(size_t)bc * 50 + m] = s / (float)(bs * bs);
    }
}

// ---------------------------------------------------------------------------
__global__ void attn_kernel(const float* __restrict__ q, const float* __restrict__ k,
                            const float* __restrict__ v, float* __restrict__ ctx) {
    __shared__ float qs[32][33];
    __shared__ float ks[32][53];
    __shared__ float sim[32][53];
    int bidx = blockIdx.x;
    int b = bidx / 18;
    int n0 = (bidx % 18) * 32;
    int tid = threadIdx.x;
    for (int e = tid; e < 32 * 32; e += 256) {
        int c = e / 32, nl = e % 32;
        qs[c][nl] = q[((size_t)b * 32 + c) * 576 + n0 + nl];
    }
    for (int e = tid; e < 32 * 50; e += 256) {
        int c = e / 50, m = e % 50;
        ks[c][m] = k[((size_t)b * 32 + c) * 50 + m];
    }
    __syncthreads();
    for (int e = tid; e < 32 * 50; e += 256) {
        int nl = e / 50, m = e % 50;
        float s = 0.f;
        for (int c = 0; c < 32; ++c) s = fmaf(qs[c][nl], ks[c][m], s);
        sim[nl][m] = s;
    }
    __syncthreads();
    if (tid < 32) {
        float mx = -1e30f;
        for (int m = 0; m < 50; ++m) mx = fmaxf(mx, sim[tid][m]);
        float sum = 0.f;
        for (int m = 0; m < 50; ++m) {
            float e2 = __expf(sim[tid][m] - mx);
            sim[tid][m] = e2;
            sum += e2;
        }
        float inv = 1.f / sum;
        for (int m = 0; m < 50; ++m) sim[tid][m] *= inv;
    }
    __syncthreads();
    int nl = tid % 32, c0 = tid / 32;
    for (int c = c0; c < 512; c += 8) {
        const float* vp = v + ((size_t)b * 512 + c) * 50;
        float s = 0.f;
        for (int m = 0; m < 50; ++m) s = fmaf(vp[m], sim[nl][m], s);
        ctx[((size_t)b * 512 + c) * 576 + n0 + nl] = s;
    }
}

// ---------------------------------------------------------------------------
__global__ void __launch_bounds__(256)
conv1x1_cat_kernel(const float* __restrict__ cp, const float* __restrict__ sp,
                   const float* __restrict__ w, float* __restrict__ out) {
    __shared__ float ins[8][128];
    __shared__ float wls[8][64];
    int bid = blockIdx.x;
    int mt = bid % 72;
    int b = bid / 72;
    int m0 = mt * 128;
    int tid = threadIdx.x;
    int ml = (tid & 31) * 4;
    int col = (tid >> 5) * 8;
    float acc[8][4];
#pragma unroll
    for (int i = 0; i < 8; ++i)
#pragma unroll
        for (int j = 0; j < 4; ++j) acc[i][j] = 0.f;
    for (int c0 = 0; c0 < 512; c0 += 8) {
        {
            int e = tid * 4;
            int cl = e >> 7, mm = e & 127;
            int cidx = c0 + cl;
            const float* src = (cidx < 256)
                ? (cp + ((size_t)b * 256 + cidx) * 9216 + m0 + mm)
                : (sp + ((size_t)b * 256 + (cidx - 256)) * 9216 + m0 + mm);
            st4(&ins[cl][mm], ld4(src));
        }
        for (int e = tid; e < 512; e += 256) {
            int cl = e & 7;
            int o = e >> 3;
            wls[cl][o] = w[(size_t)o * 512 + c0 + cl];
        }
        __syncthreads();
#pragma unroll
        for (int cl = 0; cl < 8; ++cl) {
            float4 a4 = ld4(&ins[cl][ml]);
            float4 w0 = ld4(&wls[cl][col]);
            float4 w1 = ld4(&wls[cl][col + 4]);
            float av[4] = {a4.x, a4.y, a4.z, a4.w};
            float wv_[8] = {w0.x, w0.y, w0.z, w0.w, w1.x, w1.y, w1.z, w1.w};
#pragma unroll
            for (int oo = 0; oo < 8; ++oo)
#pragma unroll
                for (int j = 0; j < 4; ++j)
                    acc[oo][j] = fmaf(wv_[oo], av[j], acc[oo][j]);
        }
        __syncthreads();
    }
#pragma unroll
    for (int oo = 0; oo < 8; ++oo) {
        float4 r;
        r.x = silu_f(acc[oo][0]);
        r.y = silu_f(acc[oo][1]);
        r.z = silu_f(acc[oo][2]);
        r.w = silu_f(acc[oo][3]);
        st4(&out[((size_t)b * 64 + col + oo) * 9216 + m0 + ml], r);
    }
}

// ---------------------------------------------------------------------------
__global__ void upsample_kernel(const float* __restrict__ in, float* __restrict__ out) {
    int idx = blockIdx.x * 256 + threadIdx.x;
    const int total = 8 * 256 * 96 * 96;
    if (idx >= total) return;
    int x = idx % 96;
    int y = (idx / 96) % 96;
    int p = idx / 9216;
    float fy = y * (23.f / 95.f);
    float fx = x * (23.f / 95.f);
    int y0 = (int)fy; if (y0 > 22) y0 = 22;
    int x0 = (int)fx; if (x0 > 22) x0 = 22;
    float wy = fy - y0, wx = fx - x0;
    const float* ip = in + (size_t)p * 576;
    float a = ip[y0 * 24 + x0], b = ip[y0 * 24 + x0 + 1];
    float c = ip[(y0 + 1) * 24 + x0], d = ip[(y0 + 1) * 24 + x0 + 1];
    float l = a * (1.f - wy) + c * wy;
    float r = b * (1.f - wy) + d * wy;
    out[idx] = l * (1.f - wx) + r * wx;
}

// ---------------------------------------------------------------------------
DI float bsample(const float* __restrict__ pl, float gx, float gy) {
    float px = (gx + 1.f) * 47.5f;
    float py = (gy + 1.f) * 47.5f;
    float x0 = floorf(px), y0 = floorf(py);
    float wx = px - x0, wy = py - y0;
    float acc = 0.f;
#pragma unroll
    for (int dy = 0; dy < 2; ++dy) {
        float yf = y0 + dy;
        float wyy = dy ? wy : (1.f - wy);
        if (yf < 0.f || yf > 95.f) continue;
        int yi = (int)yf;
#pragma unroll
        for (int dx = 0; dx < 2; ++dx) {
            float xf = x0 + dx;
            float wxx = dx ? wx : (1.f - wx);
            if (xf < 0.f || xf > 95.f) continue;
            acc = fmaf(pl[yi * 96 + (int)xf], wyy * wxx, acc);
        }
    }
    return acc;
}

__global__ void gsample_kernel(const float* __restrict__ cp, const float* __restrict__ sp,
                               const float* __restrict__ cr, float* __restrict__ p5o) {
    int idx = blockIdx.x * 256 + threadIdx.x;
    const int total = 8 * 256 * 96 * 96;
    if (idx >= total) return;
    int x = idx % 96;
    int y = (idx / 96) % 96;
    int c = (idx / 9216) % 256;
    int b = idx / (9216 * 256);
    int g = c >> 7;
    const float* crb = cr + (size_t)b * 10 * 9216;
    int pix = y * 96 + x;
    float offlx = crb[(2 * g) * 9216 + pix];
    float offly = crb[(2 * g + 1) * 9216 + pix];
    float offhx = crb[(4 + 2 * g) * 9216 + pix];
    float offhy = crb[(5 + 2 * g) * 9216 + pix];
    float bx = -1.f + x * (2.f / 95.f);
    float by = -1.f + y * (2.f / 95.f);
    const float* cpp = cp + (size_t)(b * 256 + c) * 9216;
    const float* spp = sp + (size_t)(b * 256 + c) * 9216;
    float cps = bsample(cpp, bx + offlx * (1.f / 96.f), by + offly * (1.f / 96.f));
    float sps = bsample(spp, bx + offhx * (1.f / 96.f), by + offhy * (1.f / 96.f));
    float att0 = 1.f + tanhf(crb[8 * 9216 + pix]);
    float att1 = 1.f + tanhf(crb[9 * 9216 + pix]);
    p5o[idx] = sps * att0 + cps * att1;
}

// ---------------------------------------------------------------------------
extern "C" void kernel_launch(void* const* d_in, const int* in_sizes, int n_in,
                              void* d_out, int out_size, void* d_ws, size_t ws_size,
                              hipStream_t stream) {
    const float* p3    = (const float*)d_in[0];
    const float* p5    = (const float*)d_in[1];
    const float* w_red = (const float*)d_in[2];
    const float* wq    = (const float*)d_in[3];
    const float* bq    = (const float*)d_in[4];
    const float* wk    = (const float*)d_in[5];
    const float* bk    = (const float*)d_in[6];
    const float* wv    = (const float*)d_in[7];
    const float* bv    = (const float*)d_in[8];
    const float* la_w1 = (const float*)d_in[9];
    const float* la_w2 = (const float*)d_in[10];
    const float* w32   = (const float*)d_in[11];
    const float* w8    = (const float*)d_in[12];
    const float* woff1 = (const float*)d_in[13];
    const float* woff2 = (const float*)d_in[14];

    float* out = (float*)d_out;
    float* p3o = out;                 // [8,512,24,24]
    float* p5o = out + 2359296;       // [8,256,96,96]

    float* ws = (float*)d_ws;
    float* x_   = ws + 0;             // 2359296
    float* ctx  = ws + 2359296;       // 2359296
    float* q    = ws + 4718592;       // 147456
    float* kf   = ws + 4866048;       // 204800
    float* km   = ws + 5070848;       // 12800
    float* vm   = ws + 5083648;       // 204800
    float* la1  = ws + 5288448;       // 294912
    float* sp24 = ws + 5583360;       // 1179648
    float* sp96 = ws + 6763008;       // 18874368
    float* cp   = ws + 25637376;      // 18874368
    unsigned short* wred_pk = (unsigned short*)(ws + 44511744); // 2424832 u16
    unsigned short* w32_pk  = (unsigned short*)(ws + 45724160); // 1212416 u16
    unsigned short* w8_pk   = (unsigned short*)(ws + 46330368); // 606208 u16
    // Packed activations live INSIDE the sp96 region (all dead before K9
    // writes sp96): p5_pk + p3_pk(/p3o_pk) + la1_pk + wla2_pk.
    unsigned short* p5_pk   = (unsigned short*)(ws + 6763008);  // 18874368 u16
    unsigned short* p3_pk   = (unsigned short*)(ws + 16200192); // 2359296 u16 (reused as p3o_pk)
    unsigned short* la1_pk  = (unsigned short*)(ws + 17379840); // 294912 u16
    unsigned short* wla2_pk = (unsigned short*)(ws + 17527296); // 303104 u16
    // reuse (dead after p3o phase):
    float* t64  = ws + 0;             // spans x_/ctx (dead by K11)
    float* cr   = ws + 4718592;       // spans q..la1 (dead by K12)

    // P0: pack weights
    pack_w_kernel<<<dim3((2424832 + 255) / 256), dim3(256), 0, stream>>>(w_red, wred_pk, 512, 512);
    pack_w_kernel<<<dim3((1212416 + 255) / 256), dim3(256), 0, stream>>>(w32, w32_pk, 512, 256);
    pack_w_kernel<<<dim3((606208 + 255) / 256), dim3(256), 0, stream>>>(w8, w8_pk, 256, 256);
    pack_w_kernel<<<dim3((303104 + 255) / 256), dim3(256), 0, stream>>>(la_w2, wla2_pk, 64, 512);
    // P1: pack inputs
    pack_in_kernel<<<dim3(2359296 / 256), dim3(256), 0, stream>>>(p5, p5_pk, 256, 9216, 2359296);
    pack_in_kernel<<<dim3(294912 / 256), dim3(256), 0, stream>>>(p3, p3_pk, 512, 576, 294912);

    // K10: cp = silu(conv3x3(p5, w8)) 256->256, 96x96  [MFMA, dominant]
    conv3x3_mfma<8, 16, 2, 1><<<dim3(2304), dim3(256), 0, stream>>>(
        p5_pk, w8_pk, cp, 8, 256, 256, 96, 96, nullptr, nullptr);
    // K1: x = silu(conv3x3(p3, w_red)) 512->512, 24x24  [MFMA]
    conv3x3_mfma<8, 24, 3, 1><<<dim3(192), dim3(256), 0, stream>>>(
        p3_pk, wred_pk, x_, 8, 512, 512, 24, 24, nullptr, nullptr);
    // K2: q = conv1x1(x, wq) + bq
    matmul_bcm<0><<<dim3((8 * 32 * 576 + 255) / 256), dim3(256), 0, stream>>>(
        wq, bq, x_, q, 8, 512, 32, 576);
    // K3: kfeat = psp(x)
    psp_kernel<<<dim3(8 * 512), dim3(64), 0, stream>>>(x_, kf);
    // K4: k, v projections
    matmul_bcm<0><<<dim3((8 * 32 * 50 + 255) / 256), dim3(256), 0, stream>>>(
        wk, bk, kf, km, 8, 512, 32, 50);
    matmul_bcm<0><<<dim3((8 * 512 * 50 + 255) / 256), dim3(256), 0, stream>>>(
        wv, bv, kf, vm, 8, 512, 512, 50);
    // K5: attention
    attn_kernel<<<dim3(8 * 18), dim3(256), 0, stream>>>(q, km, vm, ctx);
    // K6: la1 = silu(conv1x1(ctx, la_w1))
    matmul_bcm<1><<<dim3((8 * 64 * 576 + 255) / 256), dim3(256), 0, stream>>>(
        la_w1, nullptr, ctx, la1, 8, 512, 64, 576);
    // pack la1 (64 ci)
    pack_in_kernel<<<dim3(36864 / 256), dim3(256), 0, stream>>>(la1, la1_pk, 64, 576, 36864);
    // K7: p3o = x + ctx*(1 + tanh(conv3x3(la1, la_w2)))  [MFMA FUSE2]
    conv3x3_mfma<8, 24, 3, 2><<<dim3(192), dim3(256), 0, stream>>>(
        la1_pk, wla2_pk, p3o, 8, 64, 512, 24, 24, ctx, x_);
    // pack p3o (reuses p3_pk region)
    pack_in_kernel<<<dim3(294912 / 256), dim3(256), 0, stream>>>(p3o, p3_pk, 512, 576, 294912);
    // K8: sp24 = silu(conv3x3(p3o, w32)) 512->256  [MFMA]
    conv3x3_mfma<8, 24, 3, 1><<<dim3(96), dim3(256), 0, stream>>>(
        p3_pk, w32_pk, sp24, 8, 512, 256, 24, 24, nullptr, nullptr);
    // K9: sp96 = bilinear upsample (overwrites packed-buffer region)
    upsample_kernel<<<dim3(8 * 256 * 9216 / 256), dim3(256), 0, stream>>>(sp24, sp96);
    // K11: t64 = silu(conv1x1(concat[cp, sp96], woff1))
    conv1x1_cat_kernel<<<dim3(8 * 72), dim3(256), 0, stream>>>(cp, sp96, woff1, t64);
    // K12: cr = conv3x3(t64, woff2) 64->10
    conv3x3_kernel<16, 32, 12, 3, 4, 0><<<dim3(8 * 6 * 3 * 1), dim3(384), 0, stream>>>(
        t64, woff2, cr, 8, 64, 10, 96, 96, nullptr, nullptr);
    // K13: p5o = grid_sample blend
    gsample_kernel<<<dim3(8 * 256 * 9216 / 256), dim3(256), 0, stream>>>(
        cp, sp96, cr, p5o);
}

// Round 4
// 1237.294 us; speedup vs baseline: 3.2231x; 1.0485x over previous
//
#include <hip/hip_runtime.h>
#include <math.h>

#define DI __device__ __forceinline__

typedef __attribute__((ext_vector_type(8))) short bf16x8;
typedef __attribute__((ext_vector_type(4))) float f32x4;

DI float silu_f(float v) { return v / (1.f + __expf(-v)); }
DI float4 ld4(const float* p) { return *reinterpret_cast<const float4*>(p); }
DI void st4(float* p, const float4& v) { *reinterpret_cast<float4*>(p) = v; }
DI unsigned short f2bf(float f) {
    unsigned u = __float_as_uint(f);
    unsigned r = (u + 0x7FFFu + ((u >> 16) & 1u)) >> 16;
    return (unsigned short)r;
}

// ---------------------------------------------------------------------------
// Weight pre-pack: w f32 [Co][Ci][3][3] -> pk bf16 [Ci/32][Co][296]
// ---------------------------------------------------------------------------
__global__ void pack_w_kernel(const float* __restrict__ w, unsigned short* __restrict__ pk,
                              int Ci, int Co) {
    int idx = blockIdx.x * 256 + threadIdx.x;
    int total = (Ci >> 5) * Co * 296;
    if (idx >= total) return;
    int e = idx % 296;
    int co = (idx / 296) % Co;
    int ch = idx / (296 * Co);
    unsigned short v = 0;
    if (e < 288) {
        int dydx = e >> 5;
        int cc = e & 31;
        v = f2bf(w[((size_t)co * Ci + (ch << 5) + cc) * 9 + dydx]);
    }
    pk[idx] = v;
}

// ---------------------------------------------------------------------------
// Input pre-pack: f32 NCHW -> bf16 [b][ci/32][H][W][32]
// ---------------------------------------------------------------------------
__global__ void pack_in_kernel(const float* __restrict__ in, unsigned short* __restrict__ pk,
                               int Ci, int HW, int total) {
    int idx = blockIdx.x * 256 + threadIdx.x;
    if (idx >= total) return;
    const int nCh = Ci >> 5;
    int cg = idx & 3;
    int t = idx >> 2;
    int pix = t % HW; t /= HW;
    int ch = t % nCh;
    int b = t / nCh;
    const float* src = in + ((size_t)b * Ci + (ch << 5) + (cg << 3)) * HW + pix;
    unsigned p[4];
#pragma unroll
    for (int j = 0; j < 4; ++j) {
        float v0 = src[(size_t)(2 * j) * HW];
        float v1 = src[(size_t)(2 * j + 1) * HW];
        p[j] = (unsigned)f2bf(v0) | ((unsigned)f2bf(v1) << 16);
    }
    *(uint4*)&pk[(((size_t)b * nCh + ch) * HW + pix) * 32 + (cg << 3)] =
        make_uint4(p[0], p[1], p[2], p[3]);
}

// ---------------------------------------------------------------------------
// MFMA implicit-GEMM 3x3 SAME conv (unchanged from round 3).
// ---------------------------------------------------------------------------
template <int TH, int TW, int BF, int FUSE>
__global__ void __launch_bounds__(256)
conv3x3_mfma(const unsigned short* __restrict__ pin, const unsigned short* __restrict__ wpk,
             float* __restrict__ out, int B, int Ci, int Co, int H, int W,
             const float* __restrict__ ctx, const float* __restrict__ xres) {
    static_assert(TH * TW == 4 * BF * 16, "tile px = 4 waves * BF frags * 16");
    constexpr int TWH = TW + 2;
    constexpr int HP = (TH + 2) * TWH;
    __shared__ __align__(16) unsigned short lin[HP * 40];
    __shared__ __align__(16) unsigned short wls[64 * 296];

    const int nTx = W / TW, nTy = H / TH, nCoG = Co >> 6;
    const int nwg = gridDim.x;
    int wg = (blockIdx.x & 7) * (nwg >> 3) + (blockIdx.x >> 3);
    const int cog = wg % nCoG; wg /= nCoG;
    const int tx = wg % nTx;   wg /= nTx;
    const int ty = wg % nTy;
    const int b = wg / nTy;
    const int ox = tx * TW, oy = ty * TH, co0 = cog << 6;

    const int tid = threadIdx.x;
    const int wave = tid >> 6, lane = tid & 63;
    const int l15 = lane & 15, g = lane >> 4;
    const int wpx = wave * (BF * 16);

    int rr[BF], cc_[BF];
#pragma unroll
    for (int bf = 0; bf < BF; ++bf) {
        int px = wpx + bf * 16 + l15;
        rr[bf] = px / TW;
        cc_[bf] = px % TW;
    }

    f32x4 acc[4][BF];
#pragma unroll
    for (int af = 0; af < 4; ++af)
#pragma unroll
        for (int bf = 0; bf < BF; ++bf) acc[af][bf] = {};

    const int nCh = Ci >> 5;
    const size_t HWs = (size_t)H * W;

    for (int ch = 0; ch < nCh; ++ch) {
#pragma unroll
        for (int it = 0; it < (HP * 4 + 255) / 256; ++it) {
            int e = tid + it * 256;
            if (e < HP * 4) {
                int cg = e & 3;
                int hp = e >> 2;
                int hy = hp / TWH, hx = hp % TWH;
                int gy = oy + hy - 1, gx = ox + hx - 1;
                uint4 v = make_uint4(0, 0, 0, 0);
                if ((unsigned)gy < (unsigned)H && (unsigned)gx < (unsigned)W)
                    v = *(const uint4*)&pin[(((size_t)b * nCh + ch) * H * W
                                            + (size_t)gy * W + gx) * 32 + (cg << 3)];
                *(uint4*)&lin[hp * 40 + (cg << 3)] = v;
            }
        }
        {
            const unsigned short* src = wpk + ((size_t)ch * Co + co0) * 296;
#pragma unroll
            for (int it = 0; it < 10; ++it) {
                int e = tid + it * 256;
                if (e < 2368) *(uint4*)&wls[e * 8] = *(const uint4*)&src[e * 8];
            }
        }
        __syncthreads();

        const unsigned short* wb = &wls[l15 * 296 + g * 8];
#pragma unroll
        for (int dy = 0; dy < 3; ++dy) {
#pragma unroll
            for (int dx = 0; dx < 3; ++dx) {
                const int dydx = dy * 3 + dx;
                bf16x8 a[4];
#pragma unroll
                for (int af = 0; af < 4; ++af)
                    a[af] = *(const bf16x8*)(wb + (af * 16) * 296 + dydx * 32);
                bf16x8 bb[BF];
#pragma unroll
                for (int bf = 0; bf < BF; ++bf)
                    bb[bf] = *(const bf16x8*)&lin[((rr[bf] + dy) * TWH + cc_[bf] + dx) * 40 + g * 8];
#pragma unroll
                for (int af = 0; af < 4; ++af)
#pragma unroll
                    for (int bf = 0; bf < BF; ++bf)
                        acc[af][bf] = __builtin_amdgcn_mfma_f32_16x16x32_bf16(
                            a[af], bb[bf], acc[af][bf], 0, 0, 0);
            }
        }
        __syncthreads();
    }
#pragma unroll
    for (int af = 0; af < 4; ++af) {
#pragma unroll
        for (int bf = 0; bf < BF; ++bf) {
            int px = wpx + bf * 16 + l15;
            int y = oy + px / TW, x = ox + px % TW;
#pragma unroll
            for (int r4 = 0; r4 < 4; ++r4) {
                int co = co0 + af * 16 + (g << 2) + r4;
                size_t base = ((size_t)b * Co + co) * HWs + (size_t)y * W + x;
                float v = acc[af][bf][r4];
                if (FUSE == 1) v = silu_f(v);
                else if (FUSE == 2) v = xres[base] + ctx[base] * (1.f + tanhf(v));
                out[base] = v;
            }
        }
    }
}

// ---------------------------------------------------------------------------
// Direct 3x3 SAME conv, f32 (K12: 64->10).
// ---------------------------------------------------------------------------
template <int TH, int TW, int CO_BLK, int CO_T, int CIC, int FUSE>
__global__ void __launch_bounds__(576)
conv3x3_kernel(const float* __restrict__ in, const float* __restrict__ wgt,
               float* __restrict__ out, int B, int Ci, int Co, int H, int W,
               const float* __restrict__ ctx, const float* __restrict__ xres) {
    constexpr int TWH = TW + 2;
    constexpr int TWP = TW + 3;
    constexpr int SPAT = TH * (TW / 4);
    __shared__ float lin[CIC][TH + 2][TWP];
    __shared__ float wls[CIC][9][CO_BLK];

    const int nTx = W / TW, nTy = H / TH;
    const int nCoG = (Co + CO_BLK - 1) / CO_BLK;
    int bid = blockIdx.x;
    const int cog = bid % nCoG; bid /= nCoG;
    const int tx = bid % nTx;   bid /= nTx;
    const int ty = bid % nTy;
    const int b = bid / nTy;
    const int ox = tx * TW, oy = ty * TH;
    const int co0 = cog * CO_BLK;

    const int tid = threadIdx.x;
    const int cot = tid / SPAT;
    const int sp = tid % SPAT;
    const int r = sp / (TW / 4);
    const int cg = sp % (TW / 4);

    float acc[4][4];
#pragma unroll
    for (int i = 0; i < 4; ++i)
#pragma unroll
        for (int j = 0; j < 4; ++j) acc[i][j] = 0.f;

    for (int ci0 = 0; ci0 < Ci; ci0 += CIC) {
        for (int e = tid; e < CIC * (TH + 2) * TWH; e += SPAT * CO_T) {
            int xx = e % TWH;
            int yy = (e / TWH) % (TH + 2);
            int cc = e / (TWH * (TH + 2));
            int gy = oy - 1 + yy, gx = ox - 1 + xx;
            float v = 0.f;
            if (gy >= 0 && gy < H && gx >= 0 && gx < W)
                v = in[(((size_t)b * Ci + ci0 + cc) * H + gy) * W + gx];
            lin[cc][yy][xx] = v;
        }
        for (int e = tid; e < CIC * 9 * CO_BLK; e += SPAT * CO_T) {
            int col = e % CO_BLK;
            int k = (e / CO_BLK) % 9;
            int cc = e / (CO_BLK * 9);
            int co = co0 + col;
            float v = 0.f;
            if (co < Co) v = wgt[((size_t)co * Ci + ci0 + cc) * 9 + k];
            wls[cc][k][col] = v;
        }
        __syncthreads();
#pragma unroll
        for (int cc = 0; cc < CIC; ++cc) {
            float v0[3][6];
#pragma unroll
            for (int ky = 0; ky < 3; ++ky)
#pragma unroll
                for (int u = 0; u < 6; ++u)
                    v0[ky][u] = lin[cc][r + ky][cg * 4 + u];
#pragma unroll
            for (int ky = 0; ky < 3; ++ky)
#pragma unroll
                for (int kx = 0; kx < 3; ++kx) {
                    const float4 w4 = ld4(&wls[cc][ky * 3 + kx][cot * 4]);
                    const float wv_[4] = {w4.x, w4.y, w4.z, w4.w};
#pragma unroll
                    for (int i = 0; i < 4; ++i)
#pragma unroll
                        for (int j = 0; j < 4; ++j)
                            acc[i][j] = fmaf(wv_[i], v0[ky][kx + j], acc[i][j]);
                }
        }
        __syncthreads();
    }
    const int y = oy + r;
    const int xb = ox + cg * 4;
#pragma unroll
    for (int i = 0; i < 4; ++i) {
        int co = co0 + cot * 4 + i;
        if (co >= Co) continue;
        size_t base = (((size_t)b * Co + co) * H + y) * W + xb;
        float4 res;
        if (FUSE == 2) {
            float4 c4 = ld4(&ctx[base]);
            float4 x4 = ld4(&xres[base]);
            res.x = x4.x + c4.x * (1.f + tanhf(acc[i][0]));
            res.y = x4.y + c4.y * (1.f + tanhf(acc[i][1]));
            res.z = x4.z + c4.z * (1.f + tanhf(acc[i][2]));
            res.w = x4.w + c4.w * (1.f + tanhf(acc[i][3]));
        } else if (FUSE == 1) {
            res.x = silu_f(acc[i][0]); res.y = silu_f(acc[i][1]);
            res.z = silu_f(acc[i][2]); res.w = silu_f(acc[i][3]);
        } else {
            res.x = acc[i][0]; res.y = acc[i][1];
            res.z = acc[i][2]; res.w = acc[i][3];
        }
        st4(&out[base], res);
    }
}

// ---------------------------------------------------------------------------
// Batched GEMV: out[b][o][m] = act(sum_c W[o][c]*in[b][c][m] + bias[o])
// ---------------------------------------------------------------------------
template <int ACT>
__global__ void matmul_bcm(const float* __restrict__ W, const float* __restrict__ bias,
                           const float* __restrict__ in, float* __restrict__ out,
                           int B, int C, int O, int M) {
    long long idx = (long long)blockIdx.x * blockDim.x + threadIdx.x;
    long long total = (long long)B * O * M;
    if (idx >= total) return;
    int m = (int)(idx % M);
    int o = (int)((idx / M) % O);
    int b = (int)(idx / ((long long)M * O));
    const float* ip = in + (size_t)b * C * M + m;
    const float* wp = W + (size_t)o * C;
    float acc = bias ? bias[o] : 0.f;
    for (int c = 0; c < C; ++c) {
        acc = fmaf(wp[c], *ip, acc);
        ip += M;
    }
    if (ACT == 1) acc = silu_f(acc);
    out[idx] = acc;
}

// ---------------------------------------------------------------------------
__global__ void psp_kernel(const float* __restrict__ x, float* __restrict__ kf) {
    __shared__ float pl[576];
    int bc = blockIdx.x;
    const float* xp = x + (size_t)bc * 576;
    for (int e = threadIdx.x; e < 576; e += 64) pl[e] = xp[e];
    __syncthreads();
    int m = threadIdx.x;
    if (m < 50) {
        int g, i0;
        if (m < 36)      { g = 6; i0 = m; }
        else if (m < 45) { g = 3; i0 = m - 36; }
        else if (m < 49) { g = 2; i0 = m - 45; }
        else             { g = 1; i0 = 0; }
        int bs = 24 / g;
        int by = i0 / g, bx = i0 % g;
        float s = 0.f;
        for (int yy = 0; yy < bs; ++yy)
            for (int xx = 0; xx < bs; ++xx)
                s += pl[(by * bs + yy) * 24 + bx * bs + xx];
        kf[(size_t)bc * 50 + m] = s / (float)(bs * bs);
    }
}

// ---------------------------------------------------------------------------
// sim = softmax(q^T k): block = (b, 64 n's). simg [b][576][50]
// ---------------------------------------------------------------------------
__global__ void __launch_bounds__(256)
sim_kernel(const float* __restrict__ q, const float* __restrict__ k,
           float* __restrict__ simg) {
    __shared__ float qs[32][65];
    __shared__ float ks[32][52];
    __shared__ float sm[64][52];
    int b = blockIdx.x / 9, n0 = (blockIdx.x % 9) * 64;
    int tid = threadIdx.x;
    for (int e = tid; e < 32 * 64; e += 256) {
        int c = e >> 6, n = e & 63;
        qs[c][n] = q[((size_t)b * 32 + c) * 576 + n0 + n];
    }
    for (int e = tid; e < 32 * 50; e += 256) {
        int c = e / 50, m = e % 50;
        ks[c][m] = k[((size_t)b * 32 + c) * 50 + m];
    }
    __syncthreads();
    for (int e = tid; e < 64 * 50; e += 256) {
        int n = e / 50, m = e % 50;
        float s = 0.f;
#pragma unroll
        for (int c = 0; c < 32; ++c) s = fmaf(qs[c][n], ks[c][m], s);
        sm[n][m] = s;
    }
    __syncthreads();
    if (tid < 64) {
        float mx = -1e30f;
        for (int m = 0; m < 50; ++m) mx = fmaxf(mx, sm[tid][m]);
        float sum = 0.f;
        for (int m = 0; m < 50; ++m) {
            float e2 = __expf(sm[tid][m] - mx);
            sm[tid][m] = e2;
            sum += e2;
        }
        float inv = 1.f / sum;
        for (int m = 0; m < 50; ++m) sm[tid][m] *= inv;
    }
    __syncthreads();
    for (int e = tid; e < 64 * 50; e += 256) {
        int n = e / 50, m = e % 50;
        simg[((size_t)b * 576 + n0 + n) * 50 + m] = sm[n][m];
    }
}

// ---------------------------------------------------------------------------
// ctx[b][c][n] = sum_m v[b][c][m] * sim[b][n][m]. Block = 128c x 64n.
// ---------------------------------------------------------------------------
__global__ void __launch_bounds__(256)
ctx_kernel(const float* __restrict__ v, const float* __restrict__ simg,
           float* __restrict__ ctx) {
    __shared__ float vs[128][54];
    __shared__ float ss[64][54];
    int blk = blockIdx.x;
    int ct = blk & 3; blk >>= 2;
    int nt = blk % 9;
    int b = blk / 9;
    int c0 = ct * 128, n0 = nt * 64;
    int tid = threadIdx.x;
    for (int e = tid; e < 128 * 50; e += 256) {
        int c = e / 50, m = e % 50;
        vs[c][m] = v[((size_t)b * 512 + c0 + c) * 50 + m];
    }
    for (int e = tid; e < 64 * 50; e += 256) {
        int n = e / 50, m = e % 50;
        ss[n][m] = simg[((size_t)b * 576 + n0 + n) * 50 + m];
    }
    __syncthreads();
    int n_t = tid & 15;       // 16 n-lanes; n = n0 + j*16 + n_t
    int c_t = tid >> 4;       // 16 c-groups of 8; c = c0 + c_t*8 + i
    float acc[8][4];
#pragma unroll
    for (int i = 0; i < 8; ++i)
#pragma unroll
        for (int j = 0; j < 4; ++j) acc[i][j] = 0.f;
    for (int m = 0; m < 50; ++m) {
        float sv[4];
#pragma unroll
        for (int j = 0; j < 4; ++j) sv[j] = ss[j * 16 + n_t][m];
#pragma unroll
        for (int i = 0; i < 8; ++i) {
            float vv = vs[c_t * 8 + i][m];
#pragma unroll
            for (int j = 0; j < 4; ++j) acc[i][j] = fmaf(vv, sv[j], acc[i][j]);
        }
    }
#pragma unroll
    for (int i = 0; i < 8; ++i)
#pragma unroll
        for (int j = 0; j < 4; ++j)
            ctx[((size_t)b * 512 + c0 + c_t * 8 + i) * 576 + n0 + j * 16 + n_t] = acc[i][j];
}

// ---------------------------------------------------------------------------
// 1x1 conv on concat [cp; sp] (512 -> 64) + SiLU. Tile 64co x 128m.
// ---------------------------------------------------------------------------
__global__ void __launch_bounds__(256)
conv1x1_cat_kernel(const float* __restrict__ cp, const float* __restrict__ sp,
                   const float* __restrict__ w, float* __restrict__ out) {
    __shared__ float ins[8][128];
    __shared__ float wls[8][64];
    int bid = blockIdx.x;
    int mt = bid % 72;
    int b = bid / 72;
    int m0 = mt * 128;
    int tid = threadIdx.x;
    int ml = tid & 31;            // m = m0 + ml + 32*j
    int col = (tid >> 5) * 8;     // 8 co per thread
    float acc[8][4];
#pragma unroll
    for (int i = 0; i < 8; ++i)
#pragma unroll
        for (int j = 0; j < 4; ++j) acc[i][j] = 0.f;
    for (int c0 = 0; c0 < 512; c0 += 8) {
        {
            int e = tid * 4;
            int cl = e >> 7, mm = e & 127;
            int cidx = c0 + cl;
            const float* src = (cidx < 256)
                ? (cp + ((size_t)b * 256 + cidx) * 9216 + m0 + mm)
                : (sp + ((size_t)b * 256 + (cidx - 256)) * 9216 + m0 + mm);
            st4(&ins[cl][mm], ld4(src));
        }
        for (int e = tid; e < 512; e += 256) {
            int cl = e & 7;
            int o = e >> 3;
            wls[cl][o] = w[(size_t)o * 512 + c0 + cl];
        }
        __syncthreads();
#pragma unroll
        for (int cl = 0; cl < 8; ++cl) {
            float4 w0 = ld4(&wls[cl][col]);
            float4 w1 = ld4(&wls[cl][col + 4]);
            float av[4];
#pragma unroll
            for (int j = 0; j < 4; ++j) av[j] = ins[cl][ml + 32 * j];
            float wv_[8] = {w0.x, w0.y, w0.z, w0.w, w1.x, w1.y, w1.z, w1.w};
#pragma unroll
            for (int oo = 0; oo < 8; ++oo)
#pragma unroll
                for (int j = 0; j < 4; ++j)
                    acc[oo][j] = fmaf(wv_[oo], av[j], acc[oo][j]);
        }
        __syncthreads();
    }
#pragma unroll
    for (int oo = 0; oo < 8; ++oo)
#pragma unroll
        for (int j = 0; j < 4; ++j)
            out[((size_t)b * 64 + col + oo) * 9216 + m0 + ml + 32 * j] = silu_f(acc[oo][j]);
}

// ---------------------------------------------------------------------------
__global__ void upsample_kernel(const float* __restrict__ in, float* __restrict__ out) {
    int idx = blockIdx.x * 256 + threadIdx.x;
    const int total = 8 * 256 * 96 * 96;
    if (idx >= total) return;
    int x = idx % 96;
    int y = (idx / 96) % 96;
    int p = idx / 9216;
    float fy = y * (23.f / 95.f);
    float fx = x * (23.f / 95.f);
    int y0 = (int)fy; if (y0 > 22) y0 = 22;
    int x0 = (int)fx; if (x0 > 22) x0 = 22;
    float wy = fy - y0, wx = fx - x0;
    const float* ip = in + (size_t)p * 576;
    float a = ip[y0 * 24 + x0], b = ip[y0 * 24 + x0 + 1];
    float c = ip[(y0 + 1) * 24 + x0], d = ip[(y0 + 1) * 24 + x0 + 1];
    float l = a * (1.f - wy) + c * wy;
    float r = b * (1.f - wy) + d * wy;
    out[idx] = l * (1.f - wx) + r * wx;
}

// ---------------------------------------------------------------------------
// grid_sample prep: per (b,g,pix) compute tap indices/weights; per (b,pix) att.
// streams: 0=cp g0, 1=cp g1, 2=sp g0, 3=sp g1. Layout [stream][b][pix].
// ---------------------------------------------------------------------------
DI void gs_params(int x, int y, float ox, float oy, float4* w, int2* p) {
    const float S = 47.5f / 96.f;
    float px = x + ox * S;
    float py = y + oy * S;
    float fx0 = floorf(px), fy0 = floorf(py);
    float wx = px - fx0, wy = py - fy0;
    float vx0 = (fx0 >= 0.f && fx0 <= 95.f) ? 1.f : 0.f;
    float vx1 = (fx0 >= -1.f && fx0 <= 94.f) ? 1.f : 0.f;
    float vy0 = (fy0 >= 0.f && fy0 <= 95.f) ? 1.f : 0.f;
    float vy1 = (fy0 >= -1.f && fy0 <= 94.f) ? 1.f : 0.f;
    int x0 = (int)fminf(fmaxf(fx0, 0.f), 95.f);
    int x1 = (int)fminf(fmaxf(fx0 + 1.f, 0.f), 95.f);
    int y0 = (int)fminf(fmaxf(fy0, 0.f), 95.f);
    int y1 = (int)fminf(fmaxf(fy0 + 1.f, 0.f), 95.f);
    w->x = (1.f - wx) * (1.f - wy) * vx0 * vy0;
    w->y = wx * (1.f - wy) * vx1 * vy0;
    w->z = (1.f - wx) * wy * vx0 * vy1;
    w->w = wx * wy * vx1 * vy1;
    *p = make_int2(x0 | (x1 << 16), y0 | (y1 << 16));
}

__global__ void gprep_kernel(const float* __restrict__ cr, float4* __restrict__ wpar,
                             int2* __restrict__ ipk, float2* __restrict__ attp) {
    int idx = blockIdx.x * 256 + threadIdx.x;
    if (idx >= 8 * 2 * 9216) return;
    int pix = idx % 9216;
    int g = (idx / 9216) & 1;
    int b = idx / 18432;
    const float* crb = cr + (size_t)b * 10 * 9216 + pix;
    int x = pix % 96, y = pix / 96;
    float4 w; int2 p;
    gs_params(x, y, crb[(2 * g) * 9216], crb[(2 * g + 1) * 9216], &w, &p);
    size_t el = ((size_t)g * 8 + b) * 9216 + pix;
    wpar[el] = w; ipk[el] = p;
    gs_params(x, y, crb[(4 + 2 * g) * 9216], crb[(5 + 2 * g) * 9216], &w, &p);
    size_t eh = ((size_t)(2 + g) * 8 + b) * 9216 + pix;
    wpar[eh] = w; ipk[eh] = p;
    if (g == 0) {
        float2 at;
        at.x = 1.f + tanhf(crb[8 * 9216]);   // multiplies sps
        at.y = 1.f + tanhf(crb[9 * 9216]);   // multiplies cps
        attp[(size_t)b * 9216 + pix] = at;
    }
}

// ---------------------------------------------------------------------------
// gather-only grid_sample blend
// ---------------------------------------------------------------------------
__global__ void gsample2_kernel(const float* __restrict__ cp, const float* __restrict__ sp,
                                const float4* __restrict__ wpar, const int2* __restrict__ ipk,
                                const float2* __restrict__ attp, float* __restrict__ p5o) {
    int idx = blockIdx.x * 256 + threadIdx.x;
    const int total = 8 * 256 * 96 * 96;
    if (idx >= total) return;
    int pix = idx % 9216;
    int c = (idx / 9216) % 256;
    int b = idx / (9216 * 256);
    int g = c >> 7;
    size_t el = ((size_t)g * 8 + b) * 9216 + pix;
    size_t eh = ((size_t)(2 + g) * 8 + b) * 9216 + pix;
    float4 wl = wpar[el]; int2 pl = ipk[el];
    float4 wh = wpar[eh]; int2 ph = ipk[eh];
    const float* cpp = cp + ((size_t)b * 256 + c) * 9216;
    const float* spp = sp + ((size_t)b * 256 + c) * 9216;
    int lx0 = pl.x & 0xffff, lx1 = pl.x >> 16;
    int la0 = (pl.y & 0xffff) * 96, la1 = (pl.y >> 16) * 96;
    float cps = wl.x * cpp[la0 + lx0] + wl.y * cpp[la0 + lx1]
              + wl.z * cpp[la1 + lx0] + wl.w * cpp[la1 + lx1];
    int hx0 = ph.x & 0xffff, hx1 = ph.x >> 16;
    int ha0 = (ph.y & 0xffff) * 96, ha1 = (ph.y >> 16) * 96;
    float sps = wh.x * spp[ha0 + hx0] + wh.y * spp[ha0 + hx1]
              + wh.z * spp[ha1 + hx0] + wh.w * spp[ha1 + hx1];
    float2 at = attp[(size_t)b * 9216 + pix];
    p5o[idx] = sps * at.x + cps * at.y;
}

// ---------------------------------------------------------------------------
extern "C" void kernel_launch(void* const* d_in, const int* in_sizes, int n_in,
                              void* d_out, int out_size, void* d_ws, size_t ws_size,
                              hipStream_t stream) {
    const float* p3    = (const float*)d_in[0];
    const float* p5    = (const float*)d_in[1];
    const float* w_red = (const float*)d_in[2];
    const float* wq    = (const float*)d_in[3];
    const float* bq    = (const float*)d_in[4];
    const float* wk    = (const float*)d_in[5];
    const float* bk    = (const float*)d_in[6];
    const float* wv    = (const float*)d_in[7];
    const float* bv    = (const float*)d_in[8];
    const float* la_w1 = (const float*)d_in[9];
    const float* la_w2 = (const float*)d_in[10];
    const float* w32   = (const float*)d_in[11];
    const float* w8    = (const float*)d_in[12];
    const float* woff1 = (const float*)d_in[13];
    const float* woff2 = (const float*)d_in[14];

    float* out = (float*)d_out;
    float* p3o = out;                 // [8,512,24,24]
    float* p5o = out + 2359296;       // [8,256,96,96]

    float* ws = (float*)d_ws;
    float* x_   = ws + 0;             // 2359296
    float* ctx  = ws + 2359296;       // 2359296
    float* q    = ws + 4718592;       // 147456
    float* kf   = ws + 4866048;       // 204800
    float* km   = ws + 5070848;       // 12800
    float* vm   = ws + 5083648;       // 204800
    float* la1  = ws + 5288448;       // 294912
    float* sp24 = ws + 5583360;       // 1179648
    float* sp96 = ws + 6763008;       // 18874368
    float* cp   = ws + 25637376;      // 18874368
    unsigned short* wred_pk = (unsigned short*)(ws + 44511744); // 2424832 u16
    unsigned short* w32_pk  = (unsigned short*)(ws + 45724160); // 1212416 u16
    unsigned short* w8_pk   = (unsigned short*)(ws + 46330368); // 606208 u16
    // Packed activations inside the sp96 region (dead before K9):
    unsigned short* p5_pk   = (unsigned short*)(ws + 6763008);
    unsigned short* p3_pk   = (unsigned short*)(ws + 16200192);
    unsigned short* la1_pk  = (unsigned short*)(ws + 17379840);
    unsigned short* wla2_pk = (unsigned short*)(ws + 17527296);
    // sim buffer reuses la1 region (la1 written only at K6, sim dead by then)
    float* simg = la1;                // 115200 floats <= 294912
    // reuse (dead after p3o phase):
    float* t64  = ws + 0;             // spans x_/ctx (dead by K11..K12)
    float* cr   = ws + 4718592;       // spans q..la1 (dead by K12..gprep)
    // grid-sample params reuse t64 region (dead after K12):
    float4* wpar = (float4*)(ws + 0);            // 294912 float4
    int2*   ipk  = (int2*)(ws + 1179648);        // 294912 int2
    float2* attp = (float2*)(ws + 1769472);      // 73728 float2

    // P0: pack weights
    pack_w_kernel<<<dim3((2424832 + 255) / 256), dim3(256), 0, stream>>>(w_red, wred_pk, 512, 512);
    pack_w_kernel<<<dim3((1212416 + 255) / 256), dim3(256), 0, stream>>>(w32, w32_pk, 512, 256);
    pack_w_kernel<<<dim3((606208 + 255) / 256), dim3(256), 0, stream>>>(w8, w8_pk, 256, 256);
    pack_w_kernel<<<dim3((303104 + 255) / 256), dim3(256), 0, stream>>>(la_w2, wla2_pk, 64, 512);
    // P1: pack inputs
    pack_in_kernel<<<dim3(2359296 / 256), dim3(256), 0, stream>>>(p5, p5_pk, 256, 9216, 2359296);
    pack_in_kernel<<<dim3(294912 / 256), dim3(256), 0, stream>>>(p3, p3_pk, 512, 576, 294912);

    // K10: cp = silu(conv3x3(p5, w8)) 256->256, 96x96  [MFMA]
    conv3x3_mfma<8, 16, 2, 1><<<dim3(2304), dim3(256), 0, stream>>>(
        p5_pk, w8_pk, cp, 8, 256, 256, 96, 96, nullptr, nullptr);
    // K1: x = silu(conv3x3(p3, w_red)) 512->512, 24x24  [MFMA]
    conv3x3_mfma<8, 24, 3, 1><<<dim3(192), dim3(256), 0, stream>>>(
        p3_pk, wred_pk, x_, 8, 512, 512, 24, 24, nullptr, nullptr);
    // K2: q = conv1x1(x, wq) + bq
    matmul_bcm<0><<<dim3((8 * 32 * 576 + 255) / 256), dim3(256), 0, stream>>>(
        wq, bq, x_, q, 8, 512, 32, 576);
    // K3: kfeat = psp(x)
    psp_kernel<<<dim3(8 * 512), dim3(64), 0, stream>>>(x_, kf);
    // K4: k, v projections
    matmul_bcm<0><<<dim3((8 * 32 * 50 + 255) / 256), dim3(256), 0, stream>>>(
        wk, bk, kf, km, 8, 512, 32, 50);
    matmul_bcm<0><<<dim3((8 * 512 * 50 + 255) / 256), dim3(256), 0, stream>>>(
        wv, bv, kf, vm, 8, 512, 512, 50);
    // K5a: sim = softmax(q^T k)
    sim_kernel<<<dim3(72), dim3(256), 0, stream>>>(q, km, simg);
    // K5b: ctx = v @ sim^T
    ctx_kernel<<<dim3(288), dim3(256), 0, stream>>>(vm, simg, ctx);
    // K6: la1 = silu(conv1x1(ctx, la_w1))
    matmul_bcm<1><<<dim3((8 * 64 * 576 + 255) / 256), dim3(256), 0, stream>>>(
        la_w1, nullptr, ctx, la1, 8, 512, 64, 576);
    // pack la1
    pack_in_kernel<<<dim3(36864 / 256), dim3(256), 0, stream>>>(la1, la1_pk, 64, 576, 36864);
    // K7: p3o = x + ctx*(1 + tanh(conv3x3(la1, la_w2)))  [MFMA FUSE2]
    conv3x3_mfma<8, 24, 3, 2><<<dim3(192), dim3(256), 0, stream>>>(
        la1_pk, wla2_pk, p3o, 8, 64, 512, 24, 24, ctx, x_);
    // pack p3o
    pack_in_kernel<<<dim3(294912 / 256), dim3(256), 0, stream>>>(p3o, p3_pk, 512, 576, 294912);
    // K8: sp24 = silu(conv3x3(p3o, w32)) 512->256  [MFMA]
    conv3x3_mfma<8, 24, 3, 1><<<dim3(96), dim3(256), 0, stream>>>(
        p3_pk, w32_pk, sp24, 8, 512, 256, 24, 24, nullptr, nullptr);
    // K9: sp96 = bilinear upsample
    upsample_kernel<<<dim3(8 * 256 * 9216 / 256), dim3(256), 0, stream>>>(sp24, sp96);
    // K11: t64 = silu(conv1x1(concat[cp, sp96], woff1))
    conv1x1_cat_kernel<<<dim3(8 * 72), dim3(256), 0, stream>>>(cp, sp96, woff1, t64);
    // K12: cr = conv3x3(t64, woff2) 64->10
    conv3x3_kernel<8, 32, 12, 3, 4, 0><<<dim3(288), dim3(192), 0, stream>>>(
        t64, woff2, cr, 8, 64, 10, 96, 96, nullptr, nullptr);
    // K13a: grid-sample params + att (t64 dead now)
    gprep_kernel<<<dim3(576), dim3(256), 0, stream>>>(cr, wpar, ipk, attp);
    // K13b: p5o = gather blend
    gsample2_kernel<<<dim3(8 * 256 * 9216 / 256), dim3(256), 0, stream>>>(
        cp, sp96, wpar, ipk, attp, p5o);
}

// Round 5
// 1039.079 us; speedup vs baseline: 3.8380x; 1.1908x over previous
//
#include <hip/hip_runtime.h>
#include <math.h>

#define DI __device__ __forceinline__

typedef __attribute__((ext_vector_type(8))) short bf16x8;
typedef __attribute__((ext_vector_type(4))) float f32x4;

DI float silu_f(float v) { return v / (1.f + __expf(-v)); }
DI float4 ld4(const float* p) { return *reinterpret_cast<const float4*>(p); }
DI void st4(float* p, const float4& v) { *reinterpret_cast<float4*>(p) = v; }
DI unsigned short f2bf(float f) {
    unsigned u = __float_as_uint(f);
    unsigned r = (u + 0x7FFFu + ((u >> 16) & 1u)) >> 16;
    return (unsigned short)r;
}

// ---------------------------------------------------------------------------
// Weight pre-pack: w f32 [Co][Ci][3][3] -> pk bf16 [Ci/32][Co][296]
// ---------------------------------------------------------------------------
__global__ void pack_w_kernel(const float* __restrict__ w, unsigned short* __restrict__ pk,
                              int Ci, int Co) {
    int idx = blockIdx.x * 256 + threadIdx.x;
    int total = (Ci >> 5) * Co * 296;
    if (idx >= total) return;
    int e = idx % 296;
    int co = (idx / 296) % Co;
    int ch = idx / (296 * Co);
    unsigned short v = 0;
    if (e < 288) {
        int dydx = e >> 5;
        int cc = e & 31;
        v = f2bf(w[((size_t)co * Ci + (ch << 5) + cc) * 9 + dydx]);
    }
    pk[idx] = v;
}

// ---------------------------------------------------------------------------
// Input pre-pack: f32 NCHW -> bf16 [b][ci/32][H][W][32]
// ---------------------------------------------------------------------------
__global__ void pack_in_kernel(const float* __restrict__ in, unsigned short* __restrict__ pk,
                               int Ci, int HW, int total) {
    int idx = blockIdx.x * 256 + threadIdx.x;
    if (idx >= total) return;
    const int nCh = Ci >> 5;
    int cg = idx & 3;
    int t = idx >> 2;
    int pix = t % HW; t /= HW;
    int ch = t % nCh;
    int b = t / nCh;
    const float* src = in + ((size_t)b * Ci + (ch << 5) + (cg << 3)) * HW + pix;
    unsigned p[4];
#pragma unroll
    for (int j = 0; j < 4; ++j) {
        float v0 = src[(size_t)(2 * j) * HW];
        float v1 = src[(size_t)(2 * j + 1) * HW];
        p[j] = (unsigned)f2bf(v0) | ((unsigned)f2bf(v1) << 16);
    }
    *(uint4*)&pk[(((size_t)b * nCh + ch) * HW + pix) * 32 + (cg << 3)] =
        make_uint4(p[0], p[1], p[2], p[3]);
}

// ---------------------------------------------------------------------------
// MFMA implicit-GEMM 3x3 SAME conv.
// ---------------------------------------------------------------------------
template <int TH, int TW, int BF, int FUSE>
__global__ void __launch_bounds__(256)
conv3x3_mfma(const unsigned short* __restrict__ pin, const unsigned short* __restrict__ wpk,
             float* __restrict__ out, int B, int Ci, int Co, int H, int W,
             const float* __restrict__ ctx, const float* __restrict__ xres) {
    static_assert(TH * TW == 4 * BF * 16, "tile px = 4 waves * BF frags * 16");
    constexpr int TWH = TW + 2;
    constexpr int HP = (TH + 2) * TWH;
    __shared__ __align__(16) unsigned short lin[HP * 40];
    __shared__ __align__(16) unsigned short wls[64 * 296];

    const int nTx = W / TW, nTy = H / TH, nCoG = Co >> 6;
    const int nwg = gridDim.x;
    int wg = (blockIdx.x & 7) * (nwg >> 3) + (blockIdx.x >> 3);
    const int cog = wg % nCoG; wg /= nCoG;
    const int tx = wg % nTx;   wg /= nTx;
    const int ty = wg % nTy;
    const int b = wg / nTy;
    const int ox = tx * TW, oy = ty * TH, co0 = cog << 6;

    const int tid = threadIdx.x;
    const int wave = tid >> 6, lane = tid & 63;
    const int l15 = lane & 15, g = lane >> 4;
    const int wpx = wave * (BF * 16);

    int rr[BF], cc_[BF];
#pragma unroll
    for (int bf = 0; bf < BF; ++bf) {
        int px = wpx + bf * 16 + l15;
        rr[bf] = px / TW;
        cc_[bf] = px % TW;
    }

    f32x4 acc[4][BF];
#pragma unroll
    for (int af = 0; af < 4; ++af)
#pragma unroll
        for (int bf = 0; bf < BF; ++bf) acc[af][bf] = {};

    const int nCh = Ci >> 5;
    const size_t HWs = (size_t)H * W;

    for (int ch = 0; ch < nCh; ++ch) {
#pragma unroll
        for (int it = 0; it < (HP * 4 + 255) / 256; ++it) {
            int e = tid + it * 256;
            if (e < HP * 4) {
                int cg = e & 3;
                int hp = e >> 2;
                int hy = hp / TWH, hx = hp % TWH;
                int gy = oy + hy - 1, gx = ox + hx - 1;
                uint4 v = make_uint4(0, 0, 0, 0);
                if ((unsigned)gy < (unsigned)H && (unsigned)gx < (unsigned)W)
                    v = *(const uint4*)&pin[(((size_t)b * nCh + ch) * H * W
                                            + (size_t)gy * W + gx) * 32 + (cg << 3)];
                *(uint4*)&lin[hp * 40 + (cg << 3)] = v;
            }
        }
        {
            const unsigned short* src = wpk + ((size_t)ch * Co + co0) * 296;
#pragma unroll
            for (int it = 0; it < 10; ++it) {
                int e = tid + it * 256;
                if (e < 2368) *(uint4*)&wls[e * 8] = *(const uint4*)&src[e * 8];
            }
        }
        __syncthreads();

        const unsigned short* wb = &wls[l15 * 296 + g * 8];
#pragma unroll
        for (int dy = 0; dy < 3; ++dy) {
#pragma unroll
            for (int dx = 0; dx < 3; ++dx) {
                const int dydx = dy * 3 + dx;
                bf16x8 a[4];
#pragma unroll
                for (int af = 0; af < 4; ++af)
                    a[af] = *(const bf16x8*)(wb + (af * 16) * 296 + dydx * 32);
                bf16x8 bb[BF];
#pragma unroll
                for (int bf = 0; bf < BF; ++bf)
                    bb[bf] = *(const bf16x8*)&lin[((rr[bf] + dy) * TWH + cc_[bf] + dx) * 40 + g * 8];
#pragma unroll
                for (int af = 0; af < 4; ++af)
#pragma unroll
                    for (int bf = 0; bf < BF; ++bf)
                        acc[af][bf] = __builtin_amdgcn_mfma_f32_16x16x32_bf16(
                            a[af], bb[bf], acc[af][bf], 0, 0, 0);
            }
        }
        __syncthreads();
    }
#pragma unroll
    for (int af = 0; af < 4; ++af) {
#pragma unroll
        for (int bf = 0; bf < BF; ++bf) {
            int px = wpx + bf * 16 + l15;
            int y = oy + px / TW, x = ox + px % TW;
#pragma unroll
            for (int r4 = 0; r4 < 4; ++r4) {
                int co = co0 + af * 16 + (g << 2) + r4;
                size_t base = ((size_t)b * Co + co) * HWs + (size_t)y * W + x;
                float v = acc[af][bf][r4];
                if (FUSE == 1) v = silu_f(v);
                else if (FUSE == 2) v = xres[base] + ctx[base] * (1.f + tanhf(v));
                out[base] = v;
            }
        }
    }
}

// ---------------------------------------------------------------------------
// Direct 3x3 SAME conv, f32 (K12: 64->10).
// ---------------------------------------------------------------------------
template <int TH, int TW, int CO_BLK, int CO_T, int CIC, int FUSE>
__global__ void __launch_bounds__(576)
conv3x3_kernel(const float* __restrict__ in, const float* __restrict__ wgt,
               float* __restrict__ out, int B, int Ci, int Co, int H, int W,
               const float* __restrict__ ctx, const float* __restrict__ xres) {
    constexpr int TWH = TW + 2;
    constexpr int TWP = TW + 3;
    constexpr int SPAT = TH * (TW / 4);
    __shared__ float lin[CIC][TH + 2][TWP];
    __shared__ float wls[CIC][9][CO_BLK];

    const int nTx = W / TW, nTy = H / TH;
    const int nCoG = (Co + CO_BLK - 1) / CO_BLK;
    int bid = blockIdx.x;
    const int cog = bid % nCoG; bid /= nCoG;
    const int tx = bid % nTx;   bid /= nTx;
    const int ty = bid % nTy;
    const int b = bid / nTy;
    const int ox = tx * TW, oy = ty * TH;
    const int co0 = cog * CO_BLK;

    const int tid = threadIdx.x;
    const int cot = tid / SPAT;
    const int sp = tid % SPAT;
    const int r = sp / (TW / 4);
    const int cg = sp % (TW / 4);

    float acc[4][4];
#pragma unroll
    for (int i = 0; i < 4; ++i)
#pragma unroll
        for (int j = 0; j < 4; ++j) acc[i][j] = 0.f;

    for (int ci0 = 0; ci0 < Ci; ci0 += CIC) {
        for (int e = tid; e < CIC * (TH + 2) * TWH; e += SPAT * CO_T) {
            int xx = e % TWH;
            int yy = (e / TWH) % (TH + 2);
            int cc = e / (TWH * (TH + 2));
            int gy = oy - 1 + yy, gx = ox - 1 + xx;
            float v = 0.f;
            if (gy >= 0 && gy < H && gx >= 0 && gx < W)
                v = in[(((size_t)b * Ci + ci0 + cc) * H + gy) * W + gx];
            lin[cc][yy][xx] = v;
        }
        for (int e = tid; e < CIC * 9 * CO_BLK; e += SPAT * CO_T) {
            int col = e % CO_BLK;
            int k = (e / CO_BLK) % 9;
            int cc = e / (CO_BLK * 9);
            int co = co0 + col;
            float v = 0.f;
            if (co < Co) v = wgt[((size_t)co * Ci + ci0 + cc) * 9 + k];
            wls[cc][k][col] = v;
        }
        __syncthreads();
#pragma unroll
        for (int cc = 0; cc < CIC; ++cc) {
            float v0[3][6];
#pragma unroll
            for (int ky = 0; ky < 3; ++ky)
#pragma unroll
                for (int u = 0; u < 6; ++u)
                    v0[ky][u] = lin[cc][r + ky][cg * 4 + u];
#pragma unroll
            for (int ky = 0; ky < 3; ++ky)
#pragma unroll
                for (int kx = 0; kx < 3; ++kx) {
                    const float4 w4 = ld4(&wls[cc][ky * 3 + kx][cot * 4]);
                    const float wv_[4] = {w4.x, w4.y, w4.z, w4.w};
#pragma unroll
                    for (int i = 0; i < 4; ++i)
#pragma unroll
                        for (int j = 0; j < 4; ++j)
                            acc[i][j] = fmaf(wv_[i], v0[ky][kx + j], acc[i][j]);
                }
        }
        __syncthreads();
    }
    const int y = oy + r;
    const int xb = ox + cg * 4;
#pragma unroll
    for (int i = 0; i < 4; ++i) {
        int co = co0 + cot * 4 + i;
        if (co >= Co) continue;
        size_t base = (((size_t)b * Co + co) * H + y) * W + xb;
        float4 res;
        if (FUSE == 2) {
            float4 c4 = ld4(&ctx[base]);
            float4 x4 = ld4(&xres[base]);
            res.x = x4.x + c4.x * (1.f + tanhf(acc[i][0]));
            res.y = x4.y + c4.y * (1.f + tanhf(acc[i][1]));
            res.z = x4.z + c4.z * (1.f + tanhf(acc[i][2]));
            res.w = x4.w + c4.w * (1.f + tanhf(acc[i][3]));
        } else if (FUSE == 1) {
            res.x = silu_f(acc[i][0]); res.y = silu_f(acc[i][1]);
            res.z = silu_f(acc[i][2]); res.w = silu_f(acc[i][3]);
        } else {
            res.x = acc[i][0]; res.y = acc[i][1];
            res.z = acc[i][2]; res.w = acc[i][3];
        }
        st4(&out[base], res);
    }
}

// ---------------------------------------------------------------------------
// Tiled GEMM: out[b][o][m] = act(sum_c W[o][c] * in[b][c][m] + bias[o]).
// Block tile 64o x 64m, thread 4o x 4m, C chunked by 32 through LDS.
// ---------------------------------------------------------------------------
template <int ACT>
__global__ void __launch_bounds__(256)
gemm_om(const float* __restrict__ W, const float* __restrict__ bias,
        const float* __restrict__ in, float* __restrict__ out,
        int B, int C, int O, int M, int nOt, int nMt) {
    __shared__ float xs[32][66];
    __shared__ float wls[64][33];
    int bid = blockIdx.x;
    int mt = bid % nMt; bid /= nMt;
    int ot = bid % nOt;
    int b  = bid / nOt;
    int o0 = ot * 64, m0 = mt * 64;
    int tid = threadIdx.x;
    int m_t = tid & 15, o_g = tid >> 4;
    float acc[4][4];
#pragma unroll
    for (int i = 0; i < 4; ++i)
#pragma unroll
        for (int j = 0; j < 4; ++j) acc[i][j] = 0.f;

    for (int c0 = 0; c0 < C; c0 += 32) {
#pragma unroll
        for (int it = 0; it < 8; ++it) {
            int e = tid + it * 256;
            int mm = e & 63, cc = e >> 6;
            float v = 0.f;
            if (m0 + mm < M) v = in[((size_t)b * C + c0 + cc) * M + m0 + mm];
            xs[cc][mm] = v;
        }
#pragma unroll
        for (int it = 0; it < 8; ++it) {
            int e = tid + it * 256;
            int cc = e & 31, ol = e >> 5;
            float v = 0.f;
            if (o0 + ol < O) v = W[(size_t)(o0 + ol) * C + c0 + cc];
            wls[ol][cc] = v;
        }
        __syncthreads();
#pragma unroll
        for (int cc = 0; cc < 32; ++cc) {
            float xv[4], wv[4];
#pragma unroll
            for (int j = 0; j < 4; ++j) xv[j] = xs[cc][j * 16 + m_t];
#pragma unroll
            for (int i = 0; i < 4; ++i) wv[i] = wls[o_g * 4 + i][cc];
#pragma unroll
            for (int i = 0; i < 4; ++i)
#pragma unroll
                for (int j = 0; j < 4; ++j)
                    acc[i][j] = fmaf(wv[i], xv[j], acc[i][j]);
        }
        __syncthreads();
    }
#pragma unroll
    for (int i = 0; i < 4; ++i) {
        int o = o0 + o_g * 4 + i;
        if (o >= O) continue;
        float bv = bias ? bias[o] : 0.f;
#pragma unroll
        for (int j = 0; j < 4; ++j) {
            int m = m0 + j * 16 + m_t;
            if (m >= M) continue;
            float v = acc[i][j] + bv;
            if (ACT == 1) v = silu_f(v);
            out[((size_t)b * O + o) * M + m] = v;
        }
    }
}

// ---------------------------------------------------------------------------
__global__ void psp_kernel(const float* __restrict__ x, float* __restrict__ kf) {
    __shared__ float pl[576];
    int bc = blockIdx.x;
    const float* xp = x + (size_t)bc * 576;
    for (int e = threadIdx.x; e < 576; e += 64) pl[e] = xp[e];
    __syncthreads();
    int m = threadIdx.x;
    if (m < 50) {
        int g, i0;
        if (m < 36)      { g = 6; i0 = m; }
        else if (m < 45) { g = 3; i0 = m - 36; }
        else if (m < 49) { g = 2; i0 = m - 45; }
        else             { g = 1; i0 = 0; }
        int bs = 24 / g;
        int by = i0 / g, bx = i0 % g;
        float s = 0.f;
        for (int yy = 0; yy < bs; ++yy)
            for (int xx = 0; xx < bs; ++xx)
                s += pl[(by * bs + yy) * 24 + bx * bs + xx];
        kf[(size_t)bc * 50 + m] = s / (float)(bs * bs);
    }
}

// ---------------------------------------------------------------------------
// sim = softmax(q^T k): block = (b, 64 n's). simg [b][576][50]
// ---------------------------------------------------------------------------
__global__ void __launch_bounds__(256)
sim_kernel(const float* __restrict__ q, const float* __restrict__ k,
           float* __restrict__ simg) {
    __shared__ float qs[32][65];
    __shared__ float ks[32][52];
    __shared__ float sm[64][52];
    int b = blockIdx.x / 9, n0 = (blockIdx.x % 9) * 64;
    int tid = threadIdx.x;
    for (int e = tid; e < 32 * 64; e += 256) {
        int c = e >> 6, n = e & 63;
        qs[c][n] = q[((size_t)b * 32 + c) * 576 + n0 + n];
    }
    for (int e = tid; e < 32 * 50; e += 256) {
        int c = e / 50, m = e % 50;
        ks[c][m] = k[((size_t)b * 32 + c) * 50 + m];
    }
    __syncthreads();
    for (int e = tid; e < 64 * 50; e += 256) {
        int n = e / 50, m = e % 50;
        float s = 0.f;
#pragma unroll
        for (int c = 0; c < 32; ++c) s = fmaf(qs[c][n], ks[c][m], s);
        sm[n][m] = s;
    }
    __syncthreads();
    if (tid < 64) {
        float mx = -1e30f;
        for (int m = 0; m < 50; ++m) mx = fmaxf(mx, sm[tid][m]);
        float sum = 0.f;
        for (int m = 0; m < 50; ++m) {
            float e2 = __expf(sm[tid][m] - mx);
            sm[tid][m] = e2;
            sum += e2;
        }
        float inv = 1.f / sum;
        for (int m = 0; m < 50; ++m) sm[tid][m] *= inv;
    }
    __syncthreads();
    for (int e = tid; e < 64 * 50; e += 256) {
        int n = e / 50, m = e % 50;
        simg[((size_t)b * 576 + n0 + n) * 50 + m] = sm[n][m];
    }
}

// ---------------------------------------------------------------------------
// ctx[b][c][n] = sum_m v[b][c][m] * sim[b][n][m]. Block = 128c x 64n.
// ---------------------------------------------------------------------------
__global__ void __launch_bounds__(256)
ctx_kernel(const float* __restrict__ v, const float* __restrict__ simg,
           float* __restrict__ ctx) {
    __shared__ float vs[128][54];
    __shared__ float ss[64][54];
    int blk = blockIdx.x;
    int ct = blk & 3; blk >>= 2;
    int nt = blk % 9;
    int b = blk / 9;
    int c0 = ct * 128, n0 = nt * 64;
    int tid = threadIdx.x;
    for (int e = tid; e < 128 * 50; e += 256) {
        int c = e / 50, m = e % 50;
        vs[c][m] = v[((size_t)b * 512 + c0 + c) * 50 + m];
    }
    for (int e = tid; e < 64 * 50; e += 256) {
        int n = e / 50, m = e % 50;
        ss[n][m] = simg[((size_t)b * 576 + n0 + n) * 50 + m];
    }
    __syncthreads();
    int n_t = tid & 15;
    int c_t = tid >> 4;
    float acc[8][4];
#pragma unroll
    for (int i = 0; i < 8; ++i)
#pragma unroll
        for (int j = 0; j < 4; ++j) acc[i][j] = 0.f;
    for (int m = 0; m < 50; ++m) {
        float sv[4];
#pragma unroll
        for (int j = 0; j < 4; ++j) sv[j] = ss[j * 16 + n_t][m];
#pragma unroll
        for (int i = 0; i < 8; ++i) {
            float vv = vs[c_t * 8 + i][m];
#pragma unroll
            for (int j = 0; j < 4; ++j) acc[i][j] = fmaf(vv, sv[j], acc[i][j]);
        }
    }
#pragma unroll
    for (int i = 0; i < 8; ++i)
#pragma unroll
        for (int j = 0; j < 4; ++j)
            ctx[((size_t)b * 512 + c0 + c_t * 8 + i) * 576 + n0 + j * 16 + n_t] = acc[i][j];
}

// ---------------------------------------------------------------------------
// 1x1 conv on concat [cp; sp] (512 -> 64) + SiLU. Tile 64co x 128m.
// ---------------------------------------------------------------------------
__global__ void __launch_bounds__(256)
conv1x1_cat_kernel(const float* __restrict__ cp, const float* __restrict__ sp,
                   const float* __restrict__ w, float* __restrict__ out) {
    __shared__ float ins[8][128];
    __shared__ float wls[8][64];
    int bid = blockIdx.x;
    int mt = bid % 72;
    int b = bid / 72;
    int m0 = mt * 128;
    int tid = threadIdx.x;
    int ml = tid & 31;
    int col = (tid >> 5) * 8;
    float acc[8][4];
#pragma unroll
    for (int i = 0; i < 8; ++i)
#pragma unroll
        for (int j = 0; j < 4; ++j) acc[i][j] = 0.f;
    for (int c0 = 0; c0 < 512; c0 += 8) {
        {
            int e = tid * 4;
            int cl = e >> 7, mm = e & 127;
            int cidx = c0 + cl;
            const float* src = (cidx < 256)
                ? (cp + ((size_t)b * 256 + cidx) * 9216 + m0 + mm)
                : (sp + ((size_t)b * 256 + (cidx - 256)) * 9216 + m0 + mm);
            st4(&ins[cl][mm], ld4(src));
        }
        for (int e = tid; e < 512; e += 256) {
            int cl = e & 7;
            int o = e >> 3;
            wls[cl][o] = w[(size_t)o * 512 + c0 + cl];
        }
        __syncthreads();
#pragma unroll
        for (int cl = 0; cl < 8; ++cl) {
            float4 w0 = ld4(&wls[cl][col]);
            float4 w1 = ld4(&wls[cl][col + 4]);
            float av[4];
#pragma unroll
            for (int j = 0; j < 4; ++j) av[j] = ins[cl][ml + 32 * j];
            float wv_[8] = {w0.x, w0.y, w0.z, w0.w, w1.x, w1.y, w1.z, w1.w};
#pragma unroll
            for (int oo = 0; oo < 8; ++oo)
#pragma unroll
                for (int j = 0; j < 4; ++j)
                    acc[oo][j] = fmaf(wv_[oo], av[j], acc[oo][j]);
        }
        __syncthreads();
    }
#pragma unroll
    for (int oo = 0; oo < 8; ++oo)
#pragma unroll
        for (int j = 0; j < 4; ++j)
            out[((size_t)b * 64 + col + oo) * 9216 + m0 + ml + 32 * j] = silu_f(acc[oo][j]);
}

// ---------------------------------------------------------------------------
__global__ void upsample_kernel(const float* __restrict__ in, float* __restrict__ out) {
    int idx = blockIdx.x * 256 + threadIdx.x;
    const int total = 8 * 256 * 96 * 96;
    if (idx >= total) return;
    int x = idx % 96;
    int y = (idx / 96) % 96;
    int p = idx / 9216;
    float fy = y * (23.f / 95.f);
    float fx = x * (23.f / 95.f);
    int y0 = (int)fy; if (y0 > 22) y0 = 22;
    int x0 = (int)fx; if (x0 > 22) x0 = 22;
    float wy = fy - y0, wx = fx - x0;
    const float* ip = in + (size_t)p * 576;
    float a = ip[y0 * 24 + x0], b = ip[y0 * 24 + x0 + 1];
    float c = ip[(y0 + 1) * 24 + x0], d = ip[(y0 + 1) * 24 + x0 + 1];
    float l = a * (1.f - wy) + c * wy;
    float r = b * (1.f - wy) + d * wy;
    out[idx] = l * (1.f - wx) + r * wx;
}

// ---------------------------------------------------------------------------
// grid_sample prep
// ---------------------------------------------------------------------------
DI void gs_params(int x, int y, float ox, float oy, float4* w, int2* p) {
    const float S = 47.5f / 96.f;
    float px = x + ox * S;
    float py = y + oy * S;
    float fx0 = floorf(px), fy0 = floorf(py);
    float wx = px - fx0, wy = py - fy0;
    float vx0 = (fx0 >= 0.f && fx0 <= 95.f) ? 1.f : 0.f;
    float vx1 = (fx0 >= -1.f && fx0 <= 94.f) ? 1.f : 0.f;
    float vy0 = (fy0 >= 0.f && fy0 <= 95.f) ? 1.f : 0.f;
    float vy1 = (fy0 >= -1.f && fy0 <= 94.f) ? 1.f : 0.f;
    int x0 = (int)fminf(fmaxf(fx0, 0.f), 95.f);
    int x1 = (int)fminf(fmaxf(fx0 + 1.f, 0.f), 95.f);
    int y0 = (int)fminf(fmaxf(fy0, 0.f), 95.f);
    int y1 = (int)fminf(fmaxf(fy0 + 1.f, 0.f), 95.f);
    w->x = (1.f - wx) * (1.f - wy) * vx0 * vy0;
    w->y = wx * (1.f - wy) * vx1 * vy0;
    w->z = (1.f - wx) * wy * vx0 * vy1;
    w->w = wx * wy * vx1 * vy1;
    *p = make_int2(x0 | (x1 << 16), y0 | (y1 << 16));
}

__global__ void gprep_kernel(const float* __restrict__ cr, float4* __restrict__ wpar,
                             int2* __restrict__ ipk, float2* __restrict__ attp) {
    int idx = blockIdx.x * 256 + threadIdx.x;
    if (idx >= 8 * 2 * 9216) return;
    int pix = idx % 9216;
    int g = (idx / 9216) & 1;
    int b = idx / 18432;
    const float* crb = cr + (size_t)b * 10 * 9216 + pix;
    int x = pix % 96, y = pix / 96;
    float4 w; int2 p;
    gs_params(x, y, crb[(2 * g) * 9216], crb[(2 * g + 1) * 9216], &w, &p);
    size_t el = ((size_t)g * 8 + b) * 9216 + pix;
    wpar[el] = w; ipk[el] = p;
    gs_params(x, y, crb[(4 + 2 * g) * 9216], crb[(5 + 2 * g) * 9216], &w, &p);
    size_t eh = ((size_t)(2 + g) * 8 + b) * 9216 + pix;
    wpar[eh] = w; ipk[eh] = p;
    if (g == 0) {
        float2 at;
        at.x = 1.f + tanhf(crb[8 * 9216]);
        at.y = 1.f + tanhf(crb[9 * 9216]);
        attp[(size_t)b * 9216 + pix] = at;
    }
}

// ---------------------------------------------------------------------------
__global__ void gsample2_kernel(const float* __restrict__ cp, const float* __restrict__ sp,
                                const float4* __restrict__ wpar, const int2* __restrict__ ipk,
                                const float2* __restrict__ attp, float* __restrict__ p5o) {
    int idx = blockIdx.x * 256 + threadIdx.x;
    const int total = 8 * 256 * 96 * 96;
    if (idx >= total) return;
    int pix = idx % 9216;
    int c = (idx / 9216) % 256;
    int b = idx / (9216 * 256);
    int g = c >> 7;
    size_t el = ((size_t)g * 8 + b) * 9216 + pix;
    size_t eh = ((size_t)(2 + g) * 8 + b) * 9216 + pix;
    float4 wl = wpar[el]; int2 pl = ipk[el];
    float4 wh = wpar[eh]; int2 ph = ipk[eh];
    const float* cpp = cp + ((size_t)b * 256 + c) * 9216;
    const float* spp = sp + ((size_t)b * 256 + c) * 9216;
    int lx0 = pl.x & 0xffff, lx1 = pl.x >> 16;
    int la0 = (pl.y & 0xffff) * 96, la1 = (pl.y >> 16) * 96;
    float cps = wl.x * cpp[la0 + lx0] + wl.y * cpp[la0 + lx1]
              + wl.z * cpp[la1 + lx0] + wl.w * cpp[la1 + lx1];
    int hx0 = ph.x & 0xffff, hx1 = ph.x >> 16;
    int ha0 = (ph.y & 0xffff) * 96, ha1 = (ph.y >> 16) * 96;
    float sps = wh.x * spp[ha0 + hx0] + wh.y * spp[ha0 + hx1]
              + wh.z * spp[ha1 + hx0] + wh.w * spp[ha1 + hx1];
    float2 at = attp[(size_t)b * 9216 + pix];
    p5o[idx] = sps * at.x + cps * at.y;
}

// ---------------------------------------------------------------------------
extern "C" void kernel_launch(void* const* d_in, const int* in_sizes, int n_in,
                              void* d_out, int out_size, void* d_ws, size_t ws_size,
                              hipStream_t stream) {
    const float* p3    = (const float*)d_in[0];
    const float* p5    = (const float*)d_in[1];
    const float* w_red = (const float*)d_in[2];
    const float* wq    = (const float*)d_in[3];
    const float* bq    = (const float*)d_in[4];
    const float* wk    = (const float*)d_in[5];
    const float* bk    = (const float*)d_in[6];
    const float* wv    = (const float*)d_in[7];
    const float* bv    = (const float*)d_in[8];
    const float* la_w1 = (const float*)d_in[9];
    const float* la_w2 = (const float*)d_in[10];
    const float* w32   = (const float*)d_in[11];
    const float* w8    = (const float*)d_in[12];
    const float* woff1 = (const float*)d_in[13];
    const float* woff2 = (const float*)d_in[14];

    float* out = (float*)d_out;
    float* p3o = out;                 // [8,512,24,24]
    float* p5o = out + 2359296;       // [8,256,96,96]

    float* ws = (float*)d_ws;
    float* x_   = ws + 0;             // 2359296
    float* ctx  = ws + 2359296;       // 2359296
    float* q    = ws + 4718592;       // 147456
    float* kf   = ws + 4866048;       // 204800
    float* km   = ws + 5070848;       // 12800
    float* vm   = ws + 5083648;       // 204800
    float* la1  = ws + 5288448;       // 294912
    float* sp24 = ws + 5583360;       // 1179648
    float* sp96 = ws + 6763008;       // 18874368
    float* cp   = ws + 25637376;      // 18874368
    unsigned short* wred_pk = (unsigned short*)(ws + 44511744);
    unsigned short* w32_pk  = (unsigned short*)(ws + 45724160);
    unsigned short* w8_pk   = (unsigned short*)(ws + 46330368);
    unsigned short* p5_pk   = (unsigned short*)(ws + 6763008);
    unsigned short* p3_pk   = (unsigned short*)(ws + 16200192);
    unsigned short* la1_pk  = (unsigned short*)(ws + 17379840);
    unsigned short* wla2_pk = (unsigned short*)(ws + 17527296);
    float* simg = la1;
    float* t64  = ws + 0;
    float* cr   = ws + 4718592;
    float4* wpar = (float4*)(ws + 0);
    int2*   ipk  = (int2*)(ws + 1179648);
    float2* attp = (float2*)(ws + 1769472);

    // P0: pack weights
    pack_w_kernel<<<dim3((2424832 + 255) / 256), dim3(256), 0, stream>>>(w_red, wred_pk, 512, 512);
    pack_w_kernel<<<dim3((1212416 + 255) / 256), dim3(256), 0, stream>>>(w32, w32_pk, 512, 256);
    pack_w_kernel<<<dim3((606208 + 255) / 256), dim3(256), 0, stream>>>(w8, w8_pk, 256, 256);
    pack_w_kernel<<<dim3((303104 + 255) / 256), dim3(256), 0, stream>>>(la_w2, wla2_pk, 64, 512);
    // P1: pack inputs
    pack_in_kernel<<<dim3(2359296 / 256), dim3(256), 0, stream>>>(p5, p5_pk, 256, 9216, 2359296);
    pack_in_kernel<<<dim3(294912 / 256), dim3(256), 0, stream>>>(p3, p3_pk, 512, 576, 294912);

    // K10: cp = silu(conv3x3(p5, w8)) 256->256, 96x96  [MFMA]
    conv3x3_mfma<8, 16, 2, 1><<<dim3(2304), dim3(256), 0, stream>>>(
        p5_pk, w8_pk, cp, 8, 256, 256, 96, 96, nullptr, nullptr);
    // K1: x = silu(conv3x3(p3, w_red)) 512->512, 24x24  [MFMA]
    conv3x3_mfma<8, 24, 3, 1><<<dim3(192), dim3(256), 0, stream>>>(
        p3_pk, wred_pk, x_, 8, 512, 512, 24, 24, nullptr, nullptr);
    // K2: q = conv1x1(x, wq) + bq  [tiled GEMM: O=32, M=576]
    gemm_om<0><<<dim3(8 * 1 * 9), dim3(256), 0, stream>>>(
        wq, bq, x_, q, 8, 512, 32, 576, 1, 9);
    // K3: kfeat = psp(x)
    psp_kernel<<<dim3(8 * 512), dim3(64), 0, stream>>>(x_, kf);
    // K4: k, v projections  [tiled GEMM, M=50]
    gemm_om<0><<<dim3(8 * 1 * 1), dim3(256), 0, stream>>>(
        wk, bk, kf, km, 8, 512, 32, 50, 1, 1);
    gemm_om<0><<<dim3(8 * 8 * 1), dim3(256), 0, stream>>>(
        wv, bv, kf, vm, 8, 512, 512, 50, 8, 1);
    // K5a: sim = softmax(q^T k)
    sim_kernel<<<dim3(72), dim3(256), 0, stream>>>(q, km, simg);
    // K5b: ctx = v @ sim^T
    ctx_kernel<<<dim3(288), dim3(256), 0, stream>>>(vm, simg, ctx);
    // K6: la1 = silu(conv1x1(ctx, la_w1))  [tiled GEMM: O=64, M=576]
    gemm_om<1><<<dim3(8 * 1 * 9), dim3(256), 0, stream>>>(
        la_w1, nullptr, ctx, la1, 8, 512, 64, 576, 1, 9);
    // pack la1
    pack_in_kernel<<<dim3(36864 / 256), dim3(256), 0, stream>>>(la1, la1_pk, 64, 576, 36864);
    // K7: p3o = x + ctx*(1 + tanh(conv3x3(la1, la_w2)))  [MFMA FUSE2]
    conv3x3_mfma<8, 24, 3, 2><<<dim3(192), dim3(256), 0, stream>>>(
        la1_pk, wla2_pk, p3o, 8, 64, 512, 24, 24, ctx, x_);
    // pack p3o
    pack_in_kernel<<<dim3(294912 / 256), dim3(256), 0, stream>>>(p3o, p3_pk, 512, 576, 294912);
    // K8: sp24 = silu(conv3x3(p3o, w32)) 512->256  [MFMA]
    conv3x3_mfma<8, 24, 3, 1><<<dim3(96), dim3(256), 0, stream>>>(
        p3_pk, w32_pk, sp24, 8, 512, 256, 24, 24, nullptr, nullptr);
    // K9: sp96 = bilinear upsample
    upsample_kernel<<<dim3(8 * 256 * 9216 / 256), dim3(256), 0, stream>>>(sp24, sp96);
    // K11: t64 = silu(conv1x1(concat[cp, sp96], woff1))
    conv1x1_cat_kernel<<<dim3(8 * 72), dim3(256), 0, stream>>>(cp, sp96, woff1, t64);
    // K12: cr = conv3x3(t64, woff2) 64->10
    conv3x3_kernel<8, 32, 12, 3, 4, 0><<<dim3(288), dim3(192), 0, stream>>>(
        t64, woff2, cr, 8, 64, 10, 96, 96, nullptr, nullptr);
    // K13a: grid-sample params + att
    gprep_kernel<<<dim3(576), dim3(256), 0, stream>>>(cr, wpar, ipk, attp);
    // K13b: p5o = gather blend
    gsample2_kernel<<<dim3(8 * 256 * 9216 / 256), dim3(256), 0, stream>>>(
        cp, sp96, wpar, ipk, attp, p5o);
}

// Round 6
// 1020.847 us; speedup vs baseline: 3.9065x; 1.0179x over previous
//
#include <hip/hip_runtime.h>
#include <math.h>

#define DI __device__ __forceinline__

typedef __attribute__((ext_vector_type(8))) short bf16x8;
typedef __attribute__((ext_vector_type(4))) float f32x4;

DI float silu_f(float v) { return v / (1.f + __expf(-v)); }
DI float4 ld4(const float* p) { return *reinterpret_cast<const float4*>(p); }
DI void st4(float* p, const float4& v) { *reinterpret_cast<float4*>(p) = v; }
DI unsigned short f2bf(float f) {
    unsigned u = __float_as_uint(f);
    unsigned r = (u + 0x7FFFu + ((u >> 16) & 1u)) >> 16;
    return (unsigned short)r;
}

// ---------------------------------------------------------------------------
// Weight pre-pack: w f32 [Co][Ci][3][3] -> pk bf16 [Ci/32][Co][296]
// ---------------------------------------------------------------------------
__global__ void pack_w_kernel(const float* __restrict__ w, unsigned short* __restrict__ pk,
                              int Ci, int Co) {
    int idx = blockIdx.x * 256 + threadIdx.x;
    int total = (Ci >> 5) * Co * 296;
    if (idx >= total) return;
    int e = idx % 296;
    int co = (idx / 296) % Co;
    int ch = idx / (296 * Co);
    unsigned short v = 0;
    if (e < 288) {
        int dydx = e >> 5;
        int cc = e & 31;
        v = f2bf(w[((size_t)co * Ci + (ch << 5) + cc) * 9 + dydx]);
    }
    pk[idx] = v;
}

// ---------------------------------------------------------------------------
// Input pre-pack: f32 NCHW -> bf16 [b][ci/32][H][W][32]
// ---------------------------------------------------------------------------
__global__ void pack_in_kernel(const float* __restrict__ in, unsigned short* __restrict__ pk,
                               int Ci, int HW, int total) {
    int idx = blockIdx.x * 256 + threadIdx.x;
    if (idx >= total) return;
    const int nCh = Ci >> 5;
    int cg = idx & 3;
    int t = idx >> 2;
    int pix = t % HW; t /= HW;
    int ch = t % nCh;
    int b = t / nCh;
    const float* src = in + ((size_t)b * Ci + (ch << 5) + (cg << 3)) * HW + pix;
    unsigned p[4];
#pragma unroll
    for (int j = 0; j < 4; ++j) {
        float v0 = src[(size_t)(2 * j) * HW];
        float v1 = src[(size_t)(2 * j + 1) * HW];
        p[j] = (unsigned)f2bf(v0) | ((unsigned)f2bf(v1) << 16);
    }
    *(uint4*)&pk[(((size_t)b * nCh + ch) * HW + pix) * 32 + (cg << 3)] =
        make_uint4(p[0], p[1], p[2], p[3]);
}

// ---------------------------------------------------------------------------
// MFMA implicit-GEMM 3x3 SAME conv.
// ---------------------------------------------------------------------------
template <int TH, int TW, int BF, int FUSE>
__global__ void __launch_bounds__(256)
conv3x3_mfma(const unsigned short* __restrict__ pin, const unsigned short* __restrict__ wpk,
             float* __restrict__ out, int B, int Ci, int Co, int H, int W,
             const float* __restrict__ ctx, const float* __restrict__ xres) {
    static_assert(TH * TW == 4 * BF * 16, "tile px = 4 waves * BF frags * 16");
    constexpr int TWH = TW + 2;
    constexpr int HP = (TH + 2) * TWH;
    __shared__ __align__(16) unsigned short lin[HP * 40];
    __shared__ __align__(16) unsigned short wls[64 * 296];

    const int nTx = W / TW, nTy = H / TH, nCoG = Co >> 6;
    const int nwg = gridDim.x;
    int wg = (blockIdx.x & 7) * (nwg >> 3) + (blockIdx.x >> 3);
    const int cog = wg % nCoG; wg /= nCoG;
    const int tx = wg % nTx;   wg /= nTx;
    const int ty = wg % nTy;
    const int b = wg / nTy;
    const int ox = tx * TW, oy = ty * TH, co0 = cog << 6;

    const int tid = threadIdx.x;
    const int wave = tid >> 6, lane = tid & 63;
    const int l15 = lane & 15, g = lane >> 4;
    const int wpx = wave * (BF * 16);

    int rr[BF], cc_[BF];
#pragma unroll
    for (int bf = 0; bf < BF; ++bf) {
        int px = wpx + bf * 16 + l15;
        rr[bf] = px / TW;
        cc_[bf] = px % TW;
    }

    f32x4 acc[4][BF];
#pragma unroll
    for (int af = 0; af < 4; ++af)
#pragma unroll
        for (int bf = 0; bf < BF; ++bf) acc[af][bf] = {};

    const int nCh = Ci >> 5;
    const size_t HWs = (size_t)H * W;

    for (int ch = 0; ch < nCh; ++ch) {
#pragma unroll
        for (int it = 0; it < (HP * 4 + 255) / 256; ++it) {
            int e = tid + it * 256;
            if (e < HP * 4) {
                int cg = e & 3;
                int hp = e >> 2;
                int hy = hp / TWH, hx = hp % TWH;
                int gy = oy + hy - 1, gx = ox + hx - 1;
                uint4 v = make_uint4(0, 0, 0, 0);
                if ((unsigned)gy < (unsigned)H && (unsigned)gx < (unsigned)W)
                    v = *(const uint4*)&pin[(((size_t)b * nCh + ch) * H * W
                                            + (size_t)gy * W + gx) * 32 + (cg << 3)];
                *(uint4*)&lin[hp * 40 + (cg << 3)] = v;
            }
        }
        {
            const unsigned short* src = wpk + ((size_t)ch * Co + co0) * 296;
#pragma unroll
            for (int it = 0; it < 10; ++it) {
                int e = tid + it * 256;
                if (e < 2368) *(uint4*)&wls[e * 8] = *(const uint4*)&src[e * 8];
            }
        }
        __syncthreads();

        const unsigned short* wb = &wls[l15 * 296 + g * 8];
#pragma unroll
        for (int dy = 0; dy < 3; ++dy) {
#pragma unroll
            for (int dx = 0; dx < 3; ++dx) {
                const int dydx = dy * 3 + dx;
                bf16x8 a[4];
#pragma unroll
                for (int af = 0; af < 4; ++af)
                    a[af] = *(const bf16x8*)(wb + (af * 16) * 296 + dydx * 32);
                bf16x8 bb[BF];
#pragma unroll
                for (int bf = 0; bf < BF; ++bf)
                    bb[bf] = *(const bf16x8*)&lin[((rr[bf] + dy) * TWH + cc_[bf] + dx) * 40 + g * 8];
#pragma unroll
                for (int af = 0; af < 4; ++af)
#pragma unroll
                    for (int bf = 0; bf < BF; ++bf)
                        acc[af][bf] = __builtin_amdgcn_mfma_f32_16x16x32_bf16(
                            a[af], bb[bf], acc[af][bf], 0, 0, 0);
            }
        }
        __syncthreads();
    }
#pragma unroll
    for (int af = 0; af < 4; ++af) {
#pragma unroll
        for (int bf = 0; bf < BF; ++bf) {
            int px = wpx + bf * 16 + l15;
            int y = oy + px / TW, x = ox + px % TW;
#pragma unroll
            for (int r4 = 0; r4 < 4; ++r4) {
                int co = co0 + af * 16 + (g << 2) + r4;
                size_t base = ((size_t)b * Co + co) * HWs + (size_t)y * W + x;
                float v = acc[af][bf][r4];
                if (FUSE == 1) v = silu_f(v);
                else if (FUSE == 2) v = xres[base] + ctx[base] * (1.f + tanhf(v));
                out[base] = v;
            }
        }
    }
}

// ---------------------------------------------------------------------------
// Direct 3x3 SAME conv, f32 (K12: 64->10).
// ---------------------------------------------------------------------------
template <int TH, int TW, int CO_BLK, int CO_T, int CIC, int FUSE>
__global__ void __launch_bounds__(576)
conv3x3_kernel(const float* __restrict__ in, const float* __restrict__ wgt,
               float* __restrict__ out, int B, int Ci, int Co, int H, int W,
               const float* __restrict__ ctx, const float* __restrict__ xres) {
    constexpr int TWH = TW + 2;
    constexpr int TWP = TW + 3;
    constexpr int SPAT = TH * (TW / 4);
    __shared__ float lin[CIC][TH + 2][TWP];
    __shared__ float wls[CIC][9][CO_BLK];

    const int nTx = W / TW, nTy = H / TH;
    const int nCoG = (Co + CO_BLK - 1) / CO_BLK;
    int bid = blockIdx.x;
    const int cog = bid % nCoG; bid /= nCoG;
    const int tx = bid % nTx;   bid /= nTx;
    const int ty = bid % nTy;
    const int b = bid / nTy;
    const int ox = tx * TW, oy = ty * TH;
    const int co0 = cog * CO_BLK;

    const int tid = threadIdx.x;
    const int cot = tid / SPAT;
    const int sp = tid % SPAT;
    const int r = sp / (TW / 4);
    const int cg = sp % (TW / 4);

    float acc[4][4];
#pragma unroll
    for (int i = 0; i < 4; ++i)
#pragma unroll
        for (int j = 0; j < 4; ++j) acc[i][j] = 0.f;

    for (int ci0 = 0; ci0 < Ci; ci0 += CIC) {
        for (int e = tid; e < CIC * (TH + 2) * TWH; e += SPAT * CO_T) {
            int xx = e % TWH;
            int yy = (e / TWH) % (TH + 2);
            int cc = e / (TWH * (TH + 2));
            int gy = oy - 1 + yy, gx = ox - 1 + xx;
            float v = 0.f;
            if (gy >= 0 && gy < H && gx >= 0 && gx < W)
                v = in[(((size_t)b * Ci + ci0 + cc) * H + gy) * W + gx];
            lin[cc][yy][xx] = v;
        }
        for (int e = tid; e < CIC * 9 * CO_BLK; e += SPAT * CO_T) {
            int col = e % CO_BLK;
            int k = (e / CO_BLK) % 9;
            int cc = e / (CO_BLK * 9);
            int co = co0 + col;
            float v = 0.f;
            if (co < Co) v = wgt[((size_t)co * Ci + ci0 + cc) * 9 + k];
            wls[cc][k][col] = v;
        }
        __syncthreads();
#pragma unroll
        for (int cc = 0; cc < CIC; ++cc) {
            float v0[3][6];
#pragma unroll
            for (int ky = 0; ky < 3; ++ky)
#pragma unroll
                for (int u = 0; u < 6; ++u)
                    v0[ky][u] = lin[cc][r + ky][cg * 4 + u];
#pragma unroll
            for (int ky = 0; ky < 3; ++ky)
#pragma unroll
                for (int kx = 0; kx < 3; ++kx) {
                    const float4 w4 = ld4(&wls[cc][ky * 3 + kx][cot * 4]);
                    const float wv_[4] = {w4.x, w4.y, w4.z, w4.w};
#pragma unroll
                    for (int i = 0; i < 4; ++i)
#pragma unroll
                        for (int j = 0; j < 4; ++j)
                            acc[i][j] = fmaf(wv_[i], v0[ky][kx + j], acc[i][j]);
                }
        }
        __syncthreads();
    }
    const int y = oy + r;
    const int xb = ox + cg * 4;
#pragma unroll
    for (int i = 0; i < 4; ++i) {
        int co = co0 + cot * 4 + i;
        if (co >= Co) continue;
        size_t base = (((size_t)b * Co + co) * H + y) * W + xb;
        float4 res;
        if (FUSE == 2) {
            float4 c4 = ld4(&ctx[base]);
            float4 x4 = ld4(&xres[base]);
            res.x = x4.x + c4.x * (1.f + tanhf(acc[i][0]));
            res.y = x4.y + c4.y * (1.f + tanhf(acc[i][1]));
            res.z = x4.z + c4.z * (1.f + tanhf(acc[i][2]));
            res.w = x4.w + c4.w * (1.f + tanhf(acc[i][3]));
        } else if (FUSE == 1) {
            res.x = silu_f(acc[i][0]); res.y = silu_f(acc[i][1]);
            res.z = silu_f(acc[i][2]); res.w = silu_f(acc[i][3]);
        } else {
            res.x = acc[i][0]; res.y = acc[i][1];
            res.z = acc[i][2]; res.w = acc[i][3];
        }
        st4(&out[base], res);
    }
}

// ---------------------------------------------------------------------------
// Tiled GEMM: out[b][o][m] = act(sum_c W[o][c] * in[b][c][m] + bias[o]).
// ---------------------------------------------------------------------------
template <int ACT>
__global__ void __launch_bounds__(256)
gemm_om(const float* __restrict__ W, const float* __restrict__ bias,
        const float* __restrict__ in, float* __restrict__ out,
        int B, int C, int O, int M, int nOt, int nMt) {
    __shared__ float xs[32][66];
    __shared__ float wls[64][33];
    int bid = blockIdx.x;
    int mt = bid % nMt; bid /= nMt;
    int ot = bid % nOt;
    int b  = bid / nOt;
    int o0 = ot * 64, m0 = mt * 64;
    int tid = threadIdx.x;
    int m_t = tid & 15, o_g = tid >> 4;
    float acc[4][4];
#pragma unroll
    for (int i = 0; i < 4; ++i)
#pragma unroll
        for (int j = 0; j < 4; ++j) acc[i][j] = 0.f;

    for (int c0 = 0; c0 < C; c0 += 32) {
#pragma unroll
        for (int it = 0; it < 8; ++it) {
            int e = tid + it * 256;
            int mm = e & 63, cc = e >> 6;
            float v = 0.f;
            if (m0 + mm < M) v = in[((size_t)b * C + c0 + cc) * M + m0 + mm];
            xs[cc][mm] = v;
        }
#pragma unroll
        for (int it = 0; it < 8; ++it) {
            int e = tid + it * 256;
            int cc = e & 31, ol = e >> 5;
            float v = 0.f;
            if (o0 + ol < O) v = W[(size_t)(o0 + ol) * C + c0 + cc];
            wls[ol][cc] = v;
        }
        __syncthreads();
#pragma unroll
        for (int cc = 0; cc < 32; ++cc) {
            float xv[4], wv[4];
#pragma unroll
            for (int j = 0; j < 4; ++j) xv[j] = xs[cc][j * 16 + m_t];
#pragma unroll
            for (int i = 0; i < 4; ++i) wv[i] = wls[o_g * 4 + i][cc];
#pragma unroll
            for (int i = 0; i < 4; ++i)
#pragma unroll
                for (int j = 0; j < 4; ++j)
                    acc[i][j] = fmaf(wv[i], xv[j], acc[i][j]);
        }
        __syncthreads();
    }
#pragma unroll
    for (int i = 0; i < 4; ++i) {
        int o = o0 + o_g * 4 + i;
        if (o >= O) continue;
        float bv = bias ? bias[o] : 0.f;
#pragma unroll
        for (int j = 0; j < 4; ++j) {
            int m = m0 + j * 16 + m_t;
            if (m >= M) continue;
            float v = acc[i][j] + bv;
            if (ACT == 1) v = silu_f(v);
            out[((size_t)b * O + o) * M + m] = v;
        }
    }
}

// ---------------------------------------------------------------------------
__global__ void psp_kernel(const float* __restrict__ x, float* __restrict__ kf) {
    __shared__ float pl[576];
    int bc = blockIdx.x;
    const float* xp = x + (size_t)bc * 576;
    for (int e = threadIdx.x; e < 576; e += 64) pl[e] = xp[e];
    __syncthreads();
    int m = threadIdx.x;
    if (m < 50) {
        int g, i0;
        if (m < 36)      { g = 6; i0 = m; }
        else if (m < 45) { g = 3; i0 = m - 36; }
        else if (m < 49) { g = 2; i0 = m - 45; }
        else             { g = 1; i0 = 0; }
        int bs = 24 / g;
        int by = i0 / g, bx = i0 % g;
        float s = 0.f;
        for (int yy = 0; yy < bs; ++yy)
            for (int xx = 0; xx < bs; ++xx)
                s += pl[(by * bs + yy) * 24 + bx * bs + xx];
        kf[(size_t)bc * 50 + m] = s / (float)(bs * bs);
    }
}

// ---------------------------------------------------------------------------
__global__ void __launch_bounds__(256)
sim_kernel(const float* __restrict__ q, const float* __restrict__ k,
           float* __restrict__ simg) {
    __shared__ float qs[32][65];
    __shared__ float ks[32][52];
    __shared__ float sm[64][52];
    int b = blockIdx.x / 9, n0 = (blockIdx.x % 9) * 64;
    int tid = threadIdx.x;
    for (int e = tid; e < 32 * 64; e += 256) {
        int c = e >> 6, n = e & 63;
        qs[c][n] = q[((size_t)b * 32 + c) * 576 + n0 + n];
    }
    for (int e = tid; e < 32 * 50; e += 256) {
        int c = e / 50, m = e % 50;
        ks[c][m] = k[((size_t)b * 32 + c) * 50 + m];
    }
    __syncthreads();
    for (int e = tid; e < 64 * 50; e += 256) {
        int n = e / 50, m = e % 50;
        float s = 0.f;
#pragma unroll
        for (int c = 0; c < 32; ++c) s = fmaf(qs[c][n], ks[c][m], s);
        sm[n][m] = s;
    }
    __syncthreads();
    if (tid < 64) {
        float mx = -1e30f;
        for (int m = 0; m < 50; ++m) mx = fmaxf(mx, sm[tid][m]);
        float sum = 0.f;
        for (int m = 0; m < 50; ++m) {
            float e2 = __expf(sm[tid][m] - mx);
            sm[tid][m] = e2;
            sum += e2;
        }
        float inv = 1.f / sum;
        for (int m = 0; m < 50; ++m) sm[tid][m] *= inv;
    }
    __syncthreads();
    for (int e = tid; e < 64 * 50; e += 256) {
        int n = e / 50, m = e % 50;
        simg[((size_t)b * 576 + n0 + n) * 50 + m] = sm[n][m];
    }
}

// ---------------------------------------------------------------------------
__global__ void __launch_bounds__(256)
ctx_kernel(const float* __restrict__ v, const float* __restrict__ simg,
           float* __restrict__ ctx) {
    __shared__ float vs[128][54];
    __shared__ float ss[64][54];
    int blk = blockIdx.x;
    int ct = blk & 3; blk >>= 2;
    int nt = blk % 9;
    int b = blk / 9;
    int c0 = ct * 128, n0 = nt * 64;
    int tid = threadIdx.x;
    for (int e = tid; e < 128 * 50; e += 256) {
        int c = e / 50, m = e % 50;
        vs[c][m] = v[((size_t)b * 512 + c0 + c) * 50 + m];
    }
    for (int e = tid; e < 64 * 50; e += 256) {
        int n = e / 50, m = e % 50;
        ss[n][m] = simg[((size_t)b * 576 + n0 + n) * 50 + m];
    }
    __syncthreads();
    int n_t = tid & 15;
    int c_t = tid >> 4;
    float acc[8][4];
#pragma unroll
    for (int i = 0; i < 8; ++i)
#pragma unroll
        for (int j = 0; j < 4; ++j) acc[i][j] = 0.f;
    for (int m = 0; m < 50; ++m) {
        float sv[4];
#pragma unroll
        for (int j = 0; j < 4; ++j) sv[j] = ss[j * 16 + n_t][m];
#pragma unroll
        for (int i = 0; i < 8; ++i) {
            float vv = vs[c_t * 8 + i][m];
#pragma unroll
            for (int j = 0; j < 4; ++j) acc[i][j] = fmaf(vv, sv[j], acc[i][j]);
        }
    }
#pragma unroll
    for (int i = 0; i < 8; ++i)
#pragma unroll
        for (int j = 0; j < 4; ++j)
            ctx[((size_t)b * 512 + c0 + c_t * 8 + i) * 576 + n0 + j * 16 + n_t] = acc[i][j];
}

// ---------------------------------------------------------------------------
__global__ void __launch_bounds__(256)
conv1x1_cat_kernel(const float* __restrict__ cp, const float* __restrict__ sp,
                   const float* __restrict__ w, float* __restrict__ out) {
    __shared__ float ins[8][128];
    __shared__ float wls[8][64];
    int bid = blockIdx.x;
    int mt = bid % 72;
    int b = bid / 72;
    int m0 = mt * 128;
    int tid = threadIdx.x;
    int ml = tid & 31;
    int col = (tid >> 5) * 8;
    float acc[8][4];
#pragma unroll
    for (int i = 0; i < 8; ++i)
#pragma unroll
        for (int j = 0; j < 4; ++j) acc[i][j] = 0.f;
    for (int c0 = 0; c0 < 512; c0 += 8) {
        {
            int e = tid * 4;
            int cl = e >> 7, mm = e & 127;
            int cidx = c0 + cl;
            const float* src = (cidx < 256)
                ? (cp + ((size_t)b * 256 + cidx) * 9216 + m0 + mm)
                : (sp + ((size_t)b * 256 + (cidx - 256)) * 9216 + m0 + mm);
            st4(&ins[cl][mm], ld4(src));
        }
        for (int e = tid; e < 512; e += 256) {
            int cl = e & 7;
            int o = e >> 3;
            wls[cl][o] = w[(size_t)o * 512 + c0 + cl];
        }
        __syncthreads();
#pragma unroll
        for (int cl = 0; cl < 8; ++cl) {
            float4 w0 = ld4(&wls[cl][col]);
            float4 w1 = ld4(&wls[cl][col + 4]);
            float av[4];
#pragma unroll
            for (int j = 0; j < 4; ++j) av[j] = ins[cl][ml + 32 * j];
            float wv_[8] = {w0.x, w0.y, w0.z, w0.w, w1.x, w1.y, w1.z, w1.w};
#pragma unroll
            for (int oo = 0; oo < 8; ++oo)
#pragma unroll
                for (int j = 0; j < 4; ++j)
                    acc[oo][j] = fmaf(wv_[oo], av[j], acc[oo][j]);
        }
        __syncthreads();
    }
#pragma unroll
    for (int oo = 0; oo < 8; ++oo)
#pragma unroll
        for (int j = 0; j < 4; ++j)
            out[((size_t)b * 64 + col + oo) * 9216 + m0 + ml + 32 * j] = silu_f(acc[oo][j]);
}

// ---------------------------------------------------------------------------
__global__ void upsample_kernel(const float* __restrict__ in, float* __restrict__ out) {
    int idx = blockIdx.x * 256 + threadIdx.x;
    const int total = 8 * 256 * 96 * 96;
    if (idx >= total) return;
    int x = idx % 96;
    int y = (idx / 96) % 96;
    int p = idx / 9216;
    float fy = y * (23.f / 95.f);
    float fx = x * (23.f / 95.f);
    int y0 = (int)fy; if (y0 > 22) y0 = 22;
    int x0 = (int)fx; if (x0 > 22) x0 = 22;
    float wy = fy - y0, wx = fx - x0;
    const float* ip = in + (size_t)p * 576;
    float a = ip[y0 * 24 + x0], b = ip[y0 * 24 + x0 + 1];
    float c = ip[(y0 + 1) * 24 + x0], d = ip[(y0 + 1) * 24 + x0 + 1];
    float l = a * (1.f - wy) + c * wy;
    float r = b * (1.f - wy) + d * wy;
    out[idx] = l * (1.f - wx) + r * wx;
}

// ---------------------------------------------------------------------------
// grid_sample prep
// ---------------------------------------------------------------------------
DI void gs_params(int x, int y, float ox, float oy, float4* w, int2* p) {
    const float S = 47.5f / 96.f;
    float px = x + ox * S;
    float py = y + oy * S;
    float fx0 = floorf(px), fy0 = floorf(py);
    float wx = px - fx0, wy = py - fy0;
    float vx0 = (fx0 >= 0.f && fx0 <= 95.f) ? 1.f : 0.f;
    float vx1 = (fx0 >= -1.f && fx0 <= 94.f) ? 1.f : 0.f;
    float vy0 = (fy0 >= 0.f && fy0 <= 95.f) ? 1.f : 0.f;
    float vy1 = (fy0 >= -1.f && fy0 <= 94.f) ? 1.f : 0.f;
    int x0 = (int)fminf(fmaxf(fx0, 0.f), 95.f);
    int x1 = (int)fminf(fmaxf(fx0 + 1.f, 0.f), 95.f);
    int y0 = (int)fminf(fmaxf(fy0, 0.f), 95.f);
    int y1 = (int)fminf(fmaxf(fy0 + 1.f, 0.f), 95.f);
    w->x = (1.f - wx) * (1.f - wy) * vx0 * vy0;
    w->y = wx * (1.f - wy) * vx1 * vy0;
    w->z = (1.f - wx) * wy * vx0 * vy1;
    w->w = wx * wy * vx1 * vy1;
    *p = make_int2(x0 | (x1 << 16), y0 | (y1 << 16));
}

__global__ void gprep_kernel(const float* __restrict__ cr, float4* __restrict__ wpar,
                             int2* __restrict__ ipk, float2* __restrict__ attp) {
    int idx = blockIdx.x * 256 + threadIdx.x;
    if (idx >= 8 * 2 * 9216) return;
    int pix = idx % 9216;
    int g = (idx / 9216) & 1;
    int b = idx / 18432;
    const float* crb = cr + (size_t)b * 10 * 9216 + pix;
    int x = pix % 96, y = pix / 96;
    float4 w; int2 p;
    gs_params(x, y, crb[(2 * g) * 9216], crb[(2 * g + 1) * 9216], &w, &p);
    size_t el = ((size_t)g * 8 + b) * 9216 + pix;
    wpar[el] = w; ipk[el] = p;
    gs_params(x, y, crb[(4 + 2 * g) * 9216], crb[(5 + 2 * g) * 9216], &w, &p);
    size_t eh = ((size_t)(2 + g) * 8 + b) * 9216 + pix;
    wpar[eh] = w; ipk[eh] = p;
    if (g == 0) {
        float2 at;
        at.x = 1.f + tanhf(crb[8 * 9216]);
        at.y = 1.f + tanhf(crb[9 * 9216]);
        attp[(size_t)b * 9216 + pix] = at;
    }
}

// ---------------------------------------------------------------------------
// gather-only grid_sample blend; CPT channels per thread (params shared).
// ---------------------------------------------------------------------------
template <int CPT>
__global__ void __launch_bounds__(256)
gsample2_kernel(const float* __restrict__ cp, const float* __restrict__ sp,
                const float4* __restrict__ wpar, const int2* __restrict__ ipk,
                const float2* __restrict__ attp, float* __restrict__ p5o) {
    const int nCB = 256 / CPT;
    int idx = blockIdx.x * 256 + threadIdx.x;
    const int total = 8 * nCB * 9216;
    if (idx >= total) return;
    int pix = idx % 9216;
    int cb = (idx / 9216) % nCB;
    int b = idx / (9216 * nCB);
    int c0 = cb * CPT;
    int g = c0 >> 7;
    size_t el = ((size_t)g * 8 + b) * 9216 + pix;
    size_t eh = ((size_t)(2 + g) * 8 + b) * 9216 + pix;
    float4 wl = wpar[el]; int2 pl = ipk[el];
    float4 wh = wpar[eh]; int2 ph = ipk[eh];
    float2 at = attp[(size_t)b * 9216 + pix];
    int l00 = (pl.y & 0xffff) * 96 + (pl.x & 0xffff);
    int l01 = (pl.y & 0xffff) * 96 + (pl.x >> 16);
    int l10 = (pl.y >> 16) * 96 + (pl.x & 0xffff);
    int l11 = (pl.y >> 16) * 96 + (pl.x >> 16);
    int h00 = (ph.y & 0xffff) * 96 + (ph.x & 0xffff);
    int h01 = (ph.y & 0xffff) * 96 + (ph.x >> 16);
    int h10 = (ph.y >> 16) * 96 + (ph.x & 0xffff);
    int h11 = (ph.y >> 16) * 96 + (ph.x >> 16);
    const float* cpp = cp + ((size_t)b * 256 + c0) * 9216;
    const float* spp = sp + ((size_t)b * 256 + c0) * 9216;
    float* op = p5o + ((size_t)b * 256 + c0) * 9216 + pix;
#pragma unroll
    for (int i = 0; i < CPT; ++i) {
        float cps = wl.x * cpp[l00] + wl.y * cpp[l01] + wl.z * cpp[l10] + wl.w * cpp[l11];
        float sps = wh.x * spp[h00] + wh.y * spp[h01] + wh.z * spp[h10] + wh.w * spp[h11];
        *op = sps * at.x + cps * at.y;
        cpp += 9216; spp += 9216; op += 9216;
    }
}

// ---------------------------------------------------------------------------
extern "C" void kernel_launch(void* const* d_in, const int* in_sizes, int n_in,
                              void* d_out, int out_size, void* d_ws, size_t ws_size,
                              hipStream_t stream) {
    const float* p3    = (const float*)d_in[0];
    const float* p5    = (const float*)d_in[1];
    const float* w_red = (const float*)d_in[2];
    const float* wq    = (const float*)d_in[3];
    const float* bq    = (const float*)d_in[4];
    const float* wk    = (const float*)d_in[5];
    const float* bk    = (const float*)d_in[6];
    const float* wv    = (const float*)d_in[7];
    const float* bv    = (const float*)d_in[8];
    const float* la_w1 = (const float*)d_in[9];
    const float* la_w2 = (const float*)d_in[10];
    const float* w32   = (const float*)d_in[11];
    const float* w8    = (const float*)d_in[12];
    const float* woff1 = (const float*)d_in[13];
    const float* woff2 = (const float*)d_in[14];

    float* out = (float*)d_out;
    float* p3o = out;                 // [8,512,24,24]
    float* p5o = out + 2359296;       // [8,256,96,96]

    float* ws = (float*)d_ws;
    float* x_   = ws + 0;
    float* ctx  = ws + 2359296;
    float* q    = ws + 4718592;
    float* kf   = ws + 4866048;
    float* km   = ws + 5070848;
    float* vm   = ws + 5083648;
    float* la1  = ws + 5288448;
    float* sp24 = ws + 5583360;
    float* sp96 = ws + 6763008;
    float* cp   = ws + 25637376;
    unsigned short* wred_pk = (unsigned short*)(ws + 44511744);
    unsigned short* w32_pk  = (unsigned short*)(ws + 45724160);
    unsigned short* w8_pk   = (unsigned short*)(ws + 46330368);
    unsigned short* p5_pk   = (unsigned short*)(ws + 6763008);
    unsigned short* p3_pk   = (unsigned short*)(ws + 16200192);
    unsigned short* la1_pk  = (unsigned short*)(ws + 17379840);
    unsigned short* wla2_pk = (unsigned short*)(ws + 17527296);
    float* simg = la1;
    float* t64  = ws + 0;
    float* cr   = ws + 4718592;
    float4* wpar = (float4*)(ws + 0);
    int2*   ipk  = (int2*)(ws + 1179648);
    float2* attp = (float2*)(ws + 1769472);

    // P0: pack weights
    pack_w_kernel<<<dim3((2424832 + 255) / 256), dim3(256), 0, stream>>>(w_red, wred_pk, 512, 512);
    pack_w_kernel<<<dim3((1212416 + 255) / 256), dim3(256), 0, stream>>>(w32, w32_pk, 512, 256);
    pack_w_kernel<<<dim3((606208 + 255) / 256), dim3(256), 0, stream>>>(w8, w8_pk, 256, 256);
    pack_w_kernel<<<dim3((303104 + 255) / 256), dim3(256), 0, stream>>>(la_w2, wla2_pk, 64, 512);
    // P1: pack inputs
    pack_in_kernel<<<dim3(2359296 / 256), dim3(256), 0, stream>>>(p5, p5_pk, 256, 9216, 2359296);
    pack_in_kernel<<<dim3(294912 / 256), dim3(256), 0, stream>>>(p3, p3_pk, 512, 576, 294912);

    // K10: cp = silu(conv3x3(p5, w8)) 256->256, 96x96  [MFMA, BF=4 16x16 tile]
    conv3x3_mfma<16, 16, 4, 1><<<dim3(1152), dim3(256), 0, stream>>>(
        p5_pk, w8_pk, cp, 8, 256, 256, 96, 96, nullptr, nullptr);
    // K1: x = silu(conv3x3(p3, w_red)) 512->512, 24x24  [MFMA]
    conv3x3_mfma<8, 24, 3, 1><<<dim3(192), dim3(256), 0, stream>>>(
        p3_pk, wred_pk, x_, 8, 512, 512, 24, 24, nullptr, nullptr);
    // K2: q = conv1x1(x, wq) + bq
    gemm_om<0><<<dim3(8 * 1 * 9), dim3(256), 0, stream>>>(
        wq, bq, x_, q, 8, 512, 32, 576, 1, 9);
    // K3: kfeat = psp(x)
    psp_kernel<<<dim3(8 * 512), dim3(64), 0, stream>>>(x_, kf);
    // K4: k, v projections
    gemm_om<0><<<dim3(8 * 1 * 1), dim3(256), 0, stream>>>(
        wk, bk, kf, km, 8, 512, 32, 50, 1, 1);
    gemm_om<0><<<dim3(8 * 8 * 1), dim3(256), 0, stream>>>(
        wv, bv, kf, vm, 8, 512, 512, 50, 8, 1);
    // K5a: sim = softmax(q^T k)
    sim_kernel<<<dim3(72), dim3(256), 0, stream>>>(q, km, simg);
    // K5b: ctx = v @ sim^T
    ctx_kernel<<<dim3(288), dim3(256), 0, stream>>>(vm, simg, ctx);
    // K6: la1 = silu(conv1x1(ctx, la_w1))
    gemm_om<1><<<dim3(8 * 1 * 9), dim3(256), 0, stream>>>(
        la_w1, nullptr, ctx, la1, 8, 512, 64, 576, 1, 9);
    // pack la1
    pack_in_kernel<<<dim3(36864 / 256), dim3(256), 0, stream>>>(la1, la1_pk, 64, 576, 36864);
    // K7: p3o = x + ctx*(1 + tanh(conv3x3(la1, la_w2)))  [MFMA FUSE2]
    conv3x3_mfma<8, 24, 3, 2><<<dim3(192), dim3(256), 0, stream>>>(
        la1_pk, wla2_pk, p3o, 8, 64, 512, 24, 24, ctx, x_);
    // pack p3o
    pack_in_kernel<<<dim3(294912 / 256), dim3(256), 0, stream>>>(p3o, p3_pk, 512, 576, 294912);
    // K8: sp24 = silu(conv3x3(p3o, w32)) 512->256  [MFMA]
    conv3x3_mfma<8, 24, 3, 1><<<dim3(96), dim3(256), 0, stream>>>(
        p3_pk, w32_pk, sp24, 8, 512, 256, 24, 24, nullptr, nullptr);
    // K9: sp96 = bilinear upsample
    upsample_kernel<<<dim3(8 * 256 * 9216 / 256), dim3(256), 0, stream>>>(sp24, sp96);
    // K11: t64 = silu(conv1x1(concat[cp, sp96], woff1))
    conv1x1_cat_kernel<<<dim3(8 * 72), dim3(256), 0, stream>>>(cp, sp96, woff1, t64);
    // K12: cr = conv3x3(t64, woff2) 64->10
    conv3x3_kernel<8, 32, 12, 3, 4, 0><<<dim3(288), dim3(192), 0, stream>>>(
        t64, woff2, cr, 8, 64, 10, 96, 96, nullptr, nullptr);
    // K13a: grid-sample params + att
    gprep_kernel<<<dim3(576), dim3(256), 0, stream>>>(cr, wpar, ipk, attp);
    // K13b: p5o = gather blend, 4 channels/thread
    gsample2_kernel<4><<<dim3(8 * 64 * 9216 / 256), dim3(256), 0, stream>>>(
        cp, sp96, wpar, ipk, attp, p5o);
}

// Round 7
// 995.129 us; speedup vs baseline: 4.0075x; 1.0258x over previous
//
#include <hip/hip_runtime.h>
#include <math.h>

#define DI __device__ __forceinline__

typedef __attribute__((ext_vector_type(8))) short bf16x8;
typedef __attribute__((ext_vector_type(4))) float f32x4;

DI float silu_f(float v) { return v / (1.f + __expf(-v)); }
DI float4 ld4(const float* p) { return *reinterpret_cast<const float4*>(p); }
DI void st4(float* p, const float4& v) { *reinterpret_cast<float4*>(p) = v; }
DI unsigned short f2bf(float f) {
    unsigned u = __float_as_uint(f);
    unsigned r = (u + 0x7FFFu + ((u >> 16) & 1u)) >> 16;
    return (unsigned short)r;
}

// ---------------------------------------------------------------------------
// Weight pre-pack v2: w f32 [Co][Ci][3][3] -> pk bf16
// [Ci/32][Co/COG][9][COG][32]; wave A-frag read = 1KB contiguous.
// ---------------------------------------------------------------------------
__global__ void pack_w2_kernel(const float* __restrict__ w, unsigned short* __restrict__ pk,
                               int Ci, int Co, int COG) {
    int idx = blockIdx.x * 256 + threadIdx.x;
    int total = Ci * Co * 9;
    if (idx >= total) return;
    int cc = idx & 31;
    int t = idx >> 5;
    int col = t % COG; t /= COG;
    int dydx = t % 9;  t /= 9;
    int nCoG = Co / COG;
    int cog = t % nCoG;
    int ch = t / nCoG;
    int co = cog * COG + col;
    pk[idx] = f2bf(w[((size_t)co * Ci + (ch << 5) + cc) * 9 + dydx]);
}

// ---------------------------------------------------------------------------
// Input pre-pack: f32 NCHW -> bf16 [b][ci/32][H][W][32]
// ---------------------------------------------------------------------------
__global__ void pack_in_kernel(const float* __restrict__ in, unsigned short* __restrict__ pk,
                               int Ci, int HW, int total) {
    int idx = blockIdx.x * 256 + threadIdx.x;
    if (idx >= total) return;
    const int nCh = Ci >> 5;
    int cg = idx & 3;
    int t = idx >> 2;
    int pix = t % HW; t /= HW;
    int ch = t % nCh;
    int b = t / nCh;
    const float* src = in + ((size_t)b * Ci + (ch << 5) + (cg << 3)) * HW + pix;
    unsigned p[4];
#pragma unroll
    for (int j = 0; j < 4; ++j) {
        float v0 = src[(size_t)(2 * j) * HW];
        float v1 = src[(size_t)(2 * j + 1) * HW];
        p[j] = (unsigned)f2bf(v0) | ((unsigned)f2bf(v1) << 16);
    }
    *(uint4*)&pk[(((size_t)b * nCh + ch) * HW + pix) * 32 + (cg << 3)] =
        make_uint4(p[0], p[1], p[2], p[3]);
}

// ---------------------------------------------------------------------------
// MFMA implicit-GEMM 3x3 SAME conv, v2: weights read from L2 (no weight LDS).
// Block: COG=WCO*16 co x (4*BF*16)px, 4 waves. acc[WCO][BF].
// FUSE: 0 none, 1 SiLU, 2 p3o epilogue. Grid divisible by 8 (XCD swizzle).
// ---------------------------------------------------------------------------
template <int TH, int TW, int BF, int WCO, int FUSE>
__global__ void __launch_bounds__(256)
conv3x3_mfma2(const unsigned short* __restrict__ pin, const unsigned short* __restrict__ wpk,
              float* __restrict__ out, int B, int Ci, int Co, int H, int W,
              const float* __restrict__ ctx, const float* __restrict__ xres) {
    static_assert(TH * TW == 4 * BF * 16, "tile px = 4 waves * BF frags * 16");
    constexpr int COG = WCO * 16;
    constexpr int TWH = TW + 2;
    constexpr int HP = (TH + 2) * TWH;
    __shared__ __align__(16) unsigned short lin[HP * 40];

    const int nTx = W / TW, nTy = H / TH, nCoG = Co / COG;
    const int nwg = gridDim.x;
    int wg = (blockIdx.x & 7) * (nwg >> 3) + (blockIdx.x >> 3);
    const int cog = wg % nCoG; wg /= nCoG;
    const int tx = wg % nTx;   wg /= nTx;
    const int ty = wg % nTy;
    const int b = wg / nTy;
    const int ox = tx * TW, oy = ty * TH, co0 = cog * COG;

    const int tid = threadIdx.x;
    const int wave = tid >> 6, lane = tid & 63;
    const int l15 = lane & 15, g = lane >> 4;
    const int wpx = wave * (BF * 16);

    int rr[BF], cc_[BF];
#pragma unroll
    for (int bf = 0; bf < BF; ++bf) {
        int px = wpx + bf * 16 + l15;
        rr[bf] = px / TW;
        cc_[bf] = px % TW;
    }

    f32x4 acc[WCO][BF];
#pragma unroll
    for (int af = 0; af < WCO; ++af)
#pragma unroll
        for (int bf = 0; bf < BF; ++bf) acc[af][bf] = {};

    const int nCh = Ci >> 5;
    const size_t HWs = (size_t)H * W;

    for (int ch = 0; ch < nCh; ++ch) {
        // ---- stage input: HP px * 32cc, 16B per thread-iter ----
#pragma unroll
        for (int it = 0; it < (HP * 4 + 255) / 256; ++it) {
            int e = tid + it * 256;
            if (e < HP * 4) {
                int cg = e & 3;
                int hp = e >> 2;
                int hy = hp / TWH, hx = hp % TWH;
                int gy = oy + hy - 1, gx = ox + hx - 1;
                uint4 v = make_uint4(0, 0, 0, 0);
                if ((unsigned)gy < (unsigned)H && (unsigned)gx < (unsigned)W)
                    v = *(const uint4*)&pin[(((size_t)b * nCh + ch) * H * W
                                            + (size_t)gy * W + gx) * 32 + (cg << 3)];
                *(uint4*)&lin[hp * 40 + (cg << 3)] = v;
            }
        }
        __syncthreads();

        // weights: [ch][cog][dydx][COG][32], lane (l15,g) af -> contiguous 1KB/af
        const unsigned short* wbase =
            wpk + ((((size_t)ch * nCoG + cog) * 9) * COG + l15) * 32 + g * 8;
#pragma unroll
        for (int dy = 0; dy < 3; ++dy) {
#pragma unroll
            for (int dx = 0; dx < 3; ++dx) {
                const int dydx = dy * 3 + dx;
                bf16x8 a[WCO];
#pragma unroll
                for (int af = 0; af < WCO; ++af)
                    a[af] = *(const bf16x8*)(wbase + ((size_t)dydx * COG + af * 16) * 32);
                bf16x8 bb[BF];
#pragma unroll
                for (int bf = 0; bf < BF; ++bf)
                    bb[bf] = *(const bf16x8*)&lin[((rr[bf] + dy) * TWH + cc_[bf] + dx) * 40 + g * 8];
#pragma unroll
                for (int af = 0; af < WCO; ++af)
#pragma unroll
                    for (int bf = 0; bf < BF; ++bf)
                        acc[af][bf] = __builtin_amdgcn_mfma_f32_16x16x32_bf16(
                            a[af], bb[bf], acc[af][bf], 0, 0, 0);
            }
        }
        __syncthreads();
    }
    // ---- epilogue: D col = lane&15 (px), row = 4*(lane>>4)+reg (co) ----
#pragma unroll
    for (int af = 0; af < WCO; ++af) {
#pragma unroll
        for (int bf = 0; bf < BF; ++bf) {
            int px = wpx + bf * 16 + l15;
            int y = oy + px / TW, x = ox + px % TW;
#pragma unroll
            for (int r4 = 0; r4 < 4; ++r4) {
                int co = co0 + af * 16 + (g << 2) + r4;
                size_t base = ((size_t)b * Co + co) * HWs + (size_t)y * W + x;
                float v = acc[af][bf][r4];
                if (FUSE == 1) v = silu_f(v);
                else if (FUSE == 2) v = xres[base] + ctx[base] * (1.f + tanhf(v));
                out[base] = v;
            }
        }
    }
}

// ---------------------------------------------------------------------------
// Direct 3x3 SAME conv, f32 (K12: 64->10).
// ---------------------------------------------------------------------------
template <int TH, int TW, int CO_BLK, int CO_T, int CIC, int FUSE>
__global__ void __launch_bounds__(576)
conv3x3_kernel(const float* __restrict__ in, const float* __restrict__ wgt,
               float* __restrict__ out, int B, int Ci, int Co, int H, int W,
               const float* __restrict__ ctx, const float* __restrict__ xres) {
    constexpr int TWH = TW + 2;
    constexpr int TWP = TW + 3;
    constexpr int SPAT = TH * (TW / 4);
    __shared__ float lin[CIC][TH + 2][TWP];
    __shared__ float wls[CIC][9][CO_BLK];

    const int nTx = W / TW, nTy = H / TH;
    const int nCoG = (Co + CO_BLK - 1) / CO_BLK;
    int bid = blockIdx.x;
    const int cog = bid % nCoG; bid /= nCoG;
    const int tx = bid % nTx;   bid /= nTx;
    const int ty = bid % nTy;
    const int b = bid / nTy;
    const int ox = tx * TW, oy = ty * TH;
    const int co0 = cog * CO_BLK;

    const int tid = threadIdx.x;
    const int cot = tid / SPAT;
    const int sp = tid % SPAT;
    const int r = sp / (TW / 4);
    const int cg = sp % (TW / 4);

    float acc[4][4];
#pragma unroll
    for (int i = 0; i < 4; ++i)
#pragma unroll
        for (int j = 0; j < 4; ++j) acc[i][j] = 0.f;

    for (int ci0 = 0; ci0 < Ci; ci0 += CIC) {
        for (int e = tid; e < CIC * (TH + 2) * TWH; e += SPAT * CO_T) {
            int xx = e % TWH;
            int yy = (e / TWH) % (TH + 2);
            int cc = e / (TWH * (TH + 2));
            int gy = oy - 1 + yy, gx = ox - 1 + xx;
            float v = 0.f;
            if (gy >= 0 && gy < H && gx >= 0 && gx < W)
                v = in[(((size_t)b * Ci + ci0 + cc) * H + gy) * W + gx];
            lin[cc][yy][xx] = v;
        }
        for (int e = tid; e < CIC * 9 * CO_BLK; e += SPAT * CO_T) {
            int col = e % CO_BLK;
            int k = (e / CO_BLK) % 9;
            int cc = e / (CO_BLK * 9);
            int co = co0 + col;
            float v = 0.f;
            if (co < Co) v = wgt[((size_t)co * Ci + ci0 + cc) * 9 + k];
            wls[cc][k][col] = v;
        }
        __syncthreads();
#pragma unroll
        for (int cc = 0; cc < CIC; ++cc) {
            float v0[3][6];
#pragma unroll
            for (int ky = 0; ky < 3; ++ky)
#pragma unroll
                for (int u = 0; u < 6; ++u)
                    v0[ky][u] = lin[cc][r + ky][cg * 4 + u];
#pragma unroll
            for (int ky = 0; ky < 3; ++ky)
#pragma unroll
                for (int kx = 0; kx < 3; ++kx) {
                    const float4 w4 = ld4(&wls[cc][ky * 3 + kx][cot * 4]);
                    const float wv_[4] = {w4.x, w4.y, w4.z, w4.w};
#pragma unroll
                    for (int i = 0; i < 4; ++i)
#pragma unroll
                        for (int j = 0; j < 4; ++j)
                            acc[i][j] = fmaf(wv_[i], v0[ky][kx + j], acc[i][j]);
                }
        }
        __syncthreads();
    }
    const int y = oy + r;
    const int xb = ox + cg * 4;
#pragma unroll
    for (int i = 0; i < 4; ++i) {
        int co = co0 + cot * 4 + i;
        if (co >= Co) continue;
        size_t base = (((size_t)b * Co + co) * H + y) * W + xb;
        float4 res;
        if (FUSE == 2) {
            float4 c4 = ld4(&ctx[base]);
            float4 x4 = ld4(&xres[base]);
            res.x = x4.x + c4.x * (1.f + tanhf(acc[i][0]));
            res.y = x4.y + c4.y * (1.f + tanhf(acc[i][1]));
            res.z = x4.z + c4.z * (1.f + tanhf(acc[i][2]));
            res.w = x4.w + c4.w * (1.f + tanhf(acc[i][3]));
        } else if (FUSE == 1) {
            res.x = silu_f(acc[i][0]); res.y = silu_f(acc[i][1]);
            res.z = silu_f(acc[i][2]); res.w = silu_f(acc[i][3]);
        } else {
            res.x = acc[i][0]; res.y = acc[i][1];
            res.z = acc[i][2]; res.w = acc[i][3];
        }
        st4(&out[base], res);
    }
}

// ---------------------------------------------------------------------------
// Tiled GEMM: out[b][o][m] = act(sum_c W[o][c] * in[b][c][m] + bias[o]).
// ---------------------------------------------------------------------------
template <int ACT>
__global__ void __launch_bounds__(256)
gemm_om(const float* __restrict__ W, const float* __restrict__ bias,
        const float* __restrict__ in, float* __restrict__ out,
        int B, int C, int O, int M, int nOt, int nMt) {
    __shared__ float xs[32][66];
    __shared__ float wls[64][33];
    int bid = blockIdx.x;
    int mt = bid % nMt; bid /= nMt;
    int ot = bid % nOt;
    int b  = bid / nOt;
    int o0 = ot * 64, m0 = mt * 64;
    int tid = threadIdx.x;
    int m_t = tid & 15, o_g = tid >> 4;
    float acc[4][4];
#pragma unroll
    for (int i = 0; i < 4; ++i)
#pragma unroll
        for (int j = 0; j < 4; ++j) acc[i][j] = 0.f;

    for (int c0 = 0; c0 < C; c0 += 32) {
#pragma unroll
        for (int it = 0; it < 8; ++it) {
            int e = tid + it * 256;
            int mm = e & 63, cc = e >> 6;
            float v = 0.f;
            if (m0 + mm < M) v = in[((size_t)b * C + c0 + cc) * M + m0 + mm];
            xs[cc][mm] = v;
        }
#pragma unroll
        for (int it = 0; it < 8; ++it) {
            int e = tid + it * 256;
            int cc = e & 31, ol = e >> 5;
            float v = 0.f;
            if (o0 + ol < O) v = W[(size_t)(o0 + ol) * C + c0 + cc];
            wls[ol][cc] = v;
        }
        __syncthreads();
#pragma unroll
        for (int cc = 0; cc < 32; ++cc) {
            float xv[4], wv[4];
#pragma unroll
            for (int j = 0; j < 4; ++j) xv[j] = xs[cc][j * 16 + m_t];
#pragma unroll
            for (int i = 0; i < 4; ++i) wv[i] = wls[o_g * 4 + i][cc];
#pragma unroll
            for (int i = 0; i < 4; ++i)
#pragma unroll
                for (int j = 0; j < 4; ++j)
                    acc[i][j] = fmaf(wv[i], xv[j], acc[i][j]);
        }
        __syncthreads();
    }
#pragma unroll
    for (int i = 0; i < 4; ++i) {
        int o = o0 + o_g * 4 + i;
        if (o >= O) continue;
        float bv = bias ? bias[o] : 0.f;
#pragma unroll
        for (int j = 0; j < 4; ++j) {
            int m = m0 + j * 16 + m_t;
            if (m >= M) continue;
            float v = acc[i][j] + bv;
            if (ACT == 1) v = silu_f(v);
            out[((size_t)b * O + o) * M + m] = v;
        }
    }
}

// ---------------------------------------------------------------------------
__global__ void psp_kernel(const float* __restrict__ x, float* __restrict__ kf) {
    __shared__ float pl[576];
    int bc = blockIdx.x;
    const float* xp = x + (size_t)bc * 576;
    for (int e = threadIdx.x; e < 576; e += 64) pl[e] = xp[e];
    __syncthreads();
    int m = threadIdx.x;
    if (m < 50) {
        int g, i0;
        if (m < 36)      { g = 6; i0 = m; }
        else if (m < 45) { g = 3; i0 = m - 36; }
        else if (m < 49) { g = 2; i0 = m - 45; }
        else             { g = 1; i0 = 0; }
        int bs = 24 / g;
        int by = i0 / g, bx = i0 % g;
        float s = 0.f;
        for (int yy = 0; yy < bs; ++yy)
            for (int xx = 0; xx < bs; ++xx)
                s += pl[(by * bs + yy) * 24 + bx * bs + xx];
        kf[(size_t)bc * 50 + m] = s / (float)(bs * bs);
    }
}

// ---------------------------------------------------------------------------
__global__ void __launch_bounds__(256)
sim_kernel(const float* __restrict__ q, const float* __restrict__ k,
           float* __restrict__ simg) {
    __shared__ float qs[32][65];
    __shared__ float ks[32][52];
    __shared__ float sm[64][52];
    int b = blockIdx.x / 9, n0 = (blockIdx.x % 9) * 64;
    int tid = threadIdx.x;
    for (int e = tid; e < 32 * 64; e += 256) {
        int c = e >> 6, n = e & 63;
        qs[c][n] = q[((size_t)b * 32 + c) * 576 + n0 + n];
    }
    for (int e = tid; e < 32 * 50; e += 256) {
        int c = e / 50, m = e % 50;
        ks[c][m] = k[((size_t)b * 32 + c) * 50 + m];
    }
    __syncthreads();
    for (int e = tid; e < 64 * 50; e += 256) {
        int n = e / 50, m = e % 50;
        float s = 0.f;
#pragma unroll
        for (int c = 0; c < 32; ++c) s = fmaf(qs[c][n], ks[c][m], s);
        sm[n][m] = s;
    }
    __syncthreads();
    if (tid < 64) {
        float mx = -1e30f;
        for (int m = 0; m < 50; ++m) mx = fmaxf(mx, sm[tid][m]);
        float sum = 0.f;
        for (int m = 0; m < 50; ++m) {
            float e2 = __expf(sm[tid][m] - mx);
            sm[tid][m] = e2;
            sum += e2;
        }
        float inv = 1.f / sum;
        for (int m = 0; m < 50; ++m) sm[tid][m] *= inv;
    }
    __syncthreads();
    for (int e = tid; e < 64 * 50; e += 256) {
        int n = e / 50, m = e % 50;
        simg[((size_t)b * 576 + n0 + n) * 50 + m] = sm[n][m];
    }
}

// ---------------------------------------------------------------------------
__global__ void __launch_bounds__(256)
ctx_kernel(const float* __restrict__ v, const float* __restrict__ simg,
           float* __restrict__ ctx) {
    __shared__ float vs[128][54];
    __shared__ float ss[64][54];
    int blk = blockIdx.x;
    int ct = blk & 3; blk >>= 2;
    int nt = blk % 9;
    int b = blk / 9;
    int c0 = ct * 128, n0 = nt * 64;
    int tid = threadIdx.x;
    for (int e = tid; e < 128 * 50; e += 256) {
        int c = e / 50, m = e % 50;
        vs[c][m] = v[((size_t)b * 512 + c0 + c) * 50 + m];
    }
    for (int e = tid; e < 64 * 50; e += 256) {
        int n = e / 50, m = e % 50;
        ss[n][m] = simg[((size_t)b * 576 + n0 + n) * 50 + m];
    }
    __syncthreads();
    int n_t = tid & 15;
    int c_t = tid >> 4;
    float acc[8][4];
#pragma unroll
    for (int i = 0; i < 8; ++i)
#pragma unroll
        for (int j = 0; j < 4; ++j) acc[i][j] = 0.f;
    for (int m = 0; m < 50; ++m) {
        float sv[4];
#pragma unroll
        for (int j = 0; j < 4; ++j) sv[j] = ss[j * 16 + n_t][m];
#pragma unroll
        for (int i = 0; i < 8; ++i) {
            float vv = vs[c_t * 8 + i][m];
#pragma unroll
            for (int j = 0; j < 4; ++j) acc[i][j] = fmaf(vv, sv[j], acc[i][j]);
        }
    }
#pragma unroll
    for (int i = 0; i < 8; ++i)
#pragma unroll
        for (int j = 0; j < 4; ++j)
            ctx[((size_t)b * 512 + c0 + c_t * 8 + i) * 576 + n0 + j * 16 + n_t] = acc[i][j];
}

// ---------------------------------------------------------------------------
__global__ void __launch_bounds__(256)
conv1x1_cat_kernel(const float* __restrict__ cp, const float* __restrict__ sp,
                   const float* __restrict__ w, float* __restrict__ out) {
    __shared__ float ins[8][128];
    __shared__ float wls[8][64];
    int bid = blockIdx.x;
    int mt = bid % 72;
    int b = bid / 72;
    int m0 = mt * 128;
    int tid = threadIdx.x;
    int ml = tid & 31;
    int col = (tid >> 5) * 8;
    float acc[8][4];
#pragma unroll
    for (int i = 0; i < 8; ++i)
#pragma unroll
        for (int j = 0; j < 4; ++j) acc[i][j] = 0.f;
    for (int c0 = 0; c0 < 512; c0 += 8) {
        {
            int e = tid * 4;
            int cl = e >> 7, mm = e & 127;
            int cidx = c0 + cl;
            const float* src = (cidx < 256)
                ? (cp + ((size_t)b * 256 + cidx) * 9216 + m0 + mm)
                : (sp + ((size_t)b * 256 + (cidx - 256)) * 9216 + m0 + mm);
            st4(&ins[cl][mm], ld4(src));
        }
        for (int e = tid; e < 512; e += 256) {
            int cl = e & 7;
            int o = e >> 3;
            wls[cl][o] = w[(size_t)o * 512 + c0 + cl];
        }
        __syncthreads();
#pragma unroll
        for (int cl = 0; cl < 8; ++cl) {
            float4 w0 = ld4(&wls[cl][col]);
            float4 w1 = ld4(&wls[cl][col + 4]);
            float av[4];
#pragma unroll
            for (int j = 0; j < 4; ++j) av[j] = ins[cl][ml + 32 * j];
            float wv_[8] = {w0.x, w0.y, w0.z, w0.w, w1.x, w1.y, w1.z, w1.w};
#pragma unroll
            for (int oo = 0; oo < 8; ++oo)
#pragma unroll
                for (int j = 0; j < 4; ++j)
                    acc[oo][j] = fmaf(wv_[oo], av[j], acc[oo][j]);
        }
        __syncthreads();
    }
#pragma unroll
    for (int oo = 0; oo < 8; ++oo)
#pragma unroll
        for (int j = 0; j < 4; ++j)
            out[((size_t)b * 64 + col + oo) * 9216 + m0 + ml + 32 * j] = silu_f(acc[oo][j]);
}

// ---------------------------------------------------------------------------
__global__ void upsample_kernel(const float* __restrict__ in, float* __restrict__ out) {
    int idx = blockIdx.x * 256 + threadIdx.x;
    const int total = 8 * 256 * 96 * 96;
    if (idx >= total) return;
    int x = idx % 96;
    int y = (idx / 96) % 96;
    int p = idx / 9216;
    float fy = y * (23.f / 95.f);
    float fx = x * (23.f / 95.f);
    int y0 = (int)fy; if (y0 > 22) y0 = 22;
    int x0 = (int)fx; if (x0 > 22) x0 = 22;
    float wy = fy - y0, wx = fx - x0;
    const float* ip = in + (size_t)p * 576;
    float a = ip[y0 * 24 + x0], b = ip[y0 * 24 + x0 + 1];
    float c = ip[(y0 + 1) * 24 + x0], d = ip[(y0 + 1) * 24 + x0 + 1];
    float l = a * (1.f - wy) + c * wy;
    float r = b * (1.f - wy) + d * wy;
    out[idx] = l * (1.f - wx) + r * wx;
}

// ---------------------------------------------------------------------------
// grid_sample prep
// ---------------------------------------------------------------------------
DI void gs_params(int x, int y, float ox, float oy, float4* w, int2* p) {
    const float S = 47.5f / 96.f;
    float px = x + ox * S;
    float py = y + oy * S;
    float fx0 = floorf(px), fy0 = floorf(py);
    float wx = px - fx0, wy = py - fy0;
    float vx0 = (fx0 >= 0.f && fx0 <= 95.f) ? 1.f : 0.f;
    float vx1 = (fx0 >= -1.f && fx0 <= 94.f) ? 1.f : 0.f;
    float vy0 = (fy0 >= 0.f && fy0 <= 95.f) ? 1.f : 0.f;
    float vy1 = (fy0 >= -1.f && fy0 <= 94.f) ? 1.f : 0.f;
    int x0 = (int)fminf(fmaxf(fx0, 0.f), 95.f);
    int x1 = (int)fminf(fmaxf(fx0 + 1.f, 0.f), 95.f);
    int y0 = (int)fminf(fmaxf(fy0, 0.f), 95.f);
    int y1 = (int)fminf(fmaxf(fy0 + 1.f, 0.f), 95.f);
    w->x = (1.f - wx) * (1.f - wy) * vx0 * vy0;
    w->y = wx * (1.f - wy) * vx1 * vy0;
    w->z = (1.f - wx) * wy * vx0 * vy1;
    w->w = wx * wy * vx1 * vy1;
    *p = make_int2(x0 | (x1 << 16), y0 | (y1 << 16));
}

__global__ void gprep_kernel(const float* __restrict__ cr, float4* __restrict__ wpar,
                             int2* __restrict__ ipk, float2* __restrict__ attp) {
    int idx = blockIdx.x * 256 + threadIdx.x;
    if (idx >= 8 * 2 * 9216) return;
    int pix = idx % 9216;
    int g = (idx / 9216) & 1;
    int b = idx / 18432;
    const float* crb = cr + (size_t)b * 10 * 9216 + pix;
    int x = pix % 96, y = pix / 96;
    float4 w; int2 p;
    gs_params(x, y, crb[(2 * g) * 9216], crb[(2 * g + 1) * 9216], &w, &p);
    size_t el = ((size_t)g * 8 + b) * 9216 + pix;
    wpar[el] = w; ipk[el] = p;
    gs_params(x, y, crb[(4 + 2 * g) * 9216], crb[(5 + 2 * g) * 9216], &w, &p);
    size_t eh = ((size_t)(2 + g) * 8 + b) * 9216 + pix;
    wpar[eh] = w; ipk[eh] = p;
    if (g == 0) {
        float2 at;
        at.x = 1.f + tanhf(crb[8 * 9216]);
        at.y = 1.f + tanhf(crb[9 * 9216]);
        attp[(size_t)b * 9216 + pix] = at;
    }
}

// ---------------------------------------------------------------------------
// gather-only grid_sample blend; CPT channels per thread (params shared).
// ---------------------------------------------------------------------------
template <int CPT>
__global__ void __launch_bounds__(256)
gsample2_kernel(const float* __restrict__ cp, const float* __restrict__ sp,
                const float4* __restrict__ wpar, const int2* __restrict__ ipk,
                const float2* __restrict__ attp, float* __restrict__ p5o) {
    const int nCB = 256 / CPT;
    int idx = blockIdx.x * 256 + threadIdx.x;
    const int total = 8 * nCB * 9216;
    if (idx >= total) return;
    int pix = idx % 9216;
    int cb = (idx / 9216) % nCB;
    int b = idx / (9216 * nCB);
    int c0 = cb * CPT;
    int g = c0 >> 7;
    size_t el = ((size_t)g * 8 + b) * 9216 + pix;
    size_t eh = ((size_t)(2 + g) * 8 + b) * 9216 + pix;
    float4 wl = wpar[el]; int2 pl = ipk[el];
    float4 wh = wpar[eh]; int2 ph = ipk[eh];
    float2 at = attp[(size_t)b * 9216 + pix];
    int l00 = (pl.y & 0xffff) * 96 + (pl.x & 0xffff);
    int l01 = (pl.y & 0xffff) * 96 + (pl.x >> 16);
    int l10 = (pl.y >> 16) * 96 + (pl.x & 0xffff);
    int l11 = (pl.y >> 16) * 96 + (pl.x >> 16);
    int h00 = (ph.y & 0xffff) * 96 + (ph.x & 0xffff);
    int h01 = (ph.y & 0xffff) * 96 + (ph.x >> 16);
    int h10 = (ph.y >> 16) * 96 + (ph.x & 0xffff);
    int h11 = (ph.y >> 16) * 96 + (ph.x >> 16);
    const float* cpp = cp + ((size_t)b * 256 + c0) * 9216;
    const float* spp = sp + ((size_t)b * 256 + c0) * 9216;
    float* op = p5o + ((size_t)b * 256 + c0) * 9216 + pix;
#pragma unroll
    for (int i = 0; i < CPT; ++i) {
        float cps = wl.x * cpp[l00] + wl.y * cpp[l01] + wl.z * cpp[l10] + wl.w * cpp[l11];
        float sps = wh.x * spp[h00] + wh.y * spp[h01] + wh.z * spp[h10] + wh.w * spp[h11];
        *op = sps * at.x + cps * at.y;
        cpp += 9216; spp += 9216; op += 9216;
    }
}

// ---------------------------------------------------------------------------
extern "C" void kernel_launch(void* const* d_in, const int* in_sizes, int n_in,
                              void* d_out, int out_size, void* d_ws, size_t ws_size,
                              hipStream_t stream) {
    const float* p3    = (const float*)d_in[0];
    const float* p5    = (const float*)d_in[1];
    const float* w_red = (const float*)d_in[2];
    const float* wq    = (const float*)d_in[3];
    const float* bq    = (const float*)d_in[4];
    const float* wk    = (const float*)d_in[5];
    const float* bk    = (const float*)d_in[6];
    const float* wv    = (const float*)d_in[7];
    const float* bv    = (const float*)d_in[8];
    const float* la_w1 = (const float*)d_in[9];
    const float* la_w2 = (const float*)d_in[10];
    const float* w32   = (const float*)d_in[11];
    const float* w8    = (const float*)d_in[12];
    const float* woff1 = (const float*)d_in[13];
    const float* woff2 = (const float*)d_in[14];

    float* out = (float*)d_out;
    float* p3o = out;                 // [8,512,24,24]
    float* p5o = out + 2359296;       // [8,256,96,96]

    float* ws = (float*)d_ws;
    float* x_   = ws + 0;
    float* ctx  = ws + 2359296;
    float* q    = ws + 4718592;
    float* kf   = ws + 4866048;
    float* km   = ws + 5070848;
    float* vm   = ws + 5083648;
    float* la1  = ws + 5288448;
    float* sp24 = ws + 5583360;
    float* sp96 = ws + 6763008;
    float* cp   = ws + 25637376;
    unsigned short* wred_pk = (unsigned short*)(ws + 44511744); // 2359296 u16
    unsigned short* w32_pk  = (unsigned short*)(ws + 45724160); // 1179648 u16
    unsigned short* w8_pk   = (unsigned short*)(ws + 46330368); //  589824 u16
    unsigned short* p5_pk   = (unsigned short*)(ws + 6763008);
    unsigned short* p3_pk   = (unsigned short*)(ws + 16200192);
    unsigned short* la1_pk  = (unsigned short*)(ws + 17379840);
    unsigned short* wla2_pk = (unsigned short*)(ws + 17527296); //  294912 u16
    float* simg = la1;
    float* t64  = ws + 0;
    float* cr   = ws + 4718592;
    float4* wpar = (float4*)(ws + 0);
    int2*   ipk  = (int2*)(ws + 1179648);
    float2* attp = (float2*)(ws + 1769472);

    // P0: pack weights (v2 layout, COG matched to each conv's WCO*16)
    pack_w2_kernel<<<dim3(2359296 / 256), dim3(256), 0, stream>>>(w_red, wred_pk, 512, 512, 32);
    pack_w2_kernel<<<dim3(1179648 / 256), dim3(256), 0, stream>>>(w32, w32_pk, 512, 256, 16);
    pack_w2_kernel<<<dim3(589824 / 256), dim3(256), 0, stream>>>(w8, w8_pk, 256, 256, 64);
    pack_w2_kernel<<<dim3(294912 / 256), dim3(256), 0, stream>>>(la_w2, wla2_pk, 64, 512, 32);
    // P1: pack inputs
    pack_in_kernel<<<dim3(2359296 / 256), dim3(256), 0, stream>>>(p5, p5_pk, 256, 9216, 2359296);
    pack_in_kernel<<<dim3(294912 / 256), dim3(256), 0, stream>>>(p3, p3_pk, 512, 576, 294912);

    // K10: cp = silu(conv3x3(p5, w8)) 256->256, 96x96  [MFMA v2, COG=64]
    conv3x3_mfma2<16, 16, 4, 4, 1><<<dim3(1152), dim3(256), 0, stream>>>(
        p5_pk, w8_pk, cp, 8, 256, 256, 96, 96, nullptr, nullptr);
    // K1: x = silu(conv3x3(p3, w_red)) 512->512, 24x24  [MFMA v2, COG=32]
    conv3x3_mfma2<8, 24, 3, 2, 1><<<dim3(384), dim3(256), 0, stream>>>(
        p3_pk, wred_pk, x_, 8, 512, 512, 24, 24, nullptr, nullptr);
    // K2: q = conv1x1(x, wq) + bq
    gemm_om<0><<<dim3(8 * 1 * 9), dim3(256), 0, stream>>>(
        wq, bq, x_, q, 8, 512, 32, 576, 1, 9);
    // K3: kfeat = psp(x)
    psp_kernel<<<dim3(8 * 512), dim3(64), 0, stream>>>(x_, kf);
    // K4: k, v projections
    gemm_om<0><<<dim3(8 * 1 * 1), dim3(256), 0, stream>>>(
        wk, bk, kf, km, 8, 512, 32, 50, 1, 1);
    gemm_om<0><<<dim3(8 * 8 * 1), dim3(256), 0, stream>>>(
        wv, bv, kf, vm, 8, 512, 512, 50, 8, 1);
    // K5a: sim = softmax(q^T k)
    sim_kernel<<<dim3(72), dim3(256), 0, stream>>>(q, km, simg);
    // K5b: ctx = v @ sim^T
    ctx_kernel<<<dim3(288), dim3(256), 0, stream>>>(vm, simg, ctx);
    // K6: la1 = silu(conv1x1(ctx, la_w1))
    gemm_om<1><<<dim3(8 * 1 * 9), dim3(256), 0, stream>>>(
        la_w1, nullptr, ctx, la1, 8, 512, 64, 576, 1, 9);
    // pack la1
    pack_in_kernel<<<dim3(36864 / 256), dim3(256), 0, stream>>>(la1, la1_pk, 64, 576, 36864);
    // K7: p3o = x + ctx*(1 + tanh(conv3x3(la1, la_w2)))  [MFMA v2 FUSE2, COG=32]
    conv3x3_mfma2<8, 24, 3, 2, 2><<<dim3(384), dim3(256), 0, stream>>>(
        la1_pk, wla2_pk, p3o, 8, 64, 512, 24, 24, ctx, x_);
    // pack p3o
    pack_in_kernel<<<dim3(294912 / 256), dim3(256), 0, stream>>>(p3o, p3_pk, 512, 576, 294912);
    // K8: sp24 = silu(conv3x3(p3o, w32)) 512->256  [MFMA v2, COG=16]
    conv3x3_mfma2<8, 24, 3, 1, 1><<<dim3(384), dim3(256), 0, stream>>>(
        p3_pk, w32_pk, sp24, 8, 512, 256, 24, 24, nullptr, nullptr);
    // K9: sp96 = bilinear upsample
    upsample_kernel<<<dim3(8 * 256 * 9216 / 256), dim3(256), 0, stream>>>(sp24, sp96);
    // K11: t64 = silu(conv1x1(concat[cp, sp96], woff1))
    conv1x1_cat_kernel<<<dim3(8 * 72), dim3(256), 0, stream>>>(cp, sp96, woff1, t64);
    // K12: cr = conv3x3(t64, woff2) 64->10
    conv3x3_kernel<8, 32, 12, 3, 4, 0><<<dim3(288), dim3(192), 0, stream>>>(
        t64, woff2, cr, 8, 64, 10, 96, 96, nullptr, nullptr);
    // K13a: grid-sample params + att
    gprep_kernel<<<dim3(576), dim3(256), 0, stream>>>(cr, wpar, ipk, attp);
    // K13b: p5o = gather blend, 8 channels/thread
    gsample2_kernel<8><<<dim3(8 * 32 * 9216 / 256), dim3(256), 0, stream>>>(
        cp, sp96, wpar, ipk, attp, p5o);
}

// Round 8
// 893.228 us; speedup vs baseline: 4.4647x; 1.1141x over previous
//
#include <hip/hip_runtime.h>
#include <math.h>

#define DI __device__ __forceinline__

typedef __attribute__((ext_vector_type(8))) short bf16x8;
typedef __attribute__((ext_vector_type(4))) float f32x4;

DI float silu_f(float v) { return v / (1.f + __expf(-v)); }
DI float4 ld4(const float* p) { return *reinterpret_cast<const float4*>(p); }
DI void st4(float* p, const float4& v) { *reinterpret_cast<float4*>(p) = v; }
DI unsigned short f2bf(float f) {
    unsigned u = __float_as_uint(f);
    unsigned r = (u + 0x7FFFu + ((u >> 16) & 1u)) >> 16;
    return (unsigned short)r;
}
DI float bf2f(unsigned short u) { return __uint_as_float(((unsigned)u) << 16); }

// ---------------------------------------------------------------------------
// Weight pre-pack v2 (3x3): [Ci/32][Co/COG][9][COG][32]
// ---------------------------------------------------------------------------
__global__ void pack_w2_kernel(const float* __restrict__ w, unsigned short* __restrict__ pk,
                               int Ci, int Co, int COG) {
    int idx = blockIdx.x * 256 + threadIdx.x;
    int total = Ci * Co * 9;
    if (idx >= total) return;
    int cc = idx & 31;
    int t = idx >> 5;
    int col = t % COG; t /= COG;
    int dydx = t % 9;  t /= 9;
    int nCoG = Co / COG;
    int cog = t % nCoG;
    int ch = t / nCoG;
    int co = cog * COG + col;
    pk[idx] = f2bf(w[((size_t)co * Ci + (ch << 5) + cc) * 9 + dydx]);
}

// 1x1 weight pack: w [64][512] -> [16][64][32]
__global__ void pack_w1_kernel(const float* __restrict__ w, unsigned short* __restrict__ pk) {
    int idx = blockIdx.x * 256 + threadIdx.x;
    if (idx >= 32768) return;
    int cc = idx & 31;
    int col = (idx >> 5) & 63;
    int ch = idx >> 11;
    pk[idx] = f2bf(w[(size_t)col * 512 + (ch << 5) + cc]);
}

// ---------------------------------------------------------------------------
// Input pre-pack: f32 NCHW -> bf16 [b][ci/32][H][W][32]
// ---------------------------------------------------------------------------
__global__ void pack_in_kernel(const float* __restrict__ in, unsigned short* __restrict__ pk,
                               int Ci, int HW, int total) {
    int idx = blockIdx.x * 256 + threadIdx.x;
    if (idx >= total) return;
    const int nCh = Ci >> 5;
    int cg = idx & 3;
    int t = idx >> 2;
    int pix = t % HW; t /= HW;
    int ch = t % nCh;
    int b = t / nCh;
    const float* src = in + ((size_t)b * Ci + (ch << 5) + (cg << 3)) * HW + pix;
    unsigned p[4];
#pragma unroll
    for (int j = 0; j < 4; ++j) {
        float v0 = src[(size_t)(2 * j) * HW];
        float v1 = src[(size_t)(2 * j + 1) * HW];
        p[j] = (unsigned)f2bf(v0) | ((unsigned)f2bf(v1) << 16);
    }
    *(uint4*)&pk[(((size_t)b * nCh + ch) * HW + pix) * 32 + (cg << 3)] =
        make_uint4(p[0], p[1], p[2], p[3]);
}

// ---------------------------------------------------------------------------
// MFMA implicit-GEMM 3x3 SAME conv (weights from L2).
// OUTPK: 0 = f32 planes only, 1 = packed bf16 only, 2 = both.
// ---------------------------------------------------------------------------
template <int TH, int TW, int BF, int WCO, int FUSE, int OUTPK>
__global__ void __launch_bounds__(256)
conv3x3_mfma2(const unsigned short* __restrict__ pin, const unsigned short* __restrict__ wpk,
              float* __restrict__ out, unsigned short* __restrict__ outpk,
              int B, int Ci, int Co, int H, int W,
              const float* __restrict__ ctx, const float* __restrict__ xres) {
    static_assert(TH * TW == 4 * BF * 16, "tile px = 4 waves * BF frags * 16");
    constexpr int COG = WCO * 16;
    constexpr int TWH = TW + 2;
    constexpr int HP = (TH + 2) * TWH;
    __shared__ __align__(16) unsigned short lin[HP * 40];

    const int nTx = W / TW, nTy = H / TH, nCoG = Co / COG;
    const int nwg = gridDim.x;
    int wg = (blockIdx.x & 7) * (nwg >> 3) + (blockIdx.x >> 3);
    const int cog = wg % nCoG; wg /= nCoG;
    const int tx = wg % nTx;   wg /= nTx;
    const int ty = wg % nTy;
    const int b = wg / nTy;
    const int ox = tx * TW, oy = ty * TH, co0 = cog * COG;

    const int tid = threadIdx.x;
    const int wave = tid >> 6, lane = tid & 63;
    const int l15 = lane & 15, g = lane >> 4;
    const int wpx = wave * (BF * 16);

    int rr[BF], cc_[BF];
#pragma unroll
    for (int bf = 0; bf < BF; ++bf) {
        int px = wpx + bf * 16 + l15;
        rr[bf] = px / TW;
        cc_[bf] = px % TW;
    }

    f32x4 acc[WCO][BF];
#pragma unroll
    for (int af = 0; af < WCO; ++af)
#pragma unroll
        for (int bf = 0; bf < BF; ++bf) acc[af][bf] = {};

    const int nCh = Ci >> 5;
    const size_t HWs = (size_t)H * W;

    for (int ch = 0; ch < nCh; ++ch) {
#pragma unroll
        for (int it = 0; it < (HP * 4 + 255) / 256; ++it) {
            int e = tid + it * 256;
            if (e < HP * 4) {
                int cg = e & 3;
                int hp = e >> 2;
                int hy = hp / TWH, hx = hp % TWH;
                int gy = oy + hy - 1, gx = ox + hx - 1;
                uint4 v = make_uint4(0, 0, 0, 0);
                if ((unsigned)gy < (unsigned)H && (unsigned)gx < (unsigned)W)
                    v = *(const uint4*)&pin[(((size_t)b * nCh + ch) * H * W
                                            + (size_t)gy * W + gx) * 32 + (cg << 3)];
                *(uint4*)&lin[hp * 40 + (cg << 3)] = v;
            }
        }
        __syncthreads();

        const unsigned short* wbase =
            wpk + ((((size_t)ch * nCoG + cog) * 9) * COG + l15) * 32 + g * 8;
#pragma unroll
        for (int dy = 0; dy < 3; ++dy) {
#pragma unroll
            for (int dx = 0; dx < 3; ++dx) {
                const int dydx = dy * 3 + dx;
                bf16x8 a[WCO];
#pragma unroll
                for (int af = 0; af < WCO; ++af)
                    a[af] = *(const bf16x8*)(wbase + ((size_t)dydx * COG + af * 16) * 32);
                bf16x8 bb[BF];
#pragma unroll
                for (int bf = 0; bf < BF; ++bf)
                    bb[bf] = *(const bf16x8*)&lin[((rr[bf] + dy) * TWH + cc_[bf] + dx) * 40 + g * 8];
#pragma unroll
                for (int af = 0; af < WCO; ++af)
#pragma unroll
                    for (int bf = 0; bf < BF; ++bf)
                        acc[af][bf] = __builtin_amdgcn_mfma_f32_16x16x32_bf16(
                            a[af], bb[bf], acc[af][bf], 0, 0, 0);
            }
        }
        __syncthreads();
    }
    const int nChO = Co >> 5;
#pragma unroll
    for (int af = 0; af < WCO; ++af) {
#pragma unroll
        for (int bf = 0; bf < BF; ++bf) {
            int px = wpx + bf * 16 + l15;
            int y = oy + px / TW, x = ox + px % TW;
            size_t pixg = (size_t)y * W + x;
            int coB = co0 + af * 16 + (g << 2);
            float vv[4];
#pragma unroll
            for (int r4 = 0; r4 < 4; ++r4) {
                float v = acc[af][bf][r4];
                if (FUSE == 1) v = silu_f(v);
                else if (FUSE == 2) {
                    size_t base = ((size_t)b * Co + coB + r4) * HWs + pixg;
                    v = xres[base] + ctx[base] * (1.f + tanhf(v));
                }
                vv[r4] = v;
            }
            if (OUTPK != 1) {
#pragma unroll
                for (int r4 = 0; r4 < 4; ++r4)
                    out[((size_t)b * Co + coB + r4) * HWs + pixg] = vv[r4];
            }
            if (OUTPK >= 1) {
                ushort4 s;
                s.x = f2bf(vv[0]); s.y = f2bf(vv[1]); s.z = f2bf(vv[2]); s.w = f2bf(vv[3]);
                *(ushort4*)&outpk[(((size_t)b * nChO + (coB >> 5)) * HWs + pixg) * 32 + (coB & 31)] = s;
            }
        }
    }
}

// ---------------------------------------------------------------------------
// MFMA 1x1 conv on packed concat [cp_pk; sp_pk] (512->64) + SiLU -> t64 f32.
// Block 64o x 128px, 4 waves, WCO=4, BF=2, 16 ci-chunks.
// ---------------------------------------------------------------------------
__global__ void __launch_bounds__(256)
cat_mfma(const unsigned short* __restrict__ cp_pk, const unsigned short* __restrict__ sp_pk,
         const unsigned short* __restrict__ wpk, float* __restrict__ out) {
    __shared__ __align__(16) unsigned short lin1[128 * 36];
    const int nwg = gridDim.x;
    int wg = (blockIdx.x & 7) * (nwg >> 3) + (blockIdx.x >> 3);
    int mt = wg % 72;
    int b = wg / 72;
    int m0 = mt * 128;
    const int tid = threadIdx.x;
    const int wave = tid >> 6, lane = tid & 63;
    const int l15 = lane & 15, g = lane >> 4;
    const int wpx = wave * 32;

    f32x4 acc[4][2];
#pragma unroll
    for (int af = 0; af < 4; ++af)
#pragma unroll
        for (int bf = 0; bf < 2; ++bf) acc[af][bf] = {};

    for (int ch = 0; ch < 16; ++ch) {
        const unsigned short* src = (ch < 8)
            ? cp_pk + (((size_t)b * 8 + ch) * 9216 + m0) * 32
            : sp_pk + (((size_t)b * 8 + ch - 8) * 9216 + m0) * 32;
#pragma unroll
        for (int it = 0; it < 2; ++it) {
            int e = tid + it * 256;
            int px = e >> 2, cg = e & 3;
            *(uint4*)&lin1[px * 36 + (cg << 3)] = *(const uint4*)&src[px * 32 + (cg << 3)];
        }
        __syncthreads();
        const unsigned short* wb = wpk + ((size_t)ch * 64 + l15) * 32 + g * 8;
        bf16x8 a[4];
#pragma unroll
        for (int af = 0; af < 4; ++af)
            a[af] = *(const bf16x8*)(wb + (af * 16) * 32);
        bf16x8 bb[2];
#pragma unroll
        for (int bf = 0; bf < 2; ++bf)
            bb[bf] = *(const bf16x8*)&lin1[(wpx + bf * 16 + l15) * 36 + g * 8];
#pragma unroll
        for (int af = 0; af < 4; ++af)
#pragma unroll
            for (int bf = 0; bf < 2; ++bf)
                acc[af][bf] = __builtin_amdgcn_mfma_f32_16x16x32_bf16(
                    a[af], bb[bf], acc[af][bf], 0, 0, 0);
        __syncthreads();
    }
#pragma unroll
    for (int af = 0; af < 4; ++af) {
#pragma unroll
        for (int bf = 0; bf < 2; ++bf) {
            int m = m0 + wpx + bf * 16 + l15;
#pragma unroll
            for (int r4 = 0; r4 < 4; ++r4) {
                int o = af * 16 + (g << 2) + r4;
                out[((size_t)b * 64 + o) * 9216 + m] = silu_f(acc[af][bf][r4]);
            }
        }
    }
}

// ---------------------------------------------------------------------------
// grid_sample param helper
// ---------------------------------------------------------------------------
DI void gs_params(int x, int y, float ox, float oy, float4* w, int2* p) {
    const float S = 47.5f / 96.f;
    float px = x + ox * S;
    float py = y + oy * S;
    float fx0 = floorf(px), fy0 = floorf(py);
    float wx = px - fx0, wy = py - fy0;
    float vx0 = (fx0 >= 0.f && fx0 <= 95.f) ? 1.f : 0.f;
    float vx1 = (fx0 >= -1.f && fx0 <= 94.f) ? 1.f : 0.f;
    float vy0 = (fy0 >= 0.f && fy0 <= 95.f) ? 1.f : 0.f;
    float vy1 = (fy0 >= -1.f && fy0 <= 94.f) ? 1.f : 0.f;
    int x0 = (int)fminf(fmaxf(fx0, 0.f), 95.f);
    int x1 = (int)fminf(fmaxf(fx0 + 1.f, 0.f), 95.f);
    int y0 = (int)fminf(fmaxf(fy0, 0.f), 95.f);
    int y1 = (int)fminf(fmaxf(fy0 + 1.f, 0.f), 95.f);
    w->x = (1.f - wx) * (1.f - wy) * vx0 * vy0;
    w->y = wx * (1.f - wy) * vx1 * vy0;
    w->z = (1.f - wx) * wy * vx0 * vy1;
    w->w = wx * wy * vx1 * vy1;
    *p = make_int2(x0 | (x1 << 16), y0 | (y1 << 16));
}

// ---------------------------------------------------------------------------
// Direct 3x3 SAME conv, f32. FUSE 3 = K12: conv then fused grid-sample prep
// (writes wpar/ipk/attp instead of storing conv output).
// ---------------------------------------------------------------------------
template <int TH, int TW, int CO_BLK, int CO_T, int CIC, int FUSE>
__global__ void __launch_bounds__(576)
conv3x3_kernel(const float* __restrict__ in, const float* __restrict__ wgt,
               float* __restrict__ out, int B, int Ci, int Co, int H, int W,
               float4* __restrict__ wpar, int2* __restrict__ ipk,
               float2* __restrict__ attp) {
    constexpr int TWH = TW + 2;
    constexpr int TWP = TW + 3;
    constexpr int SPAT = TH * (TW / 4);
    __shared__ float lin[CIC][TH + 2][TWP];
    __shared__ float wls[CIC][9][CO_BLK];
    __shared__ float crs[10][TH * TW + 1];

    const int nTx = W / TW, nTy = H / TH;
    const int nCoG = (Co + CO_BLK - 1) / CO_BLK;
    int bid = blockIdx.x;
    const int cog = bid % nCoG; bid /= nCoG;
    const int tx = bid % nTx;   bid /= nTx;
    const int ty = bid % nTy;
    const int b = bid / nTy;
    const int ox = tx * TW, oy = ty * TH;
    const int co0 = cog * CO_BLK;

    const int tid = threadIdx.x;
    const int cot = tid / SPAT;
    const int sp = tid % SPAT;
    const int r = sp / (TW / 4);
    const int cg = sp % (TW / 4);

    float acc[4][4];
#pragma unroll
    for (int i = 0; i < 4; ++i)
#pragma unroll
        for (int j = 0; j < 4; ++j) acc[i][j] = 0.f;

    for (int ci0 = 0; ci0 < Ci; ci0 += CIC) {
        for (int e = tid; e < CIC * (TH + 2) * TWH; e += SPAT * CO_T) {
            int xx = e % TWH;
            int yy = (e / TWH) % (TH + 2);
            int cc = e / (TWH * (TH + 2));
            int gy = oy - 1 + yy, gx = ox - 1 + xx;
            float v = 0.f;
            if (gy >= 0 && gy < H && gx >= 0 && gx < W)
                v = in[(((size_t)b * Ci + ci0 + cc) * H + gy) * W + gx];
            lin[cc][yy][xx] = v;
        }
        for (int e = tid; e < CIC * 9 * CO_BLK; e += SPAT * CO_T) {
            int col = e % CO_BLK;
            int k = (e / CO_BLK) % 9;
            int cc = e / (CO_BLK * 9);
            int co = co0 + col;
            float v = 0.f;
            if (co < Co) v = wgt[((size_t)co * Ci + ci0 + cc) * 9 + k];
            wls[cc][k][col] = v;
        }
        __syncthreads();
#pragma unroll
        for (int cc = 0; cc < CIC; ++cc) {
            float v0[3][6];
#pragma unroll
            for (int ky = 0; ky < 3; ++ky)
#pragma unroll
                for (int u = 0; u < 6; ++u)
                    v0[ky][u] = lin[cc][r + ky][cg * 4 + u];
#pragma unroll
            for (int ky = 0; ky < 3; ++ky)
#pragma unroll
                for (int kx = 0; kx < 3; ++kx) {
                    const float4 w4 = ld4(&wls[cc][ky * 3 + kx][cot * 4]);
                    const float wv_[4] = {w4.x, w4.y, w4.z, w4.w};
#pragma unroll
                    for (int i = 0; i < 4; ++i)
#pragma unroll
                        for (int j = 0; j < 4; ++j)
                            acc[i][j] = fmaf(wv_[i], v0[ky][kx + j], acc[i][j]);
                }
        }
        __syncthreads();
    }
    if (FUSE == 3) {
        // scatter acc into LDS, then per-pixel grid-sample prep
#pragma unroll
        for (int i = 0; i < 4; ++i) {
            int co = co0 + cot * 4 + i;
            if (co >= 10) continue;
#pragma unroll
            for (int j = 0; j < 4; ++j)
                crs[co][r * TW + cg * 4 + j] = acc[i][j];
        }
        __syncthreads();
        for (int e = tid; e < TH * TW; e += SPAT * CO_T) {
            int xx = ox + (e % TW), yy = oy + (e / TW);
            int pixg = yy * 96 + xx;
            float4 w; int2 p;
#pragma unroll
            for (int g2 = 0; g2 < 2; ++g2) {
                gs_params(xx, yy, crs[2 * g2][e], crs[2 * g2 + 1][e], &w, &p);
                size_t el = ((size_t)g2 * 8 + b) * 9216 + pixg;
                wpar[el] = w; ipk[el] = p;
                gs_params(xx, yy, crs[4 + 2 * g2][e], crs[5 + 2 * g2][e], &w, &p);
                size_t eh = ((size_t)(2 + g2) * 8 + b) * 9216 + pixg;
                wpar[eh] = w; ipk[eh] = p;
            }
            float2 at;
            at.x = 1.f + tanhf(crs[8][e]);
            at.y = 1.f + tanhf(crs[9][e]);
            attp[(size_t)b * 9216 + pixg] = at;
        }
    } else {
        const int y = oy + r;
        const int xb = ox + cg * 4;
#pragma unroll
        for (int i = 0; i < 4; ++i) {
            int co = co0 + cot * 4 + i;
            if (co >= Co) continue;
            size_t base = (((size_t)b * Co + co) * H + y) * W + xb;
            float4 res;
            res.x = acc[i][0]; res.y = acc[i][1]; res.z = acc[i][2]; res.w = acc[i][3];
            st4(&out[base], res);
        }
    }
}

// ---------------------------------------------------------------------------
// Tiled GEMM: out[b][o][m] = act(sum_c W[o][c]*in[b][c][m] + bias[o]).
// PK=1 -> write packed bf16 [b][o/32][m][32] instead of f32.
// ---------------------------------------------------------------------------
template <int ACT, int PK>
__global__ void __launch_bounds__(256)
gemm_om(const float* __restrict__ W, const float* __restrict__ bias,
        const float* __restrict__ in, float* __restrict__ out,
        unsigned short* __restrict__ pko,
        int B, int C, int O, int M, int nOt, int nMt) {
    __shared__ float xs[32][66];
    __shared__ float wls[64][33];
    int bid = blockIdx.x;
    int mt = bid % nMt; bid /= nMt;
    int ot = bid % nOt;
    int b  = bid / nOt;
    int o0 = ot * 64, m0 = mt * 64;
    int tid = threadIdx.x;
    int m_t = tid & 15, o_g = tid >> 4;
    float acc[4][4];
#pragma unroll
    for (int i = 0; i < 4; ++i)
#pragma unroll
        for (int j = 0; j < 4; ++j) acc[i][j] = 0.f;

    for (int c0 = 0; c0 < C; c0 += 32) {
#pragma unroll
        for (int it = 0; it < 8; ++it) {
            int e = tid + it * 256;
            int mm = e & 63, cc = e >> 6;
            float v = 0.f;
            if (m0 + mm < M) v = in[((size_t)b * C + c0 + cc) * M + m0 + mm];
            xs[cc][mm] = v;
        }
#pragma unroll
        for (int it = 0; it < 8; ++it) {
            int e = tid + it * 256;
            int cc = e & 31, ol = e >> 5;
            float v = 0.f;
            if (o0 + ol < O) v = W[(size_t)(o0 + ol) * C + c0 + cc];
            wls[ol][cc] = v;
        }
        __syncthreads();
#pragma unroll
        for (int cc = 0; cc < 32; ++cc) {
            float xv[4], wv[4];
#pragma unroll
            for (int j = 0; j < 4; ++j) xv[j] = xs[cc][j * 16 + m_t];
#pragma unroll
            for (int i = 0; i < 4; ++i) wv[i] = wls[o_g * 4 + i][cc];
#pragma unroll
            for (int i = 0; i < 4; ++i)
#pragma unroll
                for (int j = 0; j < 4; ++j)
                    acc[i][j] = fmaf(wv[i], xv[j], acc[i][j]);
        }
        __syncthreads();
    }
#pragma unroll
    for (int i = 0; i < 4; ++i) {
        int o = o0 + o_g * 4 + i;
        if (o >= O) continue;
        float bv = bias ? bias[o] : 0.f;
#pragma unroll
        for (int j = 0; j < 4; ++j) {
            int m = m0 + j * 16 + m_t;
            if (m >= M) continue;
            float v = acc[i][j] + bv;
            if (ACT == 1) v = silu_f(v);
            if (PK)
                pko[(((size_t)b * (O >> 5) + (o >> 5)) * M + m) * 32 + (o & 31)] = f2bf(v);
            else
                out[((size_t)b * O + o) * M + m] = v;
        }
    }
}

// ---------------------------------------------------------------------------
__global__ void psp_kernel(const float* __restrict__ x, float* __restrict__ kf) {
    __shared__ float pl[576];
    int bc = blockIdx.x;
    const float* xp = x + (size_t)bc * 576;
    for (int e = threadIdx.x; e < 576; e += 64) pl[e] = xp[e];
    __syncthreads();
    int m = threadIdx.x;
    if (m < 50) {
        int g, i0;
        if (m < 36)      { g = 6; i0 = m; }
        else if (m < 45) { g = 3; i0 = m - 36; }
        else if (m < 49) { g = 2; i0 = m - 45; }
        else             { g = 1; i0 = 0; }
        int bs = 24 / g;
        int by = i0 / g, bx = i0 % g;
        float s = 0.f;
        for (int yy = 0; yy < bs; ++yy)
            for (int xx = 0; xx < bs; ++xx)
                s += pl[(by * bs + yy) * 24 + bx * bs + xx];
        kf[(size_t)bc * 50 + m] = s / (float)(bs * bs);
    }
}

// ---------------------------------------------------------------------------
__global__ void __launch_bounds__(256)
sim_kernel(const float* __restrict__ q, const float* __restrict__ k,
           float* __restrict__ simg) {
    __shared__ float qs[32][65];
    __shared__ float ks[32][52];
    __shared__ float sm[64][52];
    int b = blockIdx.x / 9, n0 = (blockIdx.x % 9) * 64;
    int tid = threadIdx.x;
    for (int e = tid; e < 32 * 64; e += 256) {
        int c = e >> 6, n = e & 63;
        qs[c][n] = q[((size_t)b * 32 + c) * 576 + n0 + n];
    }
    for (int e = tid; e < 32 * 50; e += 256) {
        int c = e / 50, m = e % 50;
        ks[c][m] = k[((size_t)b * 32 + c) * 50 + m];
    }
    __syncthreads();
    for (int e = tid; e < 64 * 50; e += 256) {
        int n = e / 50, m = e % 50;
        float s = 0.f;
#pragma unroll
        for (int c = 0; c < 32; ++c) s = fmaf(qs[c][n], ks[c][m], s);
        sm[n][m] = s;
    }
    __syncthreads();
    if (tid < 64) {
        float mx = -1e30f;
        for (int m = 0; m < 50; ++m) mx = fmaxf(mx, sm[tid][m]);
        float sum = 0.f;
        for (int m = 0; m < 50; ++m) {
            float e2 = __expf(sm[tid][m] - mx);
            sm[tid][m] = e2;
            sum += e2;
        }
        float inv = 1.f / sum;
        for (int m = 0; m < 50; ++m) sm[tid][m] *= inv;
    }
    __syncthreads();
    for (int e = tid; e < 64 * 50; e += 256) {
        int n = e / 50, m = e % 50;
        simg[((size_t)b * 576 + n0 + n) * 50 + m] = sm[n][m];
    }
}

// ---------------------------------------------------------------------------
__global__ void __launch_bounds__(256)
ctx_kernel(const float* __restrict__ v, const float* __restrict__ simg,
           float* __restrict__ ctx) {
    __shared__ float vs[128][54];
    __shared__ float ss[64][54];
    int blk = blockIdx.x;
    int ct = blk & 3; blk >>= 2;
    int nt = blk % 9;
    int b = blk / 9;
    int c0 = ct * 128, n0 = nt * 64;
    int tid = threadIdx.x;
    for (int e = tid; e < 128 * 50; e += 256) {
        int c = e / 50, m = e % 50;
        vs[c][m] = v[((size_t)b * 512 + c0 + c) * 50 + m];
    }
    for (int e = tid; e < 64 * 50; e += 256) {
        int n = e / 50, m = e % 50;
        ss[n][m] = simg[((size_t)b * 576 + n0 + n) * 50 + m];
    }
    __syncthreads();
    int n_t = tid & 15;
    int c_t = tid >> 4;
    float acc[8][4];
#pragma unroll
    for (int i = 0; i < 8; ++i)
#pragma unroll
        for (int j = 0; j < 4; ++j) acc[i][j] = 0.f;
    for (int m = 0; m < 50; ++m) {
        float sv[4];
#pragma unroll
        for (int j = 0; j < 4; ++j) sv[j] = ss[j * 16 + n_t][m];
#pragma unroll
        for (int i = 0; i < 8; ++i) {
            float vv = vs[c_t * 8 + i][m];
#pragma unroll
            for (int j = 0; j < 4; ++j) acc[i][j] = fmaf(vv, sv[j], acc[i][j]);
        }
    }
#pragma unroll
    for (int i = 0; i < 8; ++i)
#pragma unroll
        for (int j = 0; j < 4; ++j)
            ctx[((size_t)b * 512 + c0 + c_t * 8 + i) * 576 + n0 + j * 16 + n_t] = acc[i][j];
}

// ---------------------------------------------------------------------------
// Bilinear upsample 24->96 into packed bf16 [b][ch][9216][32]; 8 ci/thread.
// ---------------------------------------------------------------------------
__global__ void upsample2_kernel(const float* __restrict__ in, unsigned short* __restrict__ outpk) {
    int idx = blockIdx.x * 256 + threadIdx.x;
    if (idx >= 8 * 8 * 4 * 9216) return;
    int cg = idx & 3;
    int t = idx >> 2;
    int pix = t % 9216; t /= 9216;
    int ch = t & 7;
    int b = t >> 3;
    int x = pix % 96, y = pix / 96;
    float fy = y * (23.f / 95.f);
    float fx = x * (23.f / 95.f);
    int y0 = (int)fy; if (y0 > 22) y0 = 22;
    int x0 = (int)fx; if (x0 > 22) x0 = 22;
    float wy = fy - y0, wx = fx - x0;
    const float* base = in + ((size_t)b * 256 + ch * 32 + cg * 8) * 576 + y0 * 24 + x0;
    unsigned short s[8];
#pragma unroll
    for (int j = 0; j < 8; ++j) {
        const float* ip = base + (size_t)j * 576;
        float a = ip[0], bb = ip[1], c = ip[24], d = ip[25];
        float l = a * (1.f - wy) + c * wy;
        float r = bb * (1.f - wy) + d * wy;
        s[j] = f2bf(l * (1.f - wx) + r * wx);
    }
    *(uint4*)&outpk[(((size_t)b * 8 + ch) * 9216 + pix) * 32 + cg * 8] =
        make_uint4((unsigned)s[0] | ((unsigned)s[1] << 16),
                   (unsigned)s[2] | ((unsigned)s[3] << 16),
                   (unsigned)s[4] | ((unsigned)s[5] << 16),
                   (unsigned)s[6] | ((unsigned)s[7] << 16));
}

// ---------------------------------------------------------------------------
// grid_sample gather blend from packed bf16: one uint4 per tap = 8 channels.
// ---------------------------------------------------------------------------
__global__ void __launch_bounds__(256)
gsample3_kernel(const unsigned short* __restrict__ cp_pk, const unsigned short* __restrict__ sp_pk,
                const float4* __restrict__ wpar, const int2* __restrict__ ipk,
                const float2* __restrict__ attp, float* __restrict__ p5o) {
    int idx = blockIdx.x * 256 + threadIdx.x;
    if (idx >= 8 * 32 * 9216) return;
    int pix = idx % 9216;
    int cb = (idx / 9216) & 31;
    int b = idx / (9216 * 32);
    int c0 = cb * 8;
    int g = c0 >> 7, ch = c0 >> 5, coff = c0 & 31;
    size_t el = ((size_t)g * 8 + b) * 9216 + pix;
    size_t eh = ((size_t)(2 + g) * 8 + b) * 9216 + pix;
    float4 wl = wpar[el]; int2 pl = ipk[el];
    float4 wh = wpar[eh]; int2 ph = ipk[eh];
    float2 at = attp[(size_t)b * 9216 + pix];
    int l00 = (pl.y & 0xffff) * 96 + (pl.x & 0xffff);
    int l01 = (pl.y & 0xffff) * 96 + (pl.x >> 16);
    int l10 = (pl.y >> 16) * 96 + (pl.x & 0xffff);
    int l11 = (pl.y >> 16) * 96 + (pl.x >> 16);
    int h00 = (ph.y & 0xffff) * 96 + (ph.x & 0xffff);
    int h01 = (ph.y & 0xffff) * 96 + (ph.x >> 16);
    int h10 = (ph.y >> 16) * 96 + (ph.x & 0xffff);
    int h11 = (ph.y >> 16) * 96 + (ph.x >> 16);
    const unsigned short* cb0 = cp_pk + (((size_t)b * 8 + ch) * 9216) * 32 + coff;
    const unsigned short* sb0 = sp_pk + (((size_t)b * 8 + ch) * 9216) * 32 + coff;
    ushort4 tc0 = *(const ushort4*)&cb0[(size_t)l00 * 32];
    ushort4 tc0b = *(const ushort4*)&cb0[(size_t)l00 * 32 + 4];
    ushort4 tc1 = *(const ushort4*)&cb0[(size_t)l01 * 32];
    ushort4 tc1b = *(const ushort4*)&cb0[(size_t)l01 * 32 + 4];
    ushort4 tc2 = *(const ushort4*)&cb0[(size_t)l10 * 32];
    ushort4 tc2b = *(const ushort4*)&cb0[(size_t)l10 * 32 + 4];
    ushort4 tc3 = *(const ushort4*)&cb0[(size_t)l11 * 32];
    ushort4 tc3b = *(const ushort4*)&cb0[(size_t)l11 * 32 + 4];
    ushort4 ts0 = *(const ushort4*)&sb0[(size_t)h00 * 32];
    ushort4 ts0b = *(const ushort4*)&sb0[(size_t)h00 * 32 + 4];
    ushort4 ts1 = *(const ushort4*)&sb0[(size_t)h01 * 32];
    ushort4 ts1b = *(const ushort4*)&sb0[(size_t)h01 * 32 + 4];
    ushort4 ts2 = *(const ushort4*)&sb0[(size_t)h10 * 32];
    ushort4 ts2b = *(const ushort4*)&sb0[(size_t)h10 * 32 + 4];
    ushort4 ts3 = *(const ushort4*)&sb0[(size_t)h11 * 32];
    ushort4 ts3b = *(const ushort4*)&sb0[(size_t)h11 * 32 + 4];
    const unsigned short* c0a = (const unsigned short*)&tc0;
    const unsigned short* c0bp = (const unsigned short*)&tc0b;
    const unsigned short* c1a = (const unsigned short*)&tc1;
    const unsigned short* c1bp = (const unsigned short*)&tc1b;
    const unsigned short* c2a = (const unsigned short*)&tc2;
    const unsigned short* c2bp = (const unsigned short*)&tc2b;
    const unsigned short* c3a = (const unsigned short*)&tc3;
    const unsigned short* c3bp = (const unsigned short*)&tc3b;
    const unsigned short* s0a = (const unsigned short*)&ts0;
    const unsigned short* s0bp = (const unsigned short*)&ts0b;
    const unsigned short* s1a = (const unsigned short*)&ts1;
    const unsigned short* s1bp = (const unsigned short*)&ts1b;
    const unsigned short* s2a = (const unsigned short*)&ts2;
    const unsigned short* s2bp = (const unsigned short*)&ts2b;
    const unsigned short* s3a = (const unsigned short*)&ts3;
    const unsigned short* s3bp = (const unsigned short*)&ts3b;
    float* op = p5o + ((size_t)b * 256 + c0) * 9216 + pix;
#pragma unroll
    for (int i = 0; i < 8; ++i) {
        unsigned short v0 = (i < 4) ? c0a[i] : c0bp[i - 4];
        unsigned short v1 = (i < 4) ? c1a[i] : c1bp[i - 4];
        unsigned short v2 = (i < 4) ? c2a[i] : c2bp[i - 4];
        unsigned short v3 = (i < 4) ? c3a[i] : c3bp[i - 4];
        float cps = wl.x * bf2f(v0) + wl.y * bf2f(v1) + wl.z * bf2f(v2) + wl.w * bf2f(v3);
        unsigned short u0 = (i < 4) ? s0a[i] : s0bp[i - 4];
        unsigned short u1 = (i < 4) ? s1a[i] : s1bp[i - 4];
        unsigned short u2 = (i < 4) ? s2a[i] : s2bp[i - 4];
        unsigned short u3 = (i < 4) ? s3a[i] : s3bp[i - 4];
        float sps = wh.x * bf2f(u0) + wh.y * bf2f(u1) + wh.z * bf2f(u2) + wh.w * bf2f(u3);
        op[(size_t)i * 9216] = sps * at.x + cps * at.y;
    }
}

// ---------------------------------------------------------------------------
extern "C" void kernel_launch(void* const* d_in, const int* in_sizes, int n_in,
                              void* d_out, int out_size, void* d_ws, size_t ws_size,
                              hipStream_t stream) {
    const float* p3    = (const float*)d_in[0];
    const float* p5    = (const float*)d_in[1];
    const float* w_red = (const float*)d_in[2];
    const float* wq    = (const float*)d_in[3];
    const float* bq    = (const float*)d_in[4];
    const float* wk    = (const float*)d_in[5];
    const float* bk    = (const float*)d_in[6];
    const float* wv    = (const float*)d_in[7];
    const float* bv    = (const float*)d_in[8];
    const float* la_w1 = (const float*)d_in[9];
    const float* la_w2 = (const float*)d_in[10];
    const float* w32   = (const float*)d_in[11];
    const float* w8    = (const float*)d_in[12];
    const float* woff1 = (const float*)d_in[13];
    const float* woff2 = (const float*)d_in[14];

    float* out = (float*)d_out;
    float* p3o = out;                 // [8,512,24,24]
    float* p5o = out + 2359296;       // [8,256,96,96]

    float* ws = (float*)d_ws;
    float* x_   = ws + 0;             // 2359296
    float* ctx  = ws + 2359296;       // 2359296
    float* q    = ws + 4718592;       // 147456
    float* kf   = ws + 4866048;       // 204800
    float* km   = ws + 5070848;       // 12800
    float* vm   = ws + 5083648;       // 204800
    unsigned short* la1_pk = (unsigned short*)(ws + 5288448);   // 294912 u16
    float* sp24 = ws + 5435904;       // 1179648 -> ends 6615552
    float4* wpar = (float4*)(ws + 6615552);   // 294912 f4 -> 7795200
    int2*   ipk  = (int2*)(ws + 7795200);     // 294912 i2 -> 8385024
    float2* attp = (float2*)(ws + 8385024);   //  73728 f2 -> 8532480
    unsigned short* sp96_pk = (unsigned short*)(ws + 8601600);  // 18874368 u16 -> 18038784
    unsigned short* cp_pk   = (unsigned short*)(ws + 18038784); // -> 27475968
    unsigned short* p5_pk   = (unsigned short*)(ws + 27475968); // -> 36913152
    unsigned short* p3_pk   = (unsigned short*)(ws + 36913152); // -> 38092800
    unsigned short* wred_pk = (unsigned short*)(ws + 38092800); // -> 39272448
    unsigned short* w32_pk  = (unsigned short*)(ws + 39272448); // -> 39862272
    unsigned short* w8_pk   = (unsigned short*)(ws + 39862272); // -> 40157184
    unsigned short* wla2_pk = (unsigned short*)(ws + 40157184); // -> 40304640
    unsigned short* woff1_pk= (unsigned short*)(ws + 40304640); // -> 40321024
    float* simg = ws + 5288448 + 160000;  // unused la1 slack? keep separate:
    simg = ws + 40321024;                 // 230400 floats -> 40551424
    float* t64  = ws + 0;                 // spans x_+ctx (dead by K11)

    // P0: weight packs
    pack_w2_kernel<<<dim3(2359296 / 256), dim3(256), 0, stream>>>(w_red, wred_pk, 512, 512, 32);
    pack_w2_kernel<<<dim3(1179648 / 256), dim3(256), 0, stream>>>(w32, w32_pk, 512, 256, 16);
    pack_w2_kernel<<<dim3(589824 / 256), dim3(256), 0, stream>>>(w8, w8_pk, 256, 256, 64);
    pack_w2_kernel<<<dim3(294912 / 256), dim3(256), 0, stream>>>(la_w2, wla2_pk, 64, 512, 32);
    pack_w1_kernel<<<dim3(128), dim3(256), 0, stream>>>(woff1, woff1_pk);
    // P1: input packs
    pack_in_kernel<<<dim3(2359296 / 256), dim3(256), 0, stream>>>(p5, p5_pk, 256, 9216, 2359296);
    pack_in_kernel<<<dim3(294912 / 256), dim3(256), 0, stream>>>(p3, p3_pk, 512, 576, 294912);

    // K10: cp_pk = silu(conv3x3(p5, w8))  [MFMA, packed bf16 out]
    conv3x3_mfma2<16, 16, 4, 4, 1, 1><<<dim3(1152), dim3(256), 0, stream>>>(
        p5_pk, w8_pk, nullptr, cp_pk, 8, 256, 256, 96, 96, nullptr, nullptr);
    // K1: x = silu(conv3x3(p3, w_red))
    conv3x3_mfma2<8, 24, 3, 2, 1, 0><<<dim3(384), dim3(256), 0, stream>>>(
        p3_pk, wred_pk, x_, nullptr, 8, 512, 512, 24, 24, nullptr, nullptr);
    // K2: q
    gemm_om<0, 0><<<dim3(72), dim3(256), 0, stream>>>(
        wq, bq, x_, q, nullptr, 8, 512, 32, 576, 1, 9);
    // K3: psp
    psp_kernel<<<dim3(8 * 512), dim3(64), 0, stream>>>(x_, kf);
    // K4: k, v
    gemm_om<0, 0><<<dim3(8), dim3(256), 0, stream>>>(
        wk, bk, kf, km, nullptr, 8, 512, 32, 50, 1, 1);
    gemm_om<0, 0><<<dim3(64), dim3(256), 0, stream>>>(
        wv, bv, kf, vm, nullptr, 8, 512, 512, 50, 8, 1);
    // K5: attention
    sim_kernel<<<dim3(72), dim3(256), 0, stream>>>(q, km, simg);
    ctx_kernel<<<dim3(288), dim3(256), 0, stream>>>(vm, simg, ctx);
    // K6: la1 (packed bf16 direct)
    gemm_om<1, 1><<<dim3(72), dim3(256), 0, stream>>>(
        la_w1, nullptr, ctx, nullptr, la1_pk, 8, 512, 64, 576, 1, 9);
    // K7: p3o (f32 out) + p3_pk (packed)
    conv3x3_mfma2<8, 24, 3, 2, 2, 2><<<dim3(384), dim3(256), 0, stream>>>(
        la1_pk, wla2_pk, p3o, p3_pk, 8, 64, 512, 24, 24, ctx, x_);
    // K8: sp24 = silu(conv3x3(p3o, w32))
    conv3x3_mfma2<8, 24, 3, 1, 1, 0><<<dim3(384), dim3(256), 0, stream>>>(
        p3_pk, w32_pk, sp24, nullptr, 8, 512, 256, 24, 24, nullptr, nullptr);
    // K9: sp96_pk = upsample(sp24), packed bf16
    upsample2_kernel<<<dim3(9216), dim3(256), 0, stream>>>(sp24, sp96_pk);
    // K11: t64 = silu(conv1x1(concat)) [MFMA]
    cat_mfma<<<dim3(576), dim3(256), 0, stream>>>(cp_pk, sp96_pk, woff1_pk, t64);
    // K12: conv3x3(t64, woff2) + fused grid-sample prep
    conv3x3_kernel<8, 32, 12, 3, 4, 3><<<dim3(288), dim3(192), 0, stream>>>(
        t64, woff2, nullptr, 8, 64, 10, 96, 96, wpar, ipk, attp);
    // K13: p5o = gather blend (uint4 taps, 8 ch/thread)
    gsample3_kernel<<<dim3(9216), dim3(256), 0, stream>>>(
        cp_pk, sp96_pk, wpar, ipk, attp, p5o);
}